// Round 8
// baseline (11461.177 us; speedup 1.0000x reference)
//
#include <hip/hip_runtime.h>
#include <math.h>

#define TT 1024
#define DD 384
#define NH 6
#define DI 768
#define MH 12
#define DS 64
#define NL 8
#define XDIM 1676   // 2*DI + 2*DS + MH
#define CONVC 896   // DI + 2*DS
#define NV 32000
#define PZS 3712    // fused output width: [r|k|v|g|w](1920) + [z|xBC|dt](1792 padded)
#define G_OFF 1152
#define W_OFF 1536
#define Z_OFF 1920
#define XBC_OFF 2688   // Z_OFF + DI
#define DT_OFF 3584    // Z_OFF + 1664
#define CHK 32      // scan chunk length
#define NCH 32      // number of chunks
#define MGRID 576   // mega-kernel grid
#define NGRP 16
#define GRPSZ 36    // 576/16

typedef __attribute__((ext_vector_type(8))) short short8;
typedef __attribute__((ext_vector_type(4))) float f32x4;

// ---------------- helpers ----------------
__device__ __forceinline__ float siluf(float x) { return x / (1.f + expf(-x)); }
__device__ __forceinline__ float sigmoidf_(float x) { return 1.f / (1.f + expf(-x)); }
__device__ __forceinline__ float geluf(float x) {
  return 0.5f * x * (1.f + erff(x * 0.70710678118654752440f));
}
__device__ __forceinline__ unsigned short f2b(float x) {
  union { float f; unsigned int u; } v; v.f = x;
  unsigned int r = v.u + 0x7fffu + ((v.u >> 16) & 1u);
  return (unsigned short)(r >> 16);
}

#define GLDS(gp, lp) __builtin_amdgcn_global_load_lds( \
    (const __attribute__((address_space(1))) void*)(gp), \
    (__attribute__((address_space(3))) void*)(lp), 16, 0, 0)

// ---------------- two-level software grid barrier (device scope) ----------------
// layout in bar[]: group counters at g*64 (g=0..15), root at 16*64, gen at 17*64
__device__ __forceinline__ void gridbar(unsigned* bar, int b)
{
  __syncthreads();
  if (threadIdx.x == 0) {
    __threadfence();
    unsigned* gen = bar + 17 * 64;
    unsigned g = __hip_atomic_load(gen, __ATOMIC_RELAXED, __HIP_MEMORY_SCOPE_AGENT);
    unsigned* c = bar + (unsigned)(b & (NGRP - 1)) * 64;
    unsigned t = __hip_atomic_fetch_add(c, 1u, __ATOMIC_ACQ_REL, __HIP_MEMORY_SCOPE_AGENT);
    if (t == GRPSZ - 1u) {
      __hip_atomic_store(c, 0u, __ATOMIC_RELAXED, __HIP_MEMORY_SCOPE_AGENT);
      unsigned* root = bar + 16 * 64;
      unsigned r = __hip_atomic_fetch_add(root, 1u, __ATOMIC_ACQ_REL, __HIP_MEMORY_SCOPE_AGENT);
      if (r == NGRP - 1u) {
        __hip_atomic_store(root, 0u, __ATOMIC_RELAXED, __HIP_MEMORY_SCOPE_AGENT);
        __hip_atomic_fetch_add(gen, 1u, __ATOMIC_RELEASE, __HIP_MEMORY_SCOPE_AGENT);
      } else {
        while (__hip_atomic_load(gen, __ATOMIC_ACQUIRE, __HIP_MEMORY_SCOPE_AGENT) == g)
          __builtin_amdgcn_s_sleep(2);
      }
    } else {
      while (__hip_atomic_load(gen, __ATOMIC_ACQUIRE, __HIP_MEMORY_SCOPE_AGENT) == g)
        __builtin_amdgcn_s_sleep(2);
    }
    __threadfence();
  }
  __syncthreads();
}

// ---------------- 64-tile bf16 MFMA GEMM tile (BK=64), callable per-phase ----------------
// epi: 0 = store f32, 1 = gelu->bf16, 3 = atomic-add f32
__device__ __forceinline__ void gemm64_tile(
    const unsigned short* __restrict__ A, const unsigned short* __restrict__ Bt,
    float* __restrict__ C, unsigned short* __restrict__ Cb,
    int N, int K, int ldC, int bx, int by, int kz, int nkz, int epi,
    unsigned short* As, unsigned short* Bs, int tid)
{
  __syncthreads();
  int wid = tid >> 6, lane = tid & 63;
  int m0 = by * 64, n0 = bx * 64;
  int wr = wid >> 1, wc = wid & 1;
  int r0 = tid >> 3, ch = tid & 7;
  int scs = (ch ^ (r0 & 7)) * 8;
  const unsigned short* ga = A  + (size_t)(m0 + r0) * K + scs;
  const unsigned short* gb = Bt + (size_t)(n0 + r0) * K + scs;
  unsigned short* la = As + wid * 512;
  unsigned short* lb = Bs + wid * 512;
  int fr = lane & 15, fc = lane >> 4;
  f32x4 zz = {0.f, 0.f, 0.f, 0.f};
  f32x4 acc[2][2];
  acc[0][0] = zz; acc[0][1] = zz; acc[1][0] = zz; acc[1][1] = zz;
  int kper = K / nkz;
  int ks = kz * kper, ke = ks + kper;
  size_t row32 = (size_t)32 * K;
  for (int k0 = ks; k0 < ke; k0 += 64) {
    GLDS(ga + k0, la);
    GLDS(ga + k0 + row32, la + 2048);
    GLDS(gb + k0, lb);
    GLDS(gb + k0 + row32, lb + 2048);
    __syncthreads();
#pragma unroll
    for (int kh = 0; kh < 2; ++kh) {
      short8 af[2], bf[2];
#pragma unroll
      for (int mg = 0; mg < 2; ++mg) {
        int ar = wr * 32 + mg * 16 + fr;
        af[mg] = *reinterpret_cast<const short8*>(&As[ar * 64 + (((kh * 4 + fc) ^ (ar & 7)) * 8)]);
      }
#pragma unroll
      for (int ng = 0; ng < 2; ++ng) {
        int br = wc * 32 + ng * 16 + fr;
        bf[ng] = *reinterpret_cast<const short8*>(&Bs[br * 64 + (((kh * 4 + fc) ^ (br & 7)) * 8)]);
      }
#pragma unroll
      for (int mg = 0; mg < 2; ++mg)
#pragma unroll
        for (int ng = 0; ng < 2; ++ng)
          acc[mg][ng] = __builtin_amdgcn_mfma_f32_16x16x32_bf16(af[mg], bf[ng], acc[mg][ng], 0, 0, 0);
    }
    __syncthreads();
  }
#pragma unroll
  for (int mg = 0; mg < 2; ++mg)
#pragma unroll
    for (int ng = 0; ng < 2; ++ng) {
      int col = n0 + wc * 32 + ng * 16 + fr;
#pragma unroll
      for (int j = 0; j < 4; ++j) {
        int row = m0 + wr * 32 + mg * 16 + fc * 4 + j;
        if (epi == 1)      Cb[(size_t)row * ldC + col] = f2b(geluf(acc[mg][ng][j]));
        else if (epi == 3) atomicAdd(&C[(size_t)row * ldC + col], acc[mg][ng][j]);
        else               C[(size_t)row * ldC + col]  = acc[mg][ng][j];
      }
    }
}

// ---------------- scanA item (identical math to prior scanA_kernel) ----------------
__device__ void scanA_item(int b, int tid, float* smem,
    const float* __restrict__ PZ, const float* __restrict__ u, const float* __restrict__ wbias,
    float* __restrict__ so, float* __restrict__ rPb,
    float* __restrict__ MstR, float* __restrict__ DcR,
    const float* __restrict__ cw, const float* __restrict__ cbia, const float* __restrict__ dtbias,
    const float* __restrict__ Alog, const float* __restrict__ Dpw,
    float* __restrict__ yb, float* __restrict__ Ccb,
    float* __restrict__ MstM, float* __restrict__ DcM)
{
  if (b < 192) {
    int h = b >> 5, c = b & 31;
    float* sbuf = smem; float* us = smem + 512;
    if (tid < 64) us[tid] = u[h * 64 + tid];
    int wv = tid >> 6, l = tid & 63;
    int vv = wv * 16 + (l & 15);
    int kc = l >> 4;
    int arr = tid >> 6, idx = tid & 63;
    int off = (arr == 0) ? 0 : (arr == 1) ? 384 : (arr == 2) ? W_OFF : 768;  // r,k,w(raw),v
    float wb = (arr == 2) ? wbias[h * 64 + idx] : 0.f;
    size_t base = (size_t)h * 64 + idx + off;
    int t0 = c * CHK;
    float S[16], Pc[16];
#pragma unroll
    for (int i = 0; i < 16; i++) { S[i] = 0.f; Pc[i] = 1.f; }
    float reg = PZ[(size_t)t0 * PZS + base];
    bool st = (wv == 0) && ((l & 15) == 0);
    for (int t = 0; t < CHK; ++t) {
      int tt = t0 + t;
      float* cb = sbuf + (t & 1) * 256;
      cb[arr * 64 + idx] = (arr == 2) ? expf(-expf(reg + wb)) : reg;
      if (t + 1 < CHK) reg = PZ[(size_t)(tt + 1) * PZS + base];
      __syncthreads();
      float vt = cb[192 + vv];
      float acc = 0.f;
      float rp[16];
#pragma unroll
      for (int i = 0; i < 16; ++i) {
        int kk = kc * 16 + i;
        float rv = cb[kk], kv = cb[64 + kk], dv = cb[128 + kk];
        rp[i] = rv * Pc[i];
        float kvv = kv * vt;
        acc = fmaf(rv, fmaf(us[kk], kvv, S[i]), acc);
        S[i] = fmaf(dv, S[i], kvv);
        Pc[i] *= dv;
      }
      acc += __shfl_xor(acc, 16);
      acc += __shfl_xor(acc, 32);
      if (l < 16) so[(size_t)tt * DD + h * 64 + vv] = acc;
      if (st) {
        float4* dst = (float4*)&rPb[(size_t)tt * DD + h * 64 + kc * 16];
        dst[0] = make_float4(rp[0], rp[1], rp[2], rp[3]);
        dst[1] = make_float4(rp[4], rp[5], rp[6], rp[7]);
        dst[2] = make_float4(rp[8], rp[9], rp[10], rp[11]);
        dst[3] = make_float4(rp[12], rp[13], rp[14], rp[15]);
      }
      __syncthreads();
    }
    float* ms = MstR + (size_t)(h * NCH + c) * 4096;   // [v][k]
    float4* msv = (float4*)&ms[vv * 64 + kc * 16];
    msv[0] = make_float4(S[0], S[1], S[2], S[3]);
    msv[1] = make_float4(S[4], S[5], S[6], S[7]);
    msv[2] = make_float4(S[8], S[9], S[10], S[11]);
    msv[3] = make_float4(S[12], S[13], S[14], S[15]);
    if (st) {
      float4* dd_ = (float4*)&DcR[(h * NCH + c) * 64 + kc * 16];
      dd_[0] = make_float4(Pc[0], Pc[1], Pc[2], Pc[3]);
      dd_[1] = make_float4(Pc[4], Pc[5], Pc[6], Pc[7]);
      dd_[2] = make_float4(Pc[8], Pc[9], Pc[10], Pc[11]);
      dd_[3] = make_float4(Pc[12], Pc[13], Pc[14], Pc[15]);
    }
  } else {
    int bb = b - 192;
    int hh = bb >> 5, c = bb & 31;
    float* sbuf = smem;
    int wv = tid >> 6, l = tid & 63;
    int p = wv * 16 + (l & 15);
    int sc = l >> 4;
    int arr = tid >> 6, idx = tid & 63;
    float A = -expf(Alog[hh]);
    float Dph = Dpw[hh];
    float dtbh = dtbias[hh];
    int t0 = c * CHK;
    float cw0 = 0.f, cw1 = 0.f, cw2 = 0.f, cw3 = 0.f, cbv = 0.f;
    float xw0 = 0.f, xw1 = 0.f, xw2 = 0.f, cur = 0.f;
    const float* xcol = nullptr;
    float reg = 0.f;
    if (arr < 3) {
      int chn = (arr == 0) ? (hh * 64 + idx) : (arr == 1) ? (DI + idx) : (DI + DS + idx);
      cw0 = cw[chn * 4 + 0]; cw1 = cw[chn * 4 + 1]; cw2 = cw[chn * 4 + 2]; cw3 = cw[chn * 4 + 3];
      cbv = cbia[chn];
      xcol = PZ + XBC_OFF + chn;
      xw0 = (t0 >= 3) ? xcol[(size_t)(t0 - 3) * PZS] : 0.f;
      xw1 = (t0 >= 2) ? xcol[(size_t)(t0 - 2) * PZS] : 0.f;
      xw2 = (t0 >= 1) ? xcol[(size_t)(t0 - 1) * PZS] : 0.f;
      cur = xcol[(size_t)t0 * PZS];
    } else {
      reg = PZ[(size_t)t0 * PZS + DT_OFF + hh];
    }
    float S[16]; float cdA = 1.f;
#pragma unroll
    for (int i = 0; i < 16; i++) S[i] = 0.f;
    bool st = (wv == 0) && ((l & 15) == 0);
    for (int t = 0; t < CHK; ++t) {
      int tt = t0 + t;
      float* cb = sbuf + (t & 1) * 256;
      if (arr < 3) {
        float cvv = fmaf(cw3, cur, fmaf(cw2, xw2, fmaf(cw1, xw1, fmaf(cw0, xw0, cbv))));
        cb[arr * 64 + idx] = siluf(cvv);
        float nx = (t + 1 < CHK) ? xcol[(size_t)(tt + 1) * PZS] : 0.f;
        xw0 = xw1; xw1 = xw2; xw2 = cur; cur = nx;
      } else {
        if (idx == 0) {
          float v = reg + dtbh;
          cb[192] = (v > 20.f) ? v : log1pf(expf(v));
        }
        if (t + 1 < CHK) reg = PZ[(size_t)(tt + 1) * PZS + DT_OFF + hh];
      }
      __syncthreads();
      float dt_ = cb[192];
      float dA = expf(dt_ * A);
      cdA *= dA;
      float xp = cb[p];
      float dtx = dt_ * xp;
      float acc = 0.f;
#pragma unroll
      for (int i = 0; i < 16; ++i) {
        int s = sc * 16 + i;
        S[i] = fmaf(dA, S[i], dtx * cb[64 + s]);
        acc = fmaf(S[i], cb[128 + s], acc);
      }
      acc += __shfl_xor(acc, 16);
      acc += __shfl_xor(acc, 32);
      if (l < 16) yb[(size_t)tt * DI + hh * 64 + p] = fmaf(Dph, xp, acc);
      if (st) {
        float4* dst = (float4*)&Ccb[(size_t)tt * DI + hh * 64 + sc * 16];
#pragma unroll
        for (int j4 = 0; j4 < 4; ++j4)
          dst[j4] = make_float4(cdA * cb[128 + sc * 16 + j4 * 4 + 0],
                                cdA * cb[128 + sc * 16 + j4 * 4 + 1],
                                cdA * cb[128 + sc * 16 + j4 * 4 + 2],
                                cdA * cb[128 + sc * 16 + j4 * 4 + 3]);
      }
      __syncthreads();
    }
    float* ms = MstM + (size_t)(hh * NCH + c) * 4096;  // [p][s]
    float4* msv = (float4*)&ms[p * 64 + sc * 16];
    msv[0] = make_float4(S[0], S[1], S[2], S[3]);
    msv[1] = make_float4(S[4], S[5], S[6], S[7]);
    msv[2] = make_float4(S[8], S[9], S[10], S[11]);
    msv[3] = make_float4(S[12], S[13], S[14], S[15]);
    if (tid == 0) DcM[hh * NCH + c] = cdA;
  }
}

// ---------------- corr item (prefix-combine + correction + fused gn*silu) ----------------
__device__ void corr_item(int b, int tid, float* S0l, float* Rl,
    const float* __restrict__ MstR, const float* __restrict__ DcR,
    const float* __restrict__ rPb, const float* __restrict__ so,
    const float* __restrict__ MstM, const float* __restrict__ DcM,
    const float* __restrict__ Ccb, float* __restrict__ yb,
    const float* __restrict__ PZ, const float* __restrict__ gnw, const float* __restrict__ gnb,
    unsigned short* __restrict__ gob)
{
  const float* rg; int ostride, obase, t0;
  bool rwkv = (b < 192);
  int h, cidx;
  if (rwkv) {
    h = b >> 5; cidx = b & 31;
    rg = rPb; obase = h * 64; ostride = DD;
  } else {
    int bb = b - 192; h = bb >> 5; cidx = bb & 31;
    rg = Ccb; obase = h * 64; ostride = DI;
  }
  t0 = cidx * CHK;
  float Sreg[16];
#pragma unroll
  for (int it = 0; it < 16; ++it) Sreg[it] = 0.f;
  if (rwkv) {
    int kk = tid & 63;
    for (int cp = 0; cp < cidx; ++cp) {
      float d = DcR[(h * NCH + cp) * 64 + kk];
      const float* mb = MstR + (size_t)(h * NCH + cp) * 4096;
#pragma unroll
      for (int it = 0; it < 16; ++it)
        Sreg[it] = fmaf(d, Sreg[it], mb[tid + 256 * it]);
    }
  } else {
    for (int cp = 0; cp < cidx; ++cp) {
      float d = DcM[h * NCH + cp];
      const float* mb = MstM + (size_t)(h * NCH + cp) * 4096;
#pragma unroll
      for (int it = 0; it < 16; ++it)
        Sreg[it] = fmaf(d, Sreg[it], mb[tid + 256 * it]);
    }
  }
#pragma unroll
  for (int it = 0; it < 16; ++it) {
    int gi = tid + 256 * it;
    S0l[(gi & 63) * 68 + (gi >> 6)] = Sreg[it];
  }
  {
    int t = tid >> 3, q = (tid & 7) * 8;
    const float4* src = (const float4*)&rg[(size_t)(t0 + t) * ostride + obase + q];
    float4* dst = (float4*)&Rl[t * 68 + q];
    dst[0] = src[0]; dst[1] = src[1];
  }
  __syncthreads();
  int t = tid >> 3, q = (tid & 7) * 8;
  float acc[8];
#pragma unroll
  for (int j = 0; j < 8; j++) acc[j] = 0.f;
  for (int k = 0; k < 64; ++k) {
    float rv = Rl[t * 68 + k];
    const float4* sp = (const float4*)&S0l[k * 68 + q];
    float4 s0 = sp[0], s1 = sp[1];
    acc[0] = fmaf(rv, s0.x, acc[0]);
    acc[1] = fmaf(rv, s0.y, acc[1]);
    acc[2] = fmaf(rv, s0.z, acc[2]);
    acc[3] = fmaf(rv, s0.w, acc[3]);
    acc[4] = fmaf(rv, s1.x, acc[4]);
    acc[5] = fmaf(rv, s1.y, acc[5]);
    acc[6] = fmaf(rv, s1.z, acc[6]);
    acc[7] = fmaf(rv, s1.w, acc[7]);
  }
  if (!rwkv) {
    float4* op = (float4*)&yb[(size_t)(t0 + t) * DI + obase + q];
    float4 c0 = op[0], c1 = op[1];
    c0.x += acc[0]; c0.y += acc[1]; c0.z += acc[2]; c0.w += acc[3];
    c1.x += acc[4]; c1.y += acc[5]; c1.z += acc[6]; c1.w += acc[7];
    op[0] = c0; op[1] = c1;
  } else {
    float ov[8];
    const float4* sp = (const float4*)&so[(size_t)(t0 + t) * DD + obase + q];
    float4 s0 = sp[0], s1 = sp[1];
    ov[0] = s0.x + acc[0]; ov[1] = s0.y + acc[1]; ov[2] = s0.z + acc[2]; ov[3] = s0.w + acc[3];
    ov[4] = s1.x + acc[4]; ov[5] = s1.y + acc[5]; ov[6] = s1.z + acc[6]; ov[7] = s1.w + acc[7];
    float m_ = 0.f;
#pragma unroll
    for (int j = 0; j < 8; j++) m_ += ov[j];
    m_ += __shfl_xor(m_, 1); m_ += __shfl_xor(m_, 2); m_ += __shfl_xor(m_, 4);
    float mu = m_ * (1.f / 64.f);
    float vv = 0.f;
#pragma unroll
    for (int j = 0; j < 8; j++) { float d = ov[j] - mu; vv = fmaf(d, d, vv); }
    vv += __shfl_xor(vv, 1); vv += __shfl_xor(vv, 2); vv += __shfl_xor(vv, 4);
    float rstd = rsqrtf(vv * (1.f / 64.f) + 1e-5f);
#pragma unroll
    for (int j = 0; j < 8; j++) {
      int d = obase + q + j;
      float gv = PZ[(size_t)(t0 + t) * PZS + G_OFF + d];
      float o = fmaf((ov[j] - mu) * rstd, gnw[d], gnb[d]) * siluf(gv);
      gob[(size_t)(t0 + t) * DD + d] = f2b(o);
    }
  }
}

// ---------------- mega kernel: all 8 layers, phases separated by software grid barrier ----------------
__global__ __launch_bounds__(256, 3) void mega_kernel(
    const float* __restrict__ ln_w, const float* __restrict__ u_, const float* __restrict__ w_bias,
    const float* __restrict__ conv_w, const float* __restrict__ conv_b, const float* __restrict__ dt_bias,
    const float* __restrict__ A_log, const float* __restrict__ Dp, const float* __restrict__ mn_w,
    const float* __restrict__ gn_w, const float* __restrict__ gn_b,
    const float* __restrict__ gw, const float* __restrict__ gb, const float* __restrict__ ffn_ln_w,
    const float* __restrict__ ln_out_w,
    const unsigned short* __restrict__ WallT, const unsigned short* __restrict__ WoT,
    const unsigned short* __restrict__ WoutT, const unsigned short* __restrict__ F1T,
    const unsigned short* __restrict__ F2T,
    float* __restrict__ h, float* __restrict__ PZ, float* __restrict__ yb, float* __restrict__ so,
    float* __restrict__ orb, float* __restrict__ omb, float* __restrict__ rPb, float* __restrict__ Ccb,
    float* __restrict__ MstR, float* __restrict__ DcR, float* __restrict__ MstM, float* __restrict__ DcM,
    unsigned short* __restrict__ xnb, unsigned short* __restrict__ gob,
    unsigned short* __restrict__ ynb, unsigned short* __restrict__ fhb,
    unsigned* bar)
{
  __shared__ __align__(16) char smraw[26112];
  int b = blockIdx.x, tid = threadIdx.x;
  unsigned short* As = (unsigned short*)smraw;
  unsigned short* Bs = As + 4096;
  float* fsm = (float*)smraw;
  float* S0l = fsm;
  float* Rl = fsm + 64 * 68;

  for (int i = 0; i < NL; ++i) {
    const unsigned short* WallT_i = WallT + (size_t)i * PZS * 384;
    const unsigned short* WoT_i   = WoT   + (size_t)i * 384 * 384;
    const unsigned short* WoutT_i = WoutT + (size_t)i * 384 * 768;
    const unsigned short* F1T_i   = F1T   + (size_t)i * 1536 * 384;
    const unsigned short* F2T_i   = F2T   + (size_t)i * 384 * 1536;
    const float* lnw_i = ln_w + (size_t)i * DD;
    const float* u_i   = u_ + (size_t)i * NH * 64;
    const float* wb_i  = w_bias + (size_t)i * DD;
    const float* cw_i  = conv_w + (size_t)i * CONVC * 4;
    const float* cb_i  = conv_b + (size_t)i * CONVC;
    const float* dtb_i = dt_bias + (size_t)i * MH;
    const float* Al_i  = A_log + (size_t)i * MH;
    const float* Dp_i  = Dp + (size_t)i * MH;
    const float* mnw_i = mn_w + (size_t)i * DI;
    const float* gnw_i = gn_w + (size_t)i * DD;
    const float* gnb_i = gn_b + (size_t)i * DD;
    const float* gw_i  = gw + (size_t)i * 2 * DD;
    const float* gb_i  = gb + i;
    const float* fln_i = ffn_ln_w + (size_t)i * DD;

    // P1: RMSNorm h -> xnb (wave per row)
    {
      int row = b * 4 + (tid >> 6);
      if (row < TT) {
        int lane = tid & 63;
        const float* r = h + (size_t)row * DD;
        float v[6]; float ss = 0.f;
#pragma unroll
        for (int j = 0; j < 6; ++j) { v[j] = r[lane + j * 64]; ss = fmaf(v[j], v[j], ss); }
#pragma unroll
        for (int s = 1; s < 64; s <<= 1) ss += __shfl_xor(ss, s);
        float scale = rsqrtf(ss * (1.f / DD) + 1e-6f);
#pragma unroll
        for (int j = 0; j < 6; ++j)
          xnb[(size_t)row * DD + lane + j * 64] = f2b(lnw_i[lane + j * 64] * v[j] * scale);
      }
    }
    gridbar(bar, b);

    // P2: fused projection GEMM xnb @ WallT -> PZ (928 tiles)
    for (int t5 = b; t5 < 928; t5 += MGRID)
      gemm64_tile(xnb, WallT_i, PZ, nullptr, PZS, 384, PZS, t5 % 58, t5 / 58, 0, 1, 0, As, Bs, tid);
    gridbar(bar, b);

    // P3: scans
    scanA_item(b, tid, fsm, PZ, u_i, wb_i, so, rPb, MstR, DcR,
               cw_i, cb_i, dtb_i, Al_i, Dp_i, yb, Ccb, MstM, DcM);
    gridbar(bar, b);

    // P4: prefix + correction
    corr_item(b, tid, S0l, Rl, MstR, DcR, rPb, so, MstM, DcM, Ccb, yb,
              PZ, gnw_i, gnb_i, gob);
    gridbar(bar, b);

    // P5: mamba norm -> ynb (wave per row)
    {
      int row = b * 4 + (tid >> 6);
      if (row < TT) {
        int lane = tid & 63;
        float v[12]; float ss = 0.f;
#pragma unroll
        for (int j = 0; j < 12; ++j) {
          int c = lane + j * 64;
          float z = PZ[(size_t)row * PZS + Z_OFF + c];
          float t = yb[(size_t)row * DI + c] * siluf(z);
          v[j] = t; ss = fmaf(t, t, ss);
        }
#pragma unroll
        for (int s = 1; s < 64; s <<= 1) ss += __shfl_xor(ss, s);
        float scale = rsqrtf(ss * (1.f / DI) + 1e-6f);
#pragma unroll
        for (int j = 0; j < 12; ++j) {
          int c = lane + j * 64;
          ynb[(size_t)row * DI + c] = f2b(v[j] * scale * mnw_i[c]);
        }
      }
    }
    gridbar(bar, b);

    // P6: dual GEMM: gob@Wo -> orb (96 tiles) ; ynb@Wout -> omb (96 tiles)
    if (b < 96)
      gemm64_tile(gob, WoT_i, orb, nullptr, 384, 384, 384, b % 6, b / 6, 0, 1, 0, As, Bs, tid);
    else if (b < 192) {
      int t = b - 96;
      gemm64_tile(ynb, WoutT_i, omb, nullptr, 384, 768, 384, t % 6, t / 6, 0, 1, 0, As, Bs, tid);
    }
    gridbar(bar, b);

    // P7: gate + residual + FFN RMSNorm (wave per row)
    {
      int row = b * 4 + (tid >> 6);
      if (row < TT) {
        int lane = tid & 63;
        float a[6], bq[6]; float ss = 0.f;
#pragma unroll
        for (int j = 0; j < 6; ++j) {
          int c = lane + j * 64;
          a[j] = orb[(size_t)row * DD + c]; bq[j] = omb[(size_t)row * DD + c];
          ss += a[j] * gw_i[c] + bq[j] * gw_i[DD + c];
        }
#pragma unroll
        for (int s = 1; s < 64; s <<= 1) ss += __shfl_xor(ss, s);
        float gate = sigmoidf_(ss + gb_i[0]);
        float hn[6]; float ss2 = 0.f;
#pragma unroll
        for (int j = 0; j < 6; ++j) {
          int c = lane + j * 64;
          size_t ix = (size_t)row * DD + c;
          hn[j] = h[ix] + gate * a[j] + (1.f - gate) * bq[j];
          h[ix] = hn[j];
          ss2 = fmaf(hn[j], hn[j], ss2);
        }
#pragma unroll
        for (int s = 1; s < 64; s <<= 1) ss2 += __shfl_xor(ss2, s);
        float scale = rsqrtf(ss2 * (1.f / DD) + 1e-6f);
#pragma unroll
        for (int j = 0; j < 6; ++j) {
          int c = lane + j * 64;
          xnb[(size_t)row * DD + c] = f2b(fln_i[c] * hn[j] * scale);
        }
      }
    }
    gridbar(bar, b);

    // P8: FFN1 GEMM + gelu -> fhb (384 tiles)
    if (b < 384)
      gemm64_tile(xnb, F1T_i, nullptr, fhb, 1536, 384, 1536, b % 24, b / 24, 0, 1, 1, As, Bs, tid);
    gridbar(bar, b);

    // P9: FFN2 GEMM split-K=4, atomic += h (384 tiles)
    if (b < 384) {
      int kz = b / 96, t = b % 96;
      gemm64_tile(fhb, F2T_i, h, nullptr, 384, 1536, 384, t % 6, t / 6, kz, 4, 3, As, Bs, tid);
    }
    gridbar(bar, b);
  }

  // final RMSNorm -> xnb for logits
  {
    int row = b * 4 + (tid >> 6);
    if (row < TT) {
      int lane = tid & 63;
      const float* r = h + (size_t)row * DD;
      float v[6]; float ss = 0.f;
#pragma unroll
      for (int j = 0; j < 6; ++j) { v[j] = r[lane + j * 64]; ss = fmaf(v[j], v[j], ss); }
#pragma unroll
      for (int s = 1; s < 64; s <<= 1) ss += __shfl_xor(ss, s);
      float scale = rsqrtf(ss * (1.f / DD) + 1e-6f);
#pragma unroll
      for (int j = 0; j < 6; ++j)
        xnb[(size_t)row * DD + lane + j * 64] = f2b(ln_out_w[lane + j * 64] * v[j] * scale);
    }
  }
}

// ---------------- 128-tile bf16 MFMA GEMM (logits), BK=64 ----------------
__global__ __launch_bounds__(256) void gemm128(
    const unsigned short* __restrict__ A, const unsigned short* __restrict__ Bt,
    float* __restrict__ C, int N, int K, int ldC)
{
  __shared__ unsigned short As[8192];   // [128][64]
  __shared__ unsigned short Bs[8192];
  int tid = threadIdx.x;
  int wid = tid >> 6, lane = tid & 63;
  int m0 = blockIdx.y * 128, n0 = blockIdx.x * 128;
  int wr = wid >> 1, wc = wid & 1;
  int r0 = tid >> 3, ch = tid & 7;
  int scs = (ch ^ (r0 & 7)) * 8;
  const unsigned short* ga = A  + (size_t)(m0 + r0) * K + scs;
  const unsigned short* gb = Bt + (size_t)(n0 + r0) * K + scs;
  int fr = lane & 15, fc = lane >> 4;
  f32x4 zz = {0.f, 0.f, 0.f, 0.f};
  f32x4 acc[4][4];
#pragma unroll
  for (int i = 0; i < 4; i++)
#pragma unroll
    for (int j = 0; j < 4; j++) acc[i][j] = zz;

  size_t row32 = (size_t)32 * K;
  for (int k0 = 0; k0 < K; k0 += 64) {
#pragma unroll
    for (int i = 0; i < 4; ++i) {
      GLDS(ga + k0 + i * row32, As + i * 2048 + wid * 512);
      GLDS(gb + k0 + i * row32, Bs + i * 2048 + wid * 512);
    }
    __syncthreads();
#pragma unroll
    for (int kh = 0; kh < 2; ++kh) {
      short8 af[4], bf[4];
#pragma unroll
      for (int mg = 0; mg < 4; ++mg) {
        int ar = wr * 64 + mg * 16 + fr;
        af[mg] = *reinterpret_cast<const short8*>(&As[ar * 64 + (((kh * 4 + fc) ^ (ar & 7)) * 8)]);
      }
#pragma unroll
      for (int ng = 0; ng < 4; ++ng) {
        int br = wc * 64 + ng * 16 + fr;
        bf[ng] = *reinterpret_cast<const short8*>(&Bs[br * 64 + (((kh * 4 + fc) ^ (br & 7)) * 8)]);
      }
#pragma unroll
      for (int mg = 0; mg < 4; ++mg)
#pragma unroll
        for (int ng = 0; ng < 4; ++ng)
          acc[mg][ng] = __builtin_amdgcn_mfma_f32_16x16x32_bf16(af[mg], bf[ng], acc[mg][ng], 0, 0, 0);
    }
    __syncthreads();
  }
#pragma unroll
  for (int mg = 0; mg < 4; ++mg)
#pragma unroll
    for (int ng = 0; ng < 4; ++ng) {
      int col = n0 + wc * 64 + ng * 16 + fr;
      if (col < N) {
#pragma unroll
        for (int j = 0; j < 4; ++j) {
          int row = m0 + wr * 64 + mg * 16 + fc * 4 + j;
          C[(size_t)row * ldC + col] = acc[mg][ng][j];
        }
      }
    }
}

// ---------------- merged weight transpose + fp32->bf16 (all jobs, one dispatch) ----------------
struct TCJob { const float* src; unsigned short* dst; int K, N, Npad, nx; size_t sStr, dStr; int tend; };
struct TC10 { TCJob j[10]; };

__global__ __launch_bounds__(256) void transconv_all(TC10 P)
{
  __shared__ float tile[32][33];
  int bid = blockIdx.x;
  int q = 0;
  while (bid >= P.j[q].tend) ++q;
  int tstart = (q == 0) ? 0 : P.j[q - 1].tend;
  TCJob jb = P.j[q];
  int local = bid - tstart;
  int bx = local % jb.nx, by = local / jb.nx;
  const float* src = jb.src + (size_t)blockIdx.y * jb.sStr;
  unsigned short* dst = jb.dst + (size_t)blockIdx.y * jb.dStr;
  int k0 = by * 32, n0 = bx * 32;
  int tx = threadIdx.x & 31, ty = threadIdx.x >> 5;
  for (int i = ty; i < 32; i += 8) {
    int k = k0 + i, n = n0 + tx;
    tile[i][tx] = (k < jb.K && n < jb.N) ? src[(size_t)k * jb.N + n] : 0.f;
  }
  __syncthreads();
  for (int i = ty; i < 32; i += 8) {
    int n = n0 + i, k = k0 + tx;
    if (n < jb.Npad && k < jb.K) dst[(size_t)n * jb.K + k] = f2b(tile[tx][i]);
  }
}

__global__ void conv_b16_kernel(const float* __restrict__ src, unsigned short* __restrict__ dst, int n)
{
  int idx = blockIdx.x * 256 + threadIdx.x;
  if (idx < n) dst[idx] = f2b(src[idx]);
}

__global__ void embed_kernel(const int* __restrict__ x, const float* __restrict__ embed,
                             float* __restrict__ h)
{
  int idx = blockIdx.x * 256 + threadIdx.x;
  if (idx < TT * DD) {
    int t = idx / DD, d = idx % DD;
    h[idx] = embed[(size_t)x[t] * DD + d];
  }
}

// ---------------- launcher ----------------
extern "C" void kernel_launch(void* const* d_in, const int* in_sizes, int n_in,
                              void* d_out, int out_size, void* d_ws, size_t ws_size,
                              hipStream_t stream)
{
  const int*   x        = (const int*)  d_in[0];
  const float* embed    = (const float*)d_in[1];
  const float* ln_w     = (const float*)d_in[2];
  const float* Wr       = (const float*)d_in[3];
  const float* Wk       = (const float*)d_in[4];
  const float* Wv       = (const float*)d_in[5];
  const float* Wg       = (const float*)d_in[6];
  const float* Ww       = (const float*)d_in[7];
  const float* w_bias   = (const float*)d_in[8];
  const float* u        = (const float*)d_in[9];
  const float* gn_w     = (const float*)d_in[10];
  const float* gn_b     = (const float*)d_in[11];
  const float* Wo       = (const float*)d_in[12];
  const float* W_in     = (const float*)d_in[13];
  const float* conv_w   = (const float*)d_in[14];
  const float* conv_b   = (const float*)d_in[15];
  const float* dt_bias  = (const float*)d_in[16];
  const float* A_log    = (const float*)d_in[17];
  const float* Dp       = (const float*)d_in[18];
  const float* mn_w     = (const float*)d_in[19];
  const float* W_out    = (const float*)d_in[20];
  const float* gw       = (const float*)d_in[21];
  const float* gb       = (const float*)d_in[22];
  const float* ffn_ln_w = (const float*)d_in[23];
  const float* ffn_w1   = (const float*)d_in[24];
  const float* ffn_w2   = (const float*)d_in[25];
  const float* ln_out_w = (const float*)d_in[26];

  char* base = (char*)d_ws;
  size_t off = 0;
  auto alloc = [&](size_t bytes) { off = (off + 255) & ~(size_t)255; void* p = base + off; off += bytes; return p; };

  float* h    = (float*)alloc((size_t)TT * DD * 4);
  float* PZ   = (float*)alloc((size_t)TT * PZS * 4);
  float* yb   = (float*)alloc((size_t)TT * DI * 4);
  float* so   = (float*)alloc((size_t)TT * DD * 4);
  float* orb  = (float*)alloc((size_t)TT * DD * 4);
  float* omb  = (float*)alloc((size_t)TT * DD * 4);
  float* rPb  = (float*)alloc((size_t)TT * DD * 4);
  float* Ccb  = (float*)alloc((size_t)TT * DI * 4);
  float* MstR = (float*)alloc((size_t)NH * NCH * 4096 * 4);
  float* DcR  = (float*)alloc((size_t)NH * NCH * 64 * 4);
  float* MstM = (float*)alloc((size_t)MH * NCH * 4096 * 4);
  float* DcM  = (float*)alloc((size_t)MH * NCH * 4);
  unsigned short* xnb = (unsigned short*)alloc((size_t)TT * DD * 2);
  unsigned short* gob = (unsigned short*)alloc((size_t)TT * DD * 2);
  unsigned short* ynb = (unsigned short*)alloc((size_t)TT * DI * 2);
  unsigned short* fhb = (unsigned short*)alloc((size_t)TT * 1536 * 2);
  unsigned short* WallT = (unsigned short*)alloc((size_t)NL * PZS * 384 * 2);
  unsigned short* WoT   = (unsigned short*)alloc((size_t)NL * 384 * 384 * 2);
  unsigned short* WoutT = (unsigned short*)alloc((size_t)NL * 384 * 768 * 2);
  unsigned short* F1T   = (unsigned short*)alloc((size_t)NL * 1536 * 384 * 2);
  unsigned short* F2T   = (unsigned short*)alloc((size_t)NL * 384 * 1536 * 2);
  unsigned short* embB  = (unsigned short*)alloc((size_t)NV * DD * 2);
  unsigned* bar = (unsigned*)alloc(32 * 64 * 4);
  (void)ws_size; (void)in_sizes; (void)n_in; (void)out_size;

  dim3 blk(256);
  int gTD = (TT * DD + 255) / 256;

  hipMemsetAsync(bar, 0, 32 * 64 * 4, stream);

  TC10 tc;
  int te = 0;
  auto setjob = [&](int q, const float* src, unsigned short* dst, int K, int N, int Npad,
                    int nx, int ny, size_t sStr, size_t dStr) {
    te += nx * ny;
    tc.j[q] = TCJob{src, dst, K, N, Npad, nx, sStr, dStr, te};
  };
  setjob(0, Wr, WallT + (size_t)0 * 384 * 384, 384, 384, 384, 12, 12, (size_t)384 * 384, (size_t)PZS * 384);
  setjob(1, Wk, WallT + (size_t)1 * 384 * 384, 384, 384, 384, 12, 12, (size_t)384 * 384, (size_t)PZS * 384);
  setjob(2, Wv, WallT + (size_t)2 * 384 * 384, 384, 384, 384, 12, 12, (size_t)384 * 384, (size_t)PZS * 384);
  setjob(3, Wg, WallT + (size_t)3 * 384 * 384, 384, 384, 384, 12, 12, (size_t)384 * 384, (size_t)PZS * 384);
  setjob(4, Ww, WallT + (size_t)4 * 384 * 384, 384, 384, 384, 12, 12, (size_t)384 * 384, (size_t)PZS * 384);
  setjob(5, W_in, WallT + (size_t)1920 * 384, 384, XDIM, 1792, 56, 12, (size_t)384 * XDIM, (size_t)PZS * 384);
  setjob(6, Wo, WoT, 384, 384, 384, 12, 12, (size_t)384 * 384, (size_t)384 * 384);
  setjob(7, W_out, WoutT, 768, 384, 384, 12, 24, (size_t)768 * 384, (size_t)384 * 768);
  setjob(8, ffn_w1, F1T, 384, 1536, 1536, 48, 12, (size_t)384 * 1536, (size_t)1536 * 384);
  setjob(9, ffn_w2, F2T, 1536, 384, 384, 12, 48, (size_t)1536 * 384, (size_t)384 * 1536);
  transconv_all<<<dim3(te, 8), blk, 0, stream>>>(tc);
  conv_b16_kernel<<<(NV * DD + 255) / 256, blk, 0, stream>>>(embed, embB, NV * DD);
  embed_kernel<<<gTD, blk, 0, stream>>>(x, embed, h);

  mega_kernel<<<MGRID, blk, 0, stream>>>(
      ln_w, u, w_bias, conv_w, conv_b, dt_bias, A_log, Dp, mn_w,
      gn_w, gn_b, gw, gb, ffn_ln_w, ln_out_w,
      WallT, WoT, WoutT, F1T, F2T,
      h, PZ, yb, so, orb, omb, rPb, Ccb, MstR, DcR, MstM, DcM,
      xnb, gob, ynb, fhb, bar);

  gemm128<<<dim3(250, 8), blk, 0, stream>>>(
      xnb, embB, (float*)d_out, NV, 384, NV);
}

// Round 9
// 1911.324 us; speedup vs baseline: 5.9965x; 5.9965x over previous
//
#include <hip/hip_runtime.h>
#include <math.h>

#define TT 1024
#define DD 384
#define NH 6
#define DI 768
#define MH 12
#define DS 64
#define NL 8
#define XDIM 1676   // 2*DI + 2*DS + MH
#define CONVC 896   // DI + 2*DS
#define NV 32000
#define PZS 3712    // fused output width: [r|k|v|g|w](1920) + [z|xBC|dt](1792 padded)
#define G_OFF 1152
#define W_OFF 1536
#define Z_OFF 1920
#define XBC_OFF 2688   // Z_OFF + DI
#define DT_OFF 3584    // Z_OFF + 1664
#define CHK 32      // scan chunk length
#define NCH 32      // number of chunks

typedef __attribute__((ext_vector_type(8))) short short8;
typedef __attribute__((ext_vector_type(4))) float f32x4;

// ---------------- helpers ----------------
__device__ __forceinline__ float siluf(float x) { return x / (1.f + expf(-x)); }
__device__ __forceinline__ float sigmoidf_(float x) { return 1.f / (1.f + expf(-x)); }
__device__ __forceinline__ float geluf(float x) {
  return 0.5f * x * (1.f + erff(x * 0.70710678118654752440f));
}
__device__ __forceinline__ unsigned short f2b(float x) {
  union { float f; unsigned int u; } v; v.f = x;
  unsigned int r = v.u + 0x7fffu + ((v.u >> 16) & 1u);
  return (unsigned short)(r >> 16);
}

#define GLDS(gp, lp) __builtin_amdgcn_global_load_lds( \
    (const __attribute__((address_space(1))) void*)(gp), \
    (__attribute__((address_space(3))) void*)(lp), 16, 0, 0)

// ---------------- A-resident GEMM core: A in LDS [64][384] swizzled, B staged per 64-step ----------------
__device__ __forceinline__ void gemmA_block(
    const unsigned short* __restrict__ As, unsigned short* Bs,
    const unsigned short* __restrict__ Bt, int Kfull, int n0, int kglob0, int nsteps, int aoff,
    int tid, f32x4 acc[2][2])
{
  int wid = tid >> 6, lane = tid & 63;
  int wr = wid >> 1, wc = wid & 1;
  int r0 = tid >> 3, ch = tid & 7;
  int scs = (ch ^ (r0 & 7)) * 8;
  const unsigned short* gb = Bt + (size_t)(n0 + r0) * Kfull + scs + kglob0;
  size_t row32 = (size_t)32 * Kfull;
  int fr = lane & 15, fc = lane >> 4;
  for (int s = 0; s < nsteps; ++s) {
    int k0 = s * 64;
    GLDS(gb + k0, Bs + wid * 512);
    GLDS(gb + k0 + row32, Bs + 2048 + wid * 512);
    __syncthreads();
    int acol = aoff + k0;
#pragma unroll
    for (int kh = 0; kh < 2; ++kh) {
      short8 af[2], bf[2];
#pragma unroll
      for (int mg = 0; mg < 2; ++mg) {
        int ar = wr * 32 + mg * 16 + fr;
        af[mg] = *reinterpret_cast<const short8*>(&As[ar * 384 + acol + (((kh * 4 + fc) ^ (ar & 7)) * 8)]);
      }
#pragma unroll
      for (int ng = 0; ng < 2; ++ng) {
        int br = wc * 32 + ng * 16 + fr;
        bf[ng] = *reinterpret_cast<const short8*>(&Bs[br * 64 + (((kh * 4 + fc) ^ (br & 7)) * 8)]);
      }
#pragma unroll
      for (int mg = 0; mg < 2; ++mg)
#pragma unroll
        for (int ng = 0; ng < 2; ++ng)
          acc[mg][ng] = __builtin_amdgcn_mfma_f32_16x16x32_bf16(af[mg], bf[ng], acc[mg][ng], 0, 0, 0);
    }
    __syncthreads();
  }
}

// epi: 0 = store f32, 1 = gelu->bf16
__device__ __forceinline__ void epi_store(f32x4 acc[2][2], float* C, unsigned short* Cb,
    int ldC, int m0, int n0, int epi, int tid)
{
  int wid = tid >> 6, lane = tid & 63;
  int wr = wid >> 1, wc = wid & 1;
  int fr = lane & 15, fc = lane >> 4;
#pragma unroll
  for (int mg = 0; mg < 2; ++mg)
#pragma unroll
    for (int ng = 0; ng < 2; ++ng) {
      int col = n0 + wc * 32 + ng * 16 + fr;
#pragma unroll
      for (int j = 0; j < 4; ++j) {
        int row = m0 + wr * 32 + mg * 16 + fc * 4 + j;
        if (epi == 1) Cb[(size_t)row * ldC + col] = f2b(geluf(acc[mg][ng][j]));
        else          C[(size_t)row * ldC + col] = acc[mg][ng][j];
      }
    }
}

// ---------------- standard 64-tile GEMM (A+B staged via GLDS), f32 store ----------------
__device__ __forceinline__ void gemm64_std(
    const unsigned short* __restrict__ A, const unsigned short* __restrict__ Bt,
    float* __restrict__ C, int K, int ldC, int bx, int by,
    unsigned short* As, unsigned short* Bs, int tid)
{
  int wid = tid >> 6, lane = tid & 63;
  int m0 = by * 64, n0 = bx * 64;
  int wr = wid >> 1, wc = wid & 1;
  int r0 = tid >> 3, ch = tid & 7;
  int scs = (ch ^ (r0 & 7)) * 8;
  const unsigned short* ga = A  + (size_t)(m0 + r0) * K + scs;
  const unsigned short* gb = Bt + (size_t)(n0 + r0) * K + scs;
  unsigned short* la = As + wid * 512;
  unsigned short* lb = Bs + wid * 512;
  int fr = lane & 15, fc = lane >> 4;
  f32x4 zz = {0.f, 0.f, 0.f, 0.f};
  f32x4 acc[2][2];
  acc[0][0] = zz; acc[0][1] = zz; acc[1][0] = zz; acc[1][1] = zz;
  size_t row32 = (size_t)32 * K;
  for (int k0 = 0; k0 < K; k0 += 64) {
    GLDS(ga + k0, la);
    GLDS(ga + k0 + row32, la + 2048);
    GLDS(gb + k0, lb);
    GLDS(gb + k0 + row32, lb + 2048);
    __syncthreads();
#pragma unroll
    for (int kh = 0; kh < 2; ++kh) {
      short8 af[2], bf[2];
#pragma unroll
      for (int mg = 0; mg < 2; ++mg) {
        int ar = wr * 32 + mg * 16 + fr;
        af[mg] = *reinterpret_cast<const short8*>(&As[ar * 64 + (((kh * 4 + fc) ^ (ar & 7)) * 8)]);
      }
#pragma unroll
      for (int ng = 0; ng < 2; ++ng) {
        int br = wc * 32 + ng * 16 + fr;
        bf[ng] = *reinterpret_cast<const short8*>(&Bs[br * 64 + (((kh * 4 + fc) ^ (br & 7)) * 8)]);
      }
#pragma unroll
      for (int mg = 0; mg < 2; ++mg)
#pragma unroll
        for (int ng = 0; ng < 2; ++ng)
          acc[mg][ng] = __builtin_amdgcn_mfma_f32_16x16x32_bf16(af[mg], bf[ng], acc[mg][ng], 0, 0, 0);
    }
    __syncthreads();
  }
#pragma unroll
  for (int mg = 0; mg < 2; ++mg)
#pragma unroll
    for (int ng = 0; ng < 2; ++ng) {
      int col = n0 + wc * 32 + ng * 16 + fr;
#pragma unroll
      for (int j = 0; j < 4; ++j) {
        int row = m0 + wr * 32 + mg * 16 + fc * 4 + j;
        C[(size_t)row * ldC + col] = acc[mg][ng][j];
      }
    }
}

// ---------------- K1: fused RMSNorm + projection GEMM -> PZ ----------------
__global__ __launch_bounds__(256) void proj_kernel(
    const float* __restrict__ hin, const float* __restrict__ lnw,
    const unsigned short* __restrict__ WallT_i, float* __restrict__ PZ)
{
  __shared__ unsigned short As[64 * 384];
  __shared__ unsigned short Bs[4096];
  int tid = threadIdx.x;
  int m0 = blockIdx.y * 64, n0 = blockIdx.x * 64;
  int r = tid >> 2, q = tid & 3;
  const float* hr = hin + (size_t)(m0 + r) * DD + q * 96;
  float ss = 0.f;
#pragma unroll 4
  for (int j = 0; j < 96; j += 4) {
    float4 x = *(const float4*)(hr + j);
    ss += x.x * x.x + x.y * x.y + x.z * x.z + x.w * x.w;
  }
  ss += __shfl_xor(ss, 1); ss += __shfl_xor(ss, 2);
  float scale = rsqrtf(ss * (1.f / DD) + 1e-6f);
  const float* wq = lnw + q * 96;
#pragma unroll
  for (int g = 0; g < 12; ++g) {
    int gi = q * 12 + g;
    int kb = gi >> 3, c = gi & 7;
    float4 a = *(const float4*)(hr + g * 8);
    float4 b2 = *(const float4*)(hr + g * 8 + 4);
    unsigned short tmp[8];
    tmp[0] = f2b(wq[g*8+0] * a.x * scale);  tmp[1] = f2b(wq[g*8+1] * a.y * scale);
    tmp[2] = f2b(wq[g*8+2] * a.z * scale);  tmp[3] = f2b(wq[g*8+3] * a.w * scale);
    tmp[4] = f2b(wq[g*8+4] * b2.x * scale); tmp[5] = f2b(wq[g*8+5] * b2.y * scale);
    tmp[6] = f2b(wq[g*8+6] * b2.z * scale); tmp[7] = f2b(wq[g*8+7] * b2.w * scale);
    *(short8*)(&As[r * 384 + kb * 64 + ((c ^ (r & 7)) * 8)]) = *(short8*)tmp;
  }
  f32x4 zz = {0.f, 0.f, 0.f, 0.f};
  f32x4 acc[2][2];
  acc[0][0] = zz; acc[0][1] = zz; acc[1][0] = zz; acc[1][1] = zz;
  gemmA_block(As, Bs, WallT_i, 384, n0, 0, 6, 0, tid, acc);
  epi_store(acc, PZ, nullptr, PZS, m0, n0, 0, tid);
}

// ---------------- Phase A: per-chunk local scans (decay, dt, conv1d fused) ----------------
__global__ __launch_bounds__(256) void scanA_kernel(
    const float* __restrict__ PZ, const float* __restrict__ u, const float* __restrict__ wbias,
    float* __restrict__ so, float* __restrict__ rPb,
    float* __restrict__ MstR, float* __restrict__ DcR,
    const float* __restrict__ cw, const float* __restrict__ cbia,
    const float* __restrict__ dtbias,
    const float* __restrict__ Alog, const float* __restrict__ Dpw,
    float* __restrict__ yb, float* __restrict__ Ccb,
    float* __restrict__ MstM, float* __restrict__ DcM)
{
  __shared__ float smem[2 * 256 + 64];
  int b = blockIdx.x, tid = threadIdx.x;
  if (b < 192) {
    int h = b >> 5, c = b & 31;
    float* sbuf = smem; float* us = smem + 512;
    if (tid < 64) us[tid] = u[h * 64 + tid];
    int wv = tid >> 6, l = tid & 63;
    int vv = wv * 16 + (l & 15);
    int kc = l >> 4;
    int arr = tid >> 6, idx = tid & 63;
    int off = (arr == 0) ? 0 : (arr == 1) ? 384 : (arr == 2) ? W_OFF : 768;  // r,k,w(raw),v
    float wb = (arr == 2) ? wbias[h * 64 + idx] : 0.f;
    size_t base = (size_t)h * 64 + idx + off;
    int t0 = c * CHK;
    float S[16], Pc[16];
#pragma unroll
    for (int i = 0; i < 16; i++) { S[i] = 0.f; Pc[i] = 1.f; }
    float reg = PZ[(size_t)t0 * PZS + base];
    bool st = (wv == 0) && ((l & 15) == 0);
    for (int t = 0; t < CHK; ++t) {
      int tt = t0 + t;
      float* cb = sbuf + (t & 1) * 256;
      cb[arr * 64 + idx] = (arr == 2) ? expf(-expf(reg + wb)) : reg;
      if (t + 1 < CHK) reg = PZ[(size_t)(tt + 1) * PZS + base];
      __syncthreads();
      float vt = cb[192 + vv];
      float acc = 0.f;
      float rp[16];
#pragma unroll
      for (int i = 0; i < 16; ++i) {
        int kk = kc * 16 + i;
        float rv = cb[kk], kv = cb[64 + kk], dv = cb[128 + kk];
        rp[i] = rv * Pc[i];
        float kvv = kv * vt;
        acc = fmaf(rv, fmaf(us[kk], kvv, S[i]), acc);
        S[i] = fmaf(dv, S[i], kvv);
        Pc[i] *= dv;
      }
      acc += __shfl_xor(acc, 16);
      acc += __shfl_xor(acc, 32);
      if (l < 16) so[(size_t)tt * DD + h * 64 + vv] = acc;
      if (st) {
        float4* dst = (float4*)&rPb[(size_t)tt * DD + h * 64 + kc * 16];
        dst[0] = make_float4(rp[0], rp[1], rp[2], rp[3]);
        dst[1] = make_float4(rp[4], rp[5], rp[6], rp[7]);
        dst[2] = make_float4(rp[8], rp[9], rp[10], rp[11]);
        dst[3] = make_float4(rp[12], rp[13], rp[14], rp[15]);
      }
    }
    float* ms = MstR + (size_t)(h * NCH + c) * 4096;   // [v][k]
    float4* msv = (float4*)&ms[vv * 64 + kc * 16];
    msv[0] = make_float4(S[0], S[1], S[2], S[3]);
    msv[1] = make_float4(S[4], S[5], S[6], S[7]);
    msv[2] = make_float4(S[8], S[9], S[10], S[11]);
    msv[3] = make_float4(S[12], S[13], S[14], S[15]);
    if (st) {
      float4* dd_ = (float4*)&DcR[(h * NCH + c) * 64 + kc * 16];
      dd_[0] = make_float4(Pc[0], Pc[1], Pc[2], Pc[3]);
      dd_[1] = make_float4(Pc[4], Pc[5], Pc[6], Pc[7]);
      dd_[2] = make_float4(Pc[8], Pc[9], Pc[10], Pc[11]);
      dd_[3] = make_float4(Pc[12], Pc[13], Pc[14], Pc[15]);
    }
  } else {
    int bb = b - 192;
    int hh = bb >> 5, c = bb & 31;
    float* sbuf = smem;
    int wv = tid >> 6, l = tid & 63;
    int p = wv * 16 + (l & 15);
    int sc = l >> 4;
    int arr = tid >> 6, idx = tid & 63;
    float A = -expf(Alog[hh]);
    float Dph = Dpw[hh];
    float dtbh = dtbias[hh];
    int t0 = c * CHK;
    float cw0 = 0.f, cw1 = 0.f, cw2 = 0.f, cw3 = 0.f, cbv = 0.f;
    float xw0 = 0.f, xw1 = 0.f, xw2 = 0.f, cur = 0.f;
    const float* xcol = nullptr;
    float reg = 0.f;
    if (arr < 3) {
      int chn = (arr == 0) ? (hh * 64 + idx) : (arr == 1) ? (DI + idx) : (DI + DS + idx);
      cw0 = cw[chn * 4 + 0]; cw1 = cw[chn * 4 + 1]; cw2 = cw[chn * 4 + 2]; cw3 = cw[chn * 4 + 3];
      cbv = cbia[chn];
      xcol = PZ + XBC_OFF + chn;
      xw0 = (t0 >= 3) ? xcol[(size_t)(t0 - 3) * PZS] : 0.f;
      xw1 = (t0 >= 2) ? xcol[(size_t)(t0 - 2) * PZS] : 0.f;
      xw2 = (t0 >= 1) ? xcol[(size_t)(t0 - 1) * PZS] : 0.f;
      cur = xcol[(size_t)t0 * PZS];
    } else {
      reg = PZ[(size_t)t0 * PZS + DT_OFF + hh];
    }
    float S[16]; float cdA = 1.f;
#pragma unroll
    for (int i = 0; i < 16; i++) S[i] = 0.f;
    bool st = (wv == 0) && ((l & 15) == 0);
    for (int t = 0; t < CHK; ++t) {
      int tt = t0 + t;
      float* cb = sbuf + (t & 1) * 256;
      if (arr < 3) {
        float cvv = fmaf(cw3, cur, fmaf(cw2, xw2, fmaf(cw1, xw1, fmaf(cw0, xw0, cbv))));
        cb[arr * 64 + idx] = siluf(cvv);
        float nx = (t + 1 < CHK) ? xcol[(size_t)(tt + 1) * PZS] : 0.f;
        xw0 = xw1; xw1 = xw2; xw2 = cur; cur = nx;
      } else {
        if (idx == 0) {
          float v = reg + dtbh;
          cb[192] = (v > 20.f) ? v : log1pf(expf(v));
        }
        if (t + 1 < CHK) reg = PZ[(size_t)(tt + 1) * PZS + DT_OFF + hh];
      }
      __syncthreads();
      float dt_ = cb[192];
      float dA = expf(dt_ * A);
      cdA *= dA;
      float xp = cb[p];
      float dtx = dt_ * xp;
      float acc = 0.f;
#pragma unroll
      for (int i = 0; i < 16; ++i) {
        int s = sc * 16 + i;
        S[i] = fmaf(dA, S[i], dtx * cb[64 + s]);
        acc = fmaf(S[i], cb[128 + s], acc);
      }
      acc += __shfl_xor(acc, 16);
      acc += __shfl_xor(acc, 32);
      if (l < 16) yb[(size_t)tt * DI + hh * 64 + p] = fmaf(Dph, xp, acc);
      if (st) {
        float4* dst = (float4*)&Ccb[(size_t)tt * DI + hh * 64 + sc * 16];
#pragma unroll
        for (int j4 = 0; j4 < 4; ++j4)
          dst[j4] = make_float4(cdA * cb[128 + sc * 16 + j4 * 4 + 0],
                                cdA * cb[128 + sc * 16 + j4 * 4 + 1],
                                cdA * cb[128 + sc * 16 + j4 * 4 + 2],
                                cdA * cb[128 + sc * 16 + j4 * 4 + 3]);
      }
    }
    float* ms = MstM + (size_t)(hh * NCH + c) * 4096;  // [p][s]
    float4* msv = (float4*)&ms[p * 64 + sc * 16];
    msv[0] = make_float4(S[0], S[1], S[2], S[3]);
    msv[1] = make_float4(S[4], S[5], S[6], S[7]);
    msv[2] = make_float4(S[8], S[9], S[10], S[11]);
    msv[3] = make_float4(S[12], S[13], S[14], S[15]);
    if (tid == 0) DcM[hh * NCH + c] = cdA;
  }
}

// ---------------- Phase C: prefix-combine + output correction (+ fused RWKV groupnorm*silu) ----------------
__global__ __launch_bounds__(256) void corr_kernel(
    const float* __restrict__ MstR, const float* __restrict__ DcR,
    const float* __restrict__ rPb, const float* __restrict__ so,
    const float* __restrict__ MstM, const float* __restrict__ DcM,
    const float* __restrict__ Ccb, float* __restrict__ yb,
    const float* __restrict__ PZ, const float* __restrict__ gnw, const float* __restrict__ gnb,
    unsigned short* __restrict__ gob)
{
  __shared__ float S0l[64 * 68];
  __shared__ float Rl[CHK * 68];
  int b = blockIdx.x, tid = threadIdx.x;
  const float* rg; int ostride, obase, t0;
  bool rwkv = (b < 192);
  int h, cidx;
  if (rwkv) {
    h = b >> 5; cidx = b & 31;
    rg = rPb; obase = h * 64; ostride = DD;
  } else {
    int bb = b - 192; h = bb >> 5; cidx = bb & 31;
    rg = Ccb; obase = h * 64; ostride = DI;
  }
  t0 = cidx * CHK;
  float Sreg[16];
#pragma unroll
  for (int it = 0; it < 16; ++it) Sreg[it] = 0.f;
  if (rwkv) {
    int kk = tid & 63;
    for (int cp = 0; cp < cidx; ++cp) {
      float d = DcR[(h * NCH + cp) * 64 + kk];
      const float* mb = MstR + (size_t)(h * NCH + cp) * 4096;
#pragma unroll
      for (int it = 0; it < 16; ++it)
        Sreg[it] = fmaf(d, Sreg[it], mb[tid + 256 * it]);
    }
  } else {
    for (int cp = 0; cp < cidx; ++cp) {
      float d = DcM[h * NCH + cp];
      const float* mb = MstM + (size_t)(h * NCH + cp) * 4096;
#pragma unroll
      for (int it = 0; it < 16; ++it)
        Sreg[it] = fmaf(d, Sreg[it], mb[tid + 256 * it]);
    }
  }
#pragma unroll
  for (int it = 0; it < 16; ++it) {
    int gi = tid + 256 * it;
    S0l[(gi & 63) * 68 + (gi >> 6)] = Sreg[it];
  }
  {
    int t = tid >> 3, q = (tid & 7) * 8;
    const float4* src = (const float4*)&rg[(size_t)(t0 + t) * ostride + obase + q];
    float4* dst = (float4*)&Rl[t * 68 + q];
    dst[0] = src[0]; dst[1] = src[1];
  }
  __syncthreads();
  int t = tid >> 3, q = (tid & 7) * 8;
  float acc[8];
#pragma unroll
  for (int j = 0; j < 8; j++) acc[j] = 0.f;
  for (int k = 0; k < 64; ++k) {
    float rv = Rl[t * 68 + k];
    const float4* sp = (const float4*)&S0l[k * 68 + q];
    float4 s0 = sp[0], s1 = sp[1];
    acc[0] = fmaf(rv, s0.x, acc[0]);
    acc[1] = fmaf(rv, s0.y, acc[1]);
    acc[2] = fmaf(rv, s0.z, acc[2]);
    acc[3] = fmaf(rv, s0.w, acc[3]);
    acc[4] = fmaf(rv, s1.x, acc[4]);
    acc[5] = fmaf(rv, s1.y, acc[5]);
    acc[6] = fmaf(rv, s1.z, acc[6]);
    acc[7] = fmaf(rv, s1.w, acc[7]);
  }
  if (!rwkv) {
    float4* op = (float4*)&yb[(size_t)(t0 + t) * DI + obase + q];
    float4 c0 = op[0], c1 = op[1];
    c0.x += acc[0]; c0.y += acc[1]; c0.z += acc[2]; c0.w += acc[3];
    c1.x += acc[4]; c1.y += acc[5]; c1.z += acc[6]; c1.w += acc[7];
    op[0] = c0; op[1] = c1;
  } else {
    float ov[8];
    const float4* sp = (const float4*)&so[(size_t)(t0 + t) * DD + obase + q];
    float4 s0 = sp[0], s1 = sp[1];
    ov[0] = s0.x + acc[0]; ov[1] = s0.y + acc[1]; ov[2] = s0.z + acc[2]; ov[3] = s0.w + acc[3];
    ov[4] = s1.x + acc[4]; ov[5] = s1.y + acc[5]; ov[6] = s1.z + acc[6]; ov[7] = s1.w + acc[7];
    float m_ = 0.f;
#pragma unroll
    for (int j = 0; j < 8; j++) m_ += ov[j];
    m_ += __shfl_xor(m_, 1); m_ += __shfl_xor(m_, 2); m_ += __shfl_xor(m_, 4);
    float mu = m_ * (1.f / 64.f);
    float vv = 0.f;
#pragma unroll
    for (int j = 0; j < 8; j++) { float d = ov[j] - mu; vv = fmaf(d, d, vv); }
    vv += __shfl_xor(vv, 1); vv += __shfl_xor(vv, 2); vv += __shfl_xor(vv, 4);
    float rstd = rsqrtf(vv * (1.f / 64.f) + 1e-5f);
#pragma unroll
    for (int j = 0; j < 8; j++) {
      int d = obase + q + j;
      float gv = PZ[(size_t)(t0 + t) * PZS + G_OFF + d];
      float o = fmaf((ov[j] - mu) * rstd, gnw[d], gnb[d]) * siluf(gv);
      gob[(size_t)(t0 + t) * DD + d] = f2b(o);
    }
  }
}

// ---------------- K4: Wo GEMM (std) + fused mamba_norm + Wout GEMM ----------------
__global__ __launch_bounds__(256) void wo_wout_kernel(
    const unsigned short* __restrict__ gob, const unsigned short* __restrict__ WoT_i,
    float* __restrict__ orb_,
    const float* __restrict__ yb, const float* __restrict__ PZ, const float* __restrict__ mnw,
    const unsigned short* __restrict__ WoutT_i, float* __restrict__ omb_)
{
  __shared__ unsigned short As[64 * 384];
  __shared__ unsigned short Bs[4096];
  int tid = threadIdx.x;
  int b = blockIdx.x;
  if (b < 96) {
    gemm64_std(gob, WoT_i, orb_, 384, 384, b % 6, b / 6, As, Bs, tid);
    return;
  }
  int t = b - 96;
  int bx = t % 6, by = t / 6;
  int m0 = by * 64, n0 = bx * 64;
  int r = tid >> 2, q = tid & 3;
  int row = m0 + r;
  float ss = 0.f;
  {
    const float* py = yb + (size_t)row * DI + q * 192;
    const float* pz = PZ + (size_t)row * PZS + Z_OFF + q * 192;
#pragma unroll 4
    for (int j = 0; j < 192; j += 4) {
      float4 y4 = *(const float4*)(py + j);
      float4 z4 = *(const float4*)(pz + j);
      float v0 = y4.x * siluf(z4.x), v1 = y4.y * siluf(z4.y);
      float v2 = y4.z * siluf(z4.z), v3 = y4.w * siluf(z4.w);
      ss += v0 * v0 + v1 * v1 + v2 * v2 + v3 * v3;
    }
  }
  ss += __shfl_xor(ss, 1); ss += __shfl_xor(ss, 2);
  float scale = rsqrtf(ss * (1.f / DI) + 1e-6f);
  f32x4 zz = {0.f, 0.f, 0.f, 0.f};
  f32x4 acc[2][2];
  acc[0][0] = zz; acc[0][1] = zz; acc[1][0] = zz; acc[1][1] = zz;
  for (int half = 0; half < 2; ++half) {
    const float* py = yb + (size_t)row * DI + half * 384 + q * 96;
    const float* pz = PZ + (size_t)row * PZS + Z_OFF + half * 384 + q * 96;
    const float* pw = mnw + half * 384 + q * 96;
#pragma unroll
    for (int g = 0; g < 12; ++g) {
      int gi = q * 12 + g;
      int kb = gi >> 3, c = gi & 7;
      float4 y0 = *(const float4*)(py + g * 8);
      float4 y1 = *(const float4*)(py + g * 8 + 4);
      float4 z0 = *(const float4*)(pz + g * 8);
      float4 z1 = *(const float4*)(pz + g * 8 + 4);
      unsigned short tmp[8];
      tmp[0] = f2b(y0.x * siluf(z0.x) * scale * pw[g*8+0]);
      tmp[1] = f2b(y0.y * siluf(z0.y) * scale * pw[g*8+1]);
      tmp[2] = f2b(y0.z * siluf(z0.z) * scale * pw[g*8+2]);
      tmp[3] = f2b(y0.w * siluf(z0.w) * scale * pw[g*8+3]);
      tmp[4] = f2b(y1.x * siluf(z1.x) * scale * pw[g*8+4]);
      tmp[5] = f2b(y1.y * siluf(z1.y) * scale * pw[g*8+5]);
      tmp[6] = f2b(y1.z * siluf(z1.z) * scale * pw[g*8+6]);
      tmp[7] = f2b(y1.w * siluf(z1.w) * scale * pw[g*8+7]);
      *(short8*)(&As[r * 384 + kb * 64 + ((c ^ (r & 7)) * 8)]) = *(short8*)tmp;
    }
    gemmA_block(As, Bs, WoutT_i, 768, n0, half * 384, 6, 0, tid, acc);
  }
  epi_store(acc, omb_, nullptr, 384, m0, n0, 0, tid);
}

// ---------------- K5: fused gate+residual+FFN-RMSNorm + FFN1 GEMM (gelu->bf16) ----------------
__global__ __launch_bounds__(256) void ffn1_kernel(
    const float* __restrict__ orb_, const float* __restrict__ omb_,
    const float* __restrict__ gwv, const float* __restrict__ gbv,
    const float* __restrict__ hin, float* __restrict__ hmid,
    const float* __restrict__ flnw, const unsigned short* __restrict__ F1T_i,
    unsigned short* __restrict__ fhb)
{
  __shared__ unsigned short As[64 * 384];
  __shared__ unsigned short Bs[4096];
  int tid = threadIdx.x;
  int m0 = blockIdx.y * 64, n0 = blockIdx.x * 64;
  int r = tid >> 2, q = tid & 3;
  size_t rb = (size_t)(m0 + r) * DD + q * 96;
  const float* pr = orb_ + rb;
  const float* pm = omb_ + rb;
  const float* ph = hin + rb;
  float* po = hmid + rb;
  const float* g1 = gwv + q * 96;
  const float* g2 = gwv + DD + q * 96;
  float ss = 0.f;
#pragma unroll 4
  for (int j = 0; j < 96; j += 4) {
    float4 a = *(const float4*)(pr + j), b2 = *(const float4*)(pm + j);
    float4 w1 = *(const float4*)(g1 + j), w2 = *(const float4*)(g2 + j);
    ss += a.x * w1.x + a.y * w1.y + a.z * w1.z + a.w * w1.w
        + b2.x * w2.x + b2.y * w2.y + b2.z * w2.z + b2.w * w2.w;
  }
  ss += __shfl_xor(ss, 1); ss += __shfl_xor(ss, 2);
  float gate = sigmoidf_(ss + gbv[0]);
  float ss2 = 0.f;
#pragma unroll 4
  for (int j = 0; j < 96; j += 4) {
    float4 a = *(const float4*)(pr + j), b2 = *(const float4*)(pm + j), hh = *(const float4*)(ph + j);
    float4 hn;
    hn.x = hh.x + gate * a.x + (1.f - gate) * b2.x;
    hn.y = hh.y + gate * a.y + (1.f - gate) * b2.y;
    hn.z = hh.z + gate * a.z + (1.f - gate) * b2.z;
    hn.w = hh.w + gate * a.w + (1.f - gate) * b2.w;
    *(float4*)(po + j) = hn;
    ss2 += hn.x * hn.x + hn.y * hn.y + hn.z * hn.z + hn.w * hn.w;
  }
  ss2 += __shfl_xor(ss2, 1); ss2 += __shfl_xor(ss2, 2);
  float scale = rsqrtf(ss2 * (1.f / DD) + 1e-6f);
  const float* wq = flnw + q * 96;
#pragma unroll
  for (int g = 0; g < 12; ++g) {
    int gi = q * 12 + g;
    int kb = gi >> 3, c = gi & 7;
    float4 a = *(const float4*)(po + g * 8);
    float4 b2 = *(const float4*)(po + g * 8 + 4);
    unsigned short tmp[8];
    tmp[0] = f2b(wq[g*8+0] * a.x * scale);  tmp[1] = f2b(wq[g*8+1] * a.y * scale);
    tmp[2] = f2b(wq[g*8+2] * a.z * scale);  tmp[3] = f2b(wq[g*8+3] * a.w * scale);
    tmp[4] = f2b(wq[g*8+4] * b2.x * scale); tmp[5] = f2b(wq[g*8+5] * b2.y * scale);
    tmp[6] = f2b(wq[g*8+6] * b2.z * scale); tmp[7] = f2b(wq[g*8+7] * b2.w * scale);
    *(short8*)(&As[r * 384 + kb * 64 + ((c ^ (r & 7)) * 8)]) = *(short8*)tmp;
  }
  f32x4 zz = {0.f, 0.f, 0.f, 0.f};
  f32x4 acc[2][2];
  acc[0][0] = zz; acc[0][1] = zz; acc[1][0] = zz; acc[1][1] = zz;
  gemmA_block(As, Bs, F1T_i, 384, n0, 0, 6, 0, tid, acc);
  epi_store(acc, nullptr, fhb, 1536, m0, n0, 1, tid);
}

// ---------------- FFN2: 64-tile GEMM, split-K via gridDim.z, atomic-add into h ----------------
__global__ __launch_bounds__(256) void ffn2_kernel(
    const unsigned short* __restrict__ A, const unsigned short* __restrict__ Bt,
    float* __restrict__ C, int N, int K, int ldC)
{
  __shared__ unsigned short As[4096];
  __shared__ unsigned short Bs[4096];
  int tid = threadIdx.x;
  int wid = tid >> 6, lane = tid & 63;
  int m0 = blockIdx.y * 64, n0 = blockIdx.x * 64;
  int wr = wid >> 1, wc = wid & 1;
  int r0 = tid >> 3, ch = tid & 7;
  int scs = (ch ^ (r0 & 7)) * 8;
  const unsigned short* ga = A  + (size_t)(m0 + r0) * K + scs;
  const unsigned short* gb = Bt + (size_t)(n0 + r0) * K + scs;
  unsigned short* la = As + wid * 512;
  unsigned short* lb = Bs + wid * 512;
  int fr = lane & 15, fc = lane >> 4;
  f32x4 zz = {0.f, 0.f, 0.f, 0.f};
  f32x4 acc[2][2];
  acc[0][0] = zz; acc[0][1] = zz; acc[1][0] = zz; acc[1][1] = zz;
  int kper = K / (int)gridDim.z;
  int ks = blockIdx.z * kper, ke = ks + kper;
  size_t row32 = (size_t)32 * K;
  for (int k0 = ks; k0 < ke; k0 += 64) {
    GLDS(ga + k0, la);
    GLDS(ga + k0 + row32, la + 2048);
    GLDS(gb + k0, lb);
    GLDS(gb + k0 + row32, lb + 2048);
    __syncthreads();
#pragma unroll
    for (int kh = 0; kh < 2; ++kh) {
      short8 af[2], bf[2];
#pragma unroll
      for (int mg = 0; mg < 2; ++mg) {
        int ar = wr * 32 + mg * 16 + fr;
        af[mg] = *reinterpret_cast<const short8*>(&As[ar * 64 + (((kh * 4 + fc) ^ (ar & 7)) * 8)]);
      }
#pragma unroll
      for (int ng = 0; ng < 2; ++ng) {
        int br = wc * 32 + ng * 16 + fr;
        bf[ng] = *reinterpret_cast<const short8*>(&Bs[br * 64 + (((kh * 4 + fc) ^ (br & 7)) * 8)]);
      }
#pragma unroll
      for (int mg = 0; mg < 2; ++mg)
#pragma unroll
        for (int ng = 0; ng < 2; ++ng)
          acc[mg][ng] = __builtin_amdgcn_mfma_f32_16x16x32_bf16(af[mg], bf[ng], acc[mg][ng], 0, 0, 0);
    }
    __syncthreads();
  }
#pragma unroll
  for (int mg = 0; mg < 2; ++mg)
#pragma unroll
    for (int ng = 0; ng < 2; ++ng) {
      int col = n0 + wc * 32 + ng * 16 + fr;
#pragma unroll
      for (int j = 0; j < 4; ++j) {
        int row = m0 + wr * 32 + mg * 16 + fc * 4 + j;
        atomicAdd(&C[(size_t)row * ldC + col], acc[mg][ng][j]);
      }
    }
}

// ---------------- 128-tile bf16 MFMA GEMM (logits), BK=64 ----------------
__global__ __launch_bounds__(256) void gemm128(
    const unsigned short* __restrict__ A, const unsigned short* __restrict__ Bt,
    float* __restrict__ C, int N, int K, int ldC)
{
  __shared__ unsigned short As[8192];   // [128][64]
  __shared__ unsigned short Bs[8192];
  int tid = threadIdx.x;
  int wid = tid >> 6, lane = tid & 63;
  int m0 = blockIdx.y * 128, n0 = blockIdx.x * 128;
  int wr = wid >> 1, wc = wid & 1;
  int r0 = tid >> 3, ch = tid & 7;
  int scs = (ch ^ (r0 & 7)) * 8;
  const unsigned short* ga = A  + (size_t)(m0 + r0) * K + scs;
  const unsigned short* gb = Bt + (size_t)(n0 + r0) * K + scs;
  int fr = lane & 15, fc = lane >> 4;
  f32x4 zz = {0.f, 0.f, 0.f, 0.f};
  f32x4 acc[4][4];
#pragma unroll
  for (int i = 0; i < 4; i++)
#pragma unroll
    for (int j = 0; j < 4; j++) acc[i][j] = zz;

  size_t row32 = (size_t)32 * K;
  for (int k0 = 0; k0 < K; k0 += 64) {
#pragma unroll
    for (int i = 0; i < 4; ++i) {
      GLDS(ga + k0 + i * row32, As + i * 2048 + wid * 512);
      GLDS(gb + k0 + i * row32, Bs + i * 2048 + wid * 512);
    }
    __syncthreads();
#pragma unroll
    for (int kh = 0; kh < 2; ++kh) {
      short8 af[4], bf[4];
#pragma unroll
      for (int mg = 0; mg < 4; ++mg) {
        int ar = wr * 64 + mg * 16 + fr;
        af[mg] = *reinterpret_cast<const short8*>(&As[ar * 64 + (((kh * 4 + fc) ^ (ar & 7)) * 8)]);
      }
#pragma unroll
      for (int ng = 0; ng < 4; ++ng) {
        int br = wc * 64 + ng * 16 + fr;
        bf[ng] = *reinterpret_cast<const short8*>(&Bs[br * 64 + (((kh * 4 + fc) ^ (br & 7)) * 8)]);
      }
#pragma unroll
      for (int mg = 0; mg < 4; ++mg)
#pragma unroll
        for (int ng = 0; ng < 4; ++ng)
          acc[mg][ng] = __builtin_amdgcn_mfma_f32_16x16x32_bf16(af[mg], bf[ng], acc[mg][ng], 0, 0, 0);
    }
    __syncthreads();
  }
#pragma unroll
  for (int mg = 0; mg < 4; ++mg)
#pragma unroll
    for (int ng = 0; ng < 4; ++ng) {
      int col = n0 + wc * 64 + ng * 16 + fr;
      if (col < N) {
#pragma unroll
        for (int j = 0; j < 4; ++j) {
          int row = m0 + wr * 64 + mg * 16 + fc * 4 + j;
          C[(size_t)row * ldC + col] = acc[mg][ng][j];
        }
      }
    }
}

// ---------------- merged weight transpose + fp32->bf16 (all jobs, one dispatch) ----------------
struct TCJob { const float* src; unsigned short* dst; int K, N, Npad, nx; size_t sStr, dStr; int tend; };
struct TC10 { TCJob j[10]; };

__global__ __launch_bounds__(256) void transconv_all(TC10 P)
{
  __shared__ float tile[32][33];
  int bid = blockIdx.x;
  int q = 0;
  while (bid >= P.j[q].tend) ++q;
  int tstart = (q == 0) ? 0 : P.j[q - 1].tend;
  TCJob jb = P.j[q];
  int local = bid - tstart;
  int bx = local % jb.nx, by = local / jb.nx;
  const float* src = jb.src + (size_t)blockIdx.y * jb.sStr;
  unsigned short* dst = jb.dst + (size_t)blockIdx.y * jb.dStr;
  int k0 = by * 32, n0 = bx * 32;
  int tx = threadIdx.x & 31, ty = threadIdx.x >> 5;
  for (int i = ty; i < 32; i += 8) {
    int k = k0 + i, n = n0 + tx;
    tile[i][tx] = (k < jb.K && n < jb.N) ? src[(size_t)k * jb.N + n] : 0.f;
  }
  __syncthreads();
  for (int i = ty; i < 32; i += 8) {
    int n = n0 + i, k = k0 + tx;
    if (n < jb.Npad && k < jb.K) dst[(size_t)n * jb.K + k] = f2b(tile[tx][i]);
  }
}

__global__ void conv_b16_kernel(const float* __restrict__ src, unsigned short* __restrict__ dst, int n)
{
  int idx = blockIdx.x * 256 + threadIdx.x;
  if (idx < n) dst[idx] = f2b(src[idx]);
}

__global__ void embed_kernel(const int* __restrict__ x, const float* __restrict__ embed,
                             float* __restrict__ h)
{
  int idx = blockIdx.x * 256 + threadIdx.x;
  if (idx < TT * DD) {
    int t = idx / DD, d = idx % DD;
    h[idx] = embed[(size_t)x[t] * DD + d];
  }
}

// ---------------- final RMSNorm (wave per row) -> bf16 ----------------
__global__ __launch_bounds__(256) void rms_kernel(const float* __restrict__ in,
                                                  const float* __restrict__ w,
                                                  unsigned short* __restrict__ out)
{
  int row = blockIdx.x * 4 + (threadIdx.x >> 6);
  int lane = threadIdx.x & 63;
  const float* r = in + (size_t)row * DD;
  float v[6]; float ss = 0.f;
#pragma unroll
  for (int j = 0; j < 6; ++j) { v[j] = r[lane + j * 64]; ss = fmaf(v[j], v[j], ss); }
#pragma unroll
  for (int s = 1; s < 64; s <<= 1) ss += __shfl_xor(ss, s);
  float scale = rsqrtf(ss * (1.f / DD) + 1e-6f);
#pragma unroll
  for (int j = 0; j < 6; ++j)
    out[(size_t)row * DD + lane + j * 64] = f2b(w[lane + j * 64] * v[j] * scale);
}

// ---------------- launcher ----------------
extern "C" void kernel_launch(void* const* d_in, const int* in_sizes, int n_in,
                              void* d_out, int out_size, void* d_ws, size_t ws_size,
                              hipStream_t stream)
{
  const int*   x        = (const int*)  d_in[0];
  const float* embed    = (const float*)d_in[1];
  const float* ln_w     = (const float*)d_in[2];
  const float* Wr       = (const float*)d_in[3];
  const float* Wk       = (const float*)d_in[4];
  const float* Wv       = (const float*)d_in[5];
  const float* Wg       = (const float*)d_in[6];
  const float* Ww       = (const float*)d_in[7];
  const float* w_bias   = (const float*)d_in[8];
  const float* u        = (const float*)d_in[9];
  const float* gn_w     = (const float*)d_in[10];
  const float* gn_b     = (const float*)d_in[11];
  const float* Wo       = (const float*)d_in[12];
  const float* W_in     = (const float*)d_in[13];
  const float* conv_w   = (const float*)d_in[14];
  const float* conv_b   = (const float*)d_in[15];
  const float* dt_bias  = (const float*)d_in[16];
  const float* A_log    = (const float*)d_in[17];
  const float* Dp       = (const float*)d_in[18];
  const float* mn_w     = (const float*)d_in[19];
  const float* W_out    = (const float*)d_in[20];
  const float* gw       = (const float*)d_in[21];
  const float* gb       = (const float*)d_in[22];
  const float* ffn_ln_w = (const float*)d_in[23];
  const float* ffn_w1   = (const float*)d_in[24];
  const float* ffn_w2   = (const float*)d_in[25];
  const float* ln_out_w = (const float*)d_in[26];

  char* base = (char*)d_ws;
  size_t off = 0;
  auto alloc = [&](size_t bytes) { off = (off + 255) & ~(size_t)255; void* p = base + off; off += bytes; return p; };

  float* hb0  = (float*)alloc((size_t)TT * DD * 4);
  float* hb1  = (float*)alloc((size_t)TT * DD * 4);
  float* PZ   = (float*)alloc((size_t)TT * PZS * 4);
  float* yb   = (float*)alloc((size_t)TT * DI * 4);
  float* so   = (float*)alloc((size_t)TT * DD * 4);
  float* orb  = (float*)alloc((size_t)TT * DD * 4);
  float* omb  = (float*)alloc((size_t)TT * DD * 4);
  float* rPb  = (float*)alloc((size_t)TT * DD * 4);
  float* Ccb  = (float*)alloc((size_t)TT * DI * 4);
  float* MstR = (float*)alloc((size_t)NH * NCH * 4096 * 4);
  float* DcR  = (float*)alloc((size_t)NH * NCH * 64 * 4);
  float* MstM = (float*)alloc((size_t)MH * NCH * 4096 * 4);
  float* DcM  = (float*)alloc((size_t)MH * NCH * 4);
  unsigned short* xnb = (unsigned short*)alloc((size_t)TT * DD * 2);
  unsigned short* gob = (unsigned short*)alloc((size_t)TT * DD * 2);
  unsigned short* fhb = (unsigned short*)alloc((size_t)TT * 1536 * 2);
  unsigned short* WallT = (unsigned short*)alloc((size_t)NL * PZS * 384 * 2);
  unsigned short* WoT   = (unsigned short*)alloc((size_t)NL * 384 * 384 * 2);
  unsigned short* WoutT = (unsigned short*)alloc((size_t)NL * 384 * 768 * 2);
  unsigned short* F1T   = (unsigned short*)alloc((size_t)NL * 1536 * 384 * 2);
  unsigned short* F2T   = (unsigned short*)alloc((size_t)NL * 384 * 1536 * 2);
  unsigned short* embB  = (unsigned short*)alloc((size_t)NV * DD * 2);
  (void)ws_size; (void)in_sizes; (void)n_in; (void)out_size;

  dim3 blk(256);
  int gTD = (TT * DD + 255) / 256;

  // ---- one-time (per launch) weight conversion, single dispatch ----
  TC10 tc;
  int te = 0;
  auto setjob = [&](int q, const float* src, unsigned short* dst, int K, int N, int Npad,
                    int nx, int ny, size_t sStr, size_t dStr) {
    te += nx * ny;
    tc.j[q] = TCJob{src, dst, K, N, Npad, nx, sStr, dStr, te};
  };
  setjob(0, Wr, WallT + (size_t)0 * 384 * 384, 384, 384, 384, 12, 12, (size_t)384 * 384, (size_t)PZS * 384);
  setjob(1, Wk, WallT + (size_t)1 * 384 * 384, 384, 384, 384, 12, 12, (size_t)384 * 384, (size_t)PZS * 384);
  setjob(2, Wv, WallT + (size_t)2 * 384 * 384, 384, 384, 384, 12, 12, (size_t)384 * 384, (size_t)PZS * 384);
  setjob(3, Wg, WallT + (size_t)3 * 384 * 384, 384, 384, 384, 12, 12, (size_t)384 * 384, (size_t)PZS * 384);
  setjob(4, Ww, WallT + (size_t)4 * 384 * 384, 384, 384, 384, 12, 12, (size_t)384 * 384, (size_t)PZS * 384);
  setjob(5, W_in, WallT + (size_t)1920 * 384, 384, XDIM, 1792, 56, 12, (size_t)384 * XDIM, (size_t)PZS * 384);
  setjob(6, Wo, WoT, 384, 384, 384, 12, 12, (size_t)384 * 384, (size_t)384 * 384);
  setjob(7, W_out, WoutT, 768, 384, 384, 12, 24, (size_t)768 * 384, (size_t)384 * 768);
  setjob(8, ffn_w1, F1T, 384, 1536, 1536, 48, 12, (size_t)384 * 1536, (size_t)1536 * 384);
  setjob(9, ffn_w2, F2T, 1536, 384, 384, 12, 48, (size_t)1536 * 384, (size_t)384 * 1536);
  transconv_all<<<dim3(te, 8), blk, 0, stream>>>(tc);
  conv_b16_kernel<<<(NV * DD + 255) / 256, blk, 0, stream>>>(embed, embB, NV * DD);
  embed_kernel<<<gTD, blk, 0, stream>>>(x, embed, hb0);

  for (int i = 0; i < NL; ++i) {
    float* hin  = (i & 1) ? hb1 : hb0;
    float* hmid = (i & 1) ? hb0 : hb1;

    proj_kernel<<<dim3(58, 16), blk, 0, stream>>>(
        hin, ln_w + (size_t)i * DD, WallT + (size_t)i * PZS * 384, PZ);

    scanA_kernel<<<576, blk, 0, stream>>>(PZ, u + (size_t)i * NH * 64, w_bias + (size_t)i * DD,
                                          so, rPb, MstR, DcR,
                                          conv_w + (size_t)i * CONVC * 4, conv_b + (size_t)i * CONVC,
                                          dt_bias + (size_t)i * MH,
                                          A_log + (size_t)i * MH, Dp + (size_t)i * MH,
                                          yb, Ccb, MstM, DcM);
    corr_kernel<<<576, blk, 0, stream>>>(MstR, DcR, rPb, so, MstM, DcM, Ccb, yb,
                                         PZ, gn_w + (size_t)i * DD, gn_b + (size_t)i * DD, gob);

    wo_wout_kernel<<<192, blk, 0, stream>>>(
        gob, WoT + (size_t)i * 384 * 384, orb,
        yb, PZ, mn_w + (size_t)i * DI,
        WoutT + (size_t)i * 384 * 768, omb);

    ffn1_kernel<<<dim3(24, 16), blk, 0, stream>>>(
        orb, omb, gw + (size_t)i * 2 * DD, gb + i,
        hin, hmid, ffn_ln_w + (size_t)i * DD,
        F1T + (size_t)i * 1536 * 384, fhb);

    ffn2_kernel<<<dim3(6, 16, 4), blk, 0, stream>>>(
        fhb, F2T + (size_t)i * 384 * 1536, hmid, 384, 1536, 384);
  }

  rms_kernel<<<256, blk, 0, stream>>>(hb0, ln_out_w, xnb);
  gemm128<<<dim3(250, 8), blk, 0, stream>>>(
      xnb, embB, (float*)d_out, NV, 384, NV);
}

// Round 10
// 1014.340 us; speedup vs baseline: 11.2991x; 1.8843x over previous
//
#include <hip/hip_runtime.h>
#include <math.h>

#define TT 1024
#define DD 384
#define NH 6
#define DI 768
#define MH 12
#define DS 64
#define NL 8
#define XDIM 1676   // 2*DI + 2*DS + MH
#define CONVC 896   // DI + 2*DS
#define NV 32000
#define PZS 3712    // fused output width: [r|k|v|g|w](1920) + [z|xBC|dt](1792 padded)
#define G_OFF 1152
#define W_OFF 1536
#define Z_OFF 1920
#define XBC_OFF 2688   // Z_OFF + DI
#define DT_OFF 3584    // Z_OFF + 1664
#define CHK 32      // scan chunk length
#define NCH 32      // number of chunks

typedef __attribute__((ext_vector_type(8))) short short8;
typedef __attribute__((ext_vector_type(4))) float f32x4;

// ---------------- helpers ----------------
__device__ __forceinline__ float siluf(float x) { return x / (1.f + expf(-x)); }
__device__ __forceinline__ float sigmoidf_(float x) { return 1.f / (1.f + expf(-x)); }
__device__ __forceinline__ float geluf(float x) {
  return 0.5f * x * (1.f + erff(x * 0.70710678118654752440f));
}
__device__ __forceinline__ unsigned short f2b(float x) {
  union { float f; unsigned int u; } v; v.f = x;
  unsigned int r = v.u + 0x7fffu + ((v.u >> 16) & 1u);
  return (unsigned short)(r >> 16);
}

#define GLDS(gp, lp) __builtin_amdgcn_global_load_lds( \
    (const __attribute__((address_space(1))) void*)(gp), \
    (__attribute__((address_space(3))) void*)(lp), 16, 0, 0)

// ---------------- 64-tile bf16 MFMA GEMM, BK=64. EPI: 0=f32, 1=gelu->bf16, 3=atomic-add ----------------
// Split-K via gridDim.z (K/gridDim.z must be divisible by 64).
// EPI 0/1 use a per-wave LDS-staged transposed epilogue for coalesced float4/short8 stores.
template<int EPI>
__global__ __launch_bounds__(256) void gemm_bf16(
    const unsigned short* __restrict__ A, const unsigned short* __restrict__ Bt,
    float* __restrict__ C, unsigned short* __restrict__ Cb, int N, int K, int ldC)
{
  __shared__ unsigned short As[4096];   // [64][64]
  __shared__ unsigned short Bs[4096];
  __shared__ __align__(16) float cst[4 * 16 * 36];   // per-wave staging
  int tid = threadIdx.x;
  int wid = tid >> 6, lane = tid & 63;
  int m0 = blockIdx.y * 64, n0 = blockIdx.x * 64;
  int wr = wid >> 1, wc = wid & 1;
  int r0 = tid >> 3, ch = tid & 7;
  int scs = (ch ^ (r0 & 7)) * 8;
  const unsigned short* ga = A  + (size_t)(m0 + r0) * K + scs;
  const unsigned short* gb = Bt + (size_t)(n0 + r0) * K + scs;
  unsigned short* la = As + wid * 512;
  unsigned short* lb = Bs + wid * 512;
  int fr = lane & 15, fc = lane >> 4;
  f32x4 zz = {0.f, 0.f, 0.f, 0.f};
  f32x4 acc[2][2];
  acc[0][0] = zz; acc[0][1] = zz; acc[1][0] = zz; acc[1][1] = zz;

  int kper = K / (int)gridDim.z;
  int ks = blockIdx.z * kper, ke = ks + kper;
  size_t row32 = (size_t)32 * K;
  for (int k0 = ks; k0 < ke; k0 += 64) {
    GLDS(ga + k0, la);
    GLDS(ga + k0 + row32, la + 2048);
    GLDS(gb + k0, lb);
    GLDS(gb + k0 + row32, lb + 2048);
    __syncthreads();
#pragma unroll
    for (int kh = 0; kh < 2; ++kh) {
      short8 af[2], bf[2];
#pragma unroll
      for (int mg = 0; mg < 2; ++mg) {
        int ar = wr * 32 + mg * 16 + fr;
        af[mg] = *reinterpret_cast<const short8*>(&As[ar * 64 + (((kh * 4 + fc) ^ (ar & 7)) * 8)]);
      }
#pragma unroll
      for (int ng = 0; ng < 2; ++ng) {
        int br = wc * 32 + ng * 16 + fr;
        bf[ng] = *reinterpret_cast<const short8*>(&Bs[br * 64 + (((kh * 4 + fc) ^ (br & 7)) * 8)]);
      }
#pragma unroll
      for (int mg = 0; mg < 2; ++mg)
#pragma unroll
        for (int ng = 0; ng < 2; ++ng)
          acc[mg][ng] = __builtin_amdgcn_mfma_f32_16x16x32_bf16(af[mg], bf[ng], acc[mg][ng], 0, 0, 0);
    }
    __syncthreads();
  }
  if (EPI == 3) {
#pragma unroll
    for (int mg = 0; mg < 2; ++mg)
#pragma unroll
      for (int ng = 0; ng < 2; ++ng) {
        int col = n0 + wc * 32 + ng * 16 + fr;
#pragma unroll
        for (int j = 0; j < 4; ++j) {
          int row = m0 + wr * 32 + mg * 16 + fc * 4 + j;
          atomicAdd(&C[(size_t)row * ldC + col], acc[mg][ng][j]);
        }
      }
  } else if (EPI == 0) {
    float* wst = cst + wid * (16 * 36);
    int rr = lane >> 2, qq = lane & 3;
#pragma unroll
    for (int mg = 0; mg < 2; ++mg) {
#pragma unroll
      for (int ng = 0; ng < 2; ++ng)
#pragma unroll
        for (int j = 0; j < 4; ++j)
          wst[(fc * 4 + j) * 36 + ng * 16 + fr] = acc[mg][ng][j];
      __syncthreads();
      int row = m0 + wr * 32 + mg * 16 + rr;
      int col = n0 + wc * 32 + qq * 8;
      *(float4*)&C[(size_t)row * ldC + col]     = *(const float4*)&wst[rr * 36 + qq * 8];
      *(float4*)&C[(size_t)row * ldC + col + 4] = *(const float4*)&wst[rr * 36 + qq * 8 + 4];
      __syncthreads();
    }
  } else {
    unsigned short* wst = (unsigned short*)cst + wid * (16 * 40);
    int rr = lane >> 2, qq = lane & 3;
#pragma unroll
    for (int mg = 0; mg < 2; ++mg) {
#pragma unroll
      for (int ng = 0; ng < 2; ++ng)
#pragma unroll
        for (int j = 0; j < 4; ++j)
          wst[(fc * 4 + j) * 40 + ng * 16 + fr] = f2b(geluf(acc[mg][ng][j]));
      __syncthreads();
      int row = m0 + wr * 32 + mg * 16 + rr;
      int col = n0 + wc * 32 + qq * 8;
      *(short8*)&Cb[(size_t)row * ldC + col] = *(const short8*)&wst[rr * 40 + qq * 8];
      __syncthreads();
    }
  }
}

// ---------------- dual 64-tile GEMM (BK=64): blocks [0,nb0) gemm0, rest gemm1 ----------------
__global__ __launch_bounds__(256) void gemm_dual(
    const unsigned short* __restrict__ A0, const unsigned short* __restrict__ B0t,
    float* __restrict__ C0, int K0, int ld0, int nx0, int nb0,
    const unsigned short* __restrict__ A1, const unsigned short* __restrict__ B1t,
    float* __restrict__ C1, int K1, int ld1, int nx1)
{
  __shared__ unsigned short As[4096];
  __shared__ unsigned short Bs[4096];
  __shared__ __align__(16) float cst[4 * 16 * 36];
  int b = blockIdx.x;
  const unsigned short *A, *Bt; float* C; int K, ldC, bx, by;
  if (b < nb0) { A = A0; Bt = B0t; C = C0; K = K0; ldC = ld0; bx = b % nx0; by = b / nx0; }
  else { b -= nb0; A = A1; Bt = B1t; C = C1; K = K1; ldC = ld1; bx = b % nx1; by = b / nx1; }
  int tid = threadIdx.x;
  int wid = tid >> 6, lane = tid & 63;
  int m0 = by * 64, n0 = bx * 64;
  int wr = wid >> 1, wc = wid & 1;
  int r0 = tid >> 3, ch = tid & 7;
  int scs = (ch ^ (r0 & 7)) * 8;
  const unsigned short* ga = A  + (size_t)(m0 + r0) * K + scs;
  const unsigned short* gb = Bt + (size_t)(n0 + r0) * K + scs;
  unsigned short* la = As + wid * 512;
  unsigned short* lb = Bs + wid * 512;
  int fr = lane & 15, fc = lane >> 4;
  f32x4 zz = {0.f, 0.f, 0.f, 0.f};
  f32x4 acc[2][2];
  acc[0][0] = zz; acc[0][1] = zz; acc[1][0] = zz; acc[1][1] = zz;
  size_t row32 = (size_t)32 * K;
  for (int k0 = 0; k0 < K; k0 += 64) {
    GLDS(ga + k0, la);
    GLDS(ga + k0 + row32, la + 2048);
    GLDS(gb + k0, lb);
    GLDS(gb + k0 + row32, lb + 2048);
    __syncthreads();
#pragma unroll
    for (int kh = 0; kh < 2; ++kh) {
      short8 af[2], bf[2];
#pragma unroll
      for (int mg = 0; mg < 2; ++mg) {
        int ar = wr * 32 + mg * 16 + fr;
        af[mg] = *reinterpret_cast<const short8*>(&As[ar * 64 + (((kh * 4 + fc) ^ (ar & 7)) * 8)]);
      }
#pragma unroll
      for (int ng = 0; ng < 2; ++ng) {
        int br = wc * 32 + ng * 16 + fr;
        bf[ng] = *reinterpret_cast<const short8*>(&Bs[br * 64 + (((kh * 4 + fc) ^ (br & 7)) * 8)]);
      }
#pragma unroll
      for (int mg = 0; mg < 2; ++mg)
#pragma unroll
        for (int ng = 0; ng < 2; ++ng)
          acc[mg][ng] = __builtin_amdgcn_mfma_f32_16x16x32_bf16(af[mg], bf[ng], acc[mg][ng], 0, 0, 0);
    }
    __syncthreads();
  }
  float* wst = cst + wid * (16 * 36);
  int rr = lane >> 2, qq = lane & 3;
#pragma unroll
  for (int mg = 0; mg < 2; ++mg) {
#pragma unroll
    for (int ng = 0; ng < 2; ++ng)
#pragma unroll
      for (int j = 0; j < 4; ++j)
        wst[(fc * 4 + j) * 36 + ng * 16 + fr] = acc[mg][ng][j];
    __syncthreads();
    int row = m0 + wr * 32 + mg * 16 + rr;
    int col = n0 + wc * 32 + qq * 8;
    *(float4*)&C[(size_t)row * ldC + col]     = *(const float4*)&wst[rr * 36 + qq * 8];
    *(float4*)&C[(size_t)row * ldC + col + 4] = *(const float4*)&wst[rr * 36 + qq * 8 + 4];
    __syncthreads();
  }
}

// ---------------- 128-tile bf16 MFMA GEMM (logits), BK=64, staged coalesced stores ----------------
__global__ __launch_bounds__(256) void gemm128(
    const unsigned short* __restrict__ A, const unsigned short* __restrict__ Bt,
    float* __restrict__ C, int N, int K, int ldC)
{
  __shared__ unsigned short As[8192];   // [128][64]
  __shared__ unsigned short Bs[8192];
  __shared__ __align__(16) float cst[4 * 1088];   // per-wave [16][68]
  int tid = threadIdx.x;
  int wid = tid >> 6, lane = tid & 63;
  int m0 = blockIdx.y * 128, n0 = blockIdx.x * 128;
  int wr = wid >> 1, wc = wid & 1;
  int r0 = tid >> 3, ch = tid & 7;
  int scs = (ch ^ (r0 & 7)) * 8;
  const unsigned short* ga = A  + (size_t)(m0 + r0) * K + scs;
  const unsigned short* gb = Bt + (size_t)(n0 + r0) * K + scs;
  int fr = lane & 15, fc = lane >> 4;
  f32x4 zz = {0.f, 0.f, 0.f, 0.f};
  f32x4 acc[4][4];
#pragma unroll
  for (int i = 0; i < 4; i++)
#pragma unroll
    for (int j = 0; j < 4; j++) acc[i][j] = zz;

  size_t row32 = (size_t)32 * K;
  for (int k0 = 0; k0 < K; k0 += 64) {
#pragma unroll
    for (int i = 0; i < 4; ++i) {
      GLDS(ga + k0 + i * row32, As + i * 2048 + wid * 512);
      GLDS(gb + k0 + i * row32, Bs + i * 2048 + wid * 512);
    }
    __syncthreads();
#pragma unroll
    for (int kh = 0; kh < 2; ++kh) {
      short8 af[4], bf[4];
#pragma unroll
      for (int mg = 0; mg < 4; ++mg) {
        int ar = wr * 64 + mg * 16 + fr;
        af[mg] = *reinterpret_cast<const short8*>(&As[ar * 64 + (((kh * 4 + fc) ^ (ar & 7)) * 8)]);
      }
#pragma unroll
      for (int ng = 0; ng < 4; ++ng) {
        int br = wc * 64 + ng * 16 + fr;
        bf[ng] = *reinterpret_cast<const short8*>(&Bs[br * 64 + (((kh * 4 + fc) ^ (br & 7)) * 8)]);
      }
#pragma unroll
      for (int mg = 0; mg < 4; ++mg)
#pragma unroll
        for (int ng = 0; ng < 4; ++ng)
          acc[mg][ng] = __builtin_amdgcn_mfma_f32_16x16x32_bf16(af[mg], bf[ng], acc[mg][ng], 0, 0, 0);
    }
    __syncthreads();
  }
  float* wst = cst + wid * 1088;
  int rr = lane >> 2, q = (lane & 3) * 16;
#pragma unroll
  for (int mg = 0; mg < 4; ++mg) {
#pragma unroll
    for (int ng = 0; ng < 4; ++ng)
#pragma unroll
      for (int j = 0; j < 4; ++j)
        wst[(fc * 4 + j) * 68 + ng * 16 + fr] = acc[mg][ng][j];
    __syncthreads();
    int row = m0 + wr * 64 + mg * 16 + rr;
    size_t rb = (size_t)row * ldC + n0 + wc * 64 + q;
#pragma unroll
    for (int i = 0; i < 4; ++i)
      *(float4*)&C[rb + i * 4] = *(const float4*)&wst[rr * 68 + q + i * 4];
    __syncthreads();
  }
}

// ---------------- merged weight transpose + fp32->bf16 (all jobs, one dispatch) ----------------
struct TCJob { const float* src; unsigned short* dst; int K, N, Npad, nx; size_t sStr, dStr; int tend; };
struct TC10 { TCJob j[10]; };

__global__ __launch_bounds__(256) void transconv_all(TC10 P)
{
  __shared__ float tile[32][33];
  int bid = blockIdx.x;
  int q = 0;
  while (bid >= P.j[q].tend) ++q;
  int tstart = (q == 0) ? 0 : P.j[q - 1].tend;
  TCJob jb = P.j[q];
  int local = bid - tstart;
  int bx = local % jb.nx, by = local / jb.nx;
  const float* src = jb.src + (size_t)blockIdx.y * jb.sStr;
  unsigned short* dst = jb.dst + (size_t)blockIdx.y * jb.dStr;
  int k0 = by * 32, n0 = bx * 32;
  int tx = threadIdx.x & 31, ty = threadIdx.x >> 5;
  for (int i = ty; i < 32; i += 8) {
    int k = k0 + i, n = n0 + tx;
    tile[i][tx] = (k < jb.K && n < jb.N) ? src[(size_t)k * jb.N + n] : 0.f;
  }
  __syncthreads();
  for (int i = ty; i < 32; i += 8) {
    int n = n0 + i, k = k0 + tx;
    if (n < jb.Npad && k < jb.K) dst[(size_t)n * jb.K + k] = f2b(tile[tx][i]);
  }
}

__global__ void conv_b16_kernel(const float* __restrict__ src, unsigned short* __restrict__ dst, int n)
{
  int idx = blockIdx.x * 256 + threadIdx.x;
  if (idx < n) dst[idx] = f2b(src[idx]);
}

// ---------------- embedding gather ----------------
__global__ void embed_kernel(const int* __restrict__ x, const float* __restrict__ embed,
                             float* __restrict__ h)
{
  int idx = blockIdx.x * 256 + threadIdx.x;
  if (idx < TT * DD) {
    int t = idx / DD, d = idx % DD;
    h[idx] = embed[(size_t)x[t] * DD + d];
  }
}

// ---------------- RMSNorm (wave per row) -> bf16 ----------------
__global__ __launch_bounds__(256) void rms_kernel(const float* __restrict__ in,
                                                  const float* __restrict__ w,
                                                  unsigned short* __restrict__ out)
{
  int row = blockIdx.x * 4 + (threadIdx.x >> 6);
  int lane = threadIdx.x & 63;
  const float* r = in + (size_t)row * DD;
  float v[6]; float ss = 0.f;
#pragma unroll
  for (int j = 0; j < 6; ++j) { v[j] = r[lane + j * 64]; ss = fmaf(v[j], v[j], ss); }
#pragma unroll
  for (int s = 1; s < 64; s <<= 1) ss += __shfl_xor(ss, s);
  float scale = rsqrtf(ss * (1.f / DD) + 1e-6f);
#pragma unroll
  for (int j = 0; j < 6; ++j)
    out[(size_t)row * DD + lane + j * 64] = f2b(w[lane + j * 64] * v[j] * scale);
}

// ---------------- Phase A: per-chunk local scans (decay, dt, conv1d all fused) ----------------
// blocks 0..191: RWKV (h = b>>5, chunk c = b&31); 192..575: Mamba (hh, c)
__global__ __launch_bounds__(256) void scanA_kernel(
    const float* __restrict__ PZ, const float* __restrict__ u, const float* __restrict__ wbias,
    float* __restrict__ so, float* __restrict__ rPb,
    float* __restrict__ MstR, float* __restrict__ DcR,
    const float* __restrict__ cw, const float* __restrict__ cbia,
    const float* __restrict__ dtbias,
    const float* __restrict__ Alog, const float* __restrict__ Dpw,
    float* __restrict__ yb, float* __restrict__ Ccb,
    float* __restrict__ MstM, float* __restrict__ DcM)
{
  __shared__ float smem[2 * 256 + 64];
  int b = blockIdx.x, tid = threadIdx.x;
  if (b < 192) {
    int h = b >> 5, c = b & 31;
    float* sbuf = smem; float* us = smem + 512;
    if (tid < 64) us[tid] = u[h * 64 + tid];
    int wv = tid >> 6, l = tid & 63;
    int vv = wv * 16 + (l & 15);
    int kc = l >> 4;
    int arr = tid >> 6, idx = tid & 63;
    int off = (arr == 0) ? 0 : (arr == 1) ? 384 : (arr == 2) ? W_OFF : 768;  // r,k,w(raw),v
    float wb = (arr == 2) ? wbias[h * 64 + idx] : 0.f;
    size_t base = (size_t)h * 64 + idx + off;
    int t0 = c * CHK;
    float S[16], Pc[16];
#pragma unroll
    for (int i = 0; i < 16; i++) { S[i] = 0.f; Pc[i] = 1.f; }
    float reg = PZ[(size_t)t0 * PZS + base];
    bool st = (wv == 0) && ((l & 15) == 0);   // 4 threads, kc = 0..3
    for (int t = 0; t < CHK; ++t) {
      int tt = t0 + t;
      float* cb = sbuf + (t & 1) * 256;
      cb[arr * 64 + idx] = (arr == 2) ? expf(-expf(reg + wb)) : reg;
      if (t + 1 < CHK) reg = PZ[(size_t)(tt + 1) * PZS + base];
      __syncthreads();
      float vt = cb[192 + vv];
      float acc = 0.f;
      float rp[16];
#pragma unroll
      for (int i = 0; i < 16; ++i) {
        int kk = kc * 16 + i;
        float rv = cb[kk], kv = cb[64 + kk], dv = cb[128 + kk];
        rp[i] = rv * Pc[i];
        float kvv = kv * vt;
        acc = fmaf(rv, fmaf(us[kk], kvv, S[i]), acc);
        S[i] = fmaf(dv, S[i], kvv);
        Pc[i] *= dv;
      }
      acc += __shfl_xor(acc, 16);
      acc += __shfl_xor(acc, 32);
      if (l < 16) so[(size_t)tt * DD + h * 64 + vv] = acc;
      if (st) {
        float4* dst = (float4*)&rPb[(size_t)tt * DD + h * 64 + kc * 16];
        dst[0] = make_float4(rp[0], rp[1], rp[2], rp[3]);
        dst[1] = make_float4(rp[4], rp[5], rp[6], rp[7]);
        dst[2] = make_float4(rp[8], rp[9], rp[10], rp[11]);
        dst[3] = make_float4(rp[12], rp[13], rp[14], rp[15]);
      }
    }
    float* ms = MstR + (size_t)(h * NCH + c) * 4096;   // [v][k]
    float4* msv = (float4*)&ms[vv * 64 + kc * 16];
    msv[0] = make_float4(S[0], S[1], S[2], S[3]);
    msv[1] = make_float4(S[4], S[5], S[6], S[7]);
    msv[2] = make_float4(S[8], S[9], S[10], S[11]);
    msv[3] = make_float4(S[12], S[13], S[14], S[15]);
    if (st) {
      float4* dd_ = (float4*)&DcR[(h * NCH + c) * 64 + kc * 16];
      dd_[0] = make_float4(Pc[0], Pc[1], Pc[2], Pc[3]);
      dd_[1] = make_float4(Pc[4], Pc[5], Pc[6], Pc[7]);
      dd_[2] = make_float4(Pc[8], Pc[9], Pc[10], Pc[11]);
      dd_[3] = make_float4(Pc[12], Pc[13], Pc[14], Pc[15]);
    }
  } else {
    int bb = b - 192;
    int hh = bb >> 5, c = bb & 31;
    float* sbuf = smem;
    int wv = tid >> 6, l = tid & 63;
    int p = wv * 16 + (l & 15);
    int sc = l >> 4;
    int arr = tid >> 6, idx = tid & 63;
    float A = -expf(Alog[hh]);
    float Dph = Dpw[hh];
    float dtbh = dtbias[hh];
    int t0 = c * CHK;
    float cw0 = 0.f, cw1 = 0.f, cw2 = 0.f, cw3 = 0.f, cbv = 0.f;
    float xw0 = 0.f, xw1 = 0.f, xw2 = 0.f, cur = 0.f;
    const float* xcol = nullptr;
    float reg = 0.f;
    if (arr < 3) {
      int chn = (arr == 0) ? (hh * 64 + idx) : (arr == 1) ? (DI + idx) : (DI + DS + idx);
      cw0 = cw[chn * 4 + 0]; cw1 = cw[chn * 4 + 1]; cw2 = cw[chn * 4 + 2]; cw3 = cw[chn * 4 + 3];
      cbv = cbia[chn];
      xcol = PZ + XBC_OFF + chn;
      xw0 = (t0 >= 3) ? xcol[(size_t)(t0 - 3) * PZS] : 0.f;
      xw1 = (t0 >= 2) ? xcol[(size_t)(t0 - 2) * PZS] : 0.f;
      xw2 = (t0 >= 1) ? xcol[(size_t)(t0 - 1) * PZS] : 0.f;
      cur = xcol[(size_t)t0 * PZS];
    } else {
      reg = PZ[(size_t)t0 * PZS + DT_OFF + hh];
    }
    float S[16]; float cdA = 1.f;
#pragma unroll
    for (int i = 0; i < 16; i++) S[i] = 0.f;
    bool st = (wv == 0) && ((l & 15) == 0);
    for (int t = 0; t < CHK; ++t) {
      int tt = t0 + t;
      float* cb = sbuf + (t & 1) * 256;
      if (arr < 3) {
        float cvv = fmaf(cw3, cur, fmaf(cw2, xw2, fmaf(cw1, xw1, fmaf(cw0, xw0, cbv))));
        cb[arr * 64 + idx] = siluf(cvv);
        float nx = (t + 1 < CHK) ? xcol[(size_t)(tt + 1) * PZS] : 0.f;
        xw0 = xw1; xw1 = xw2; xw2 = cur; cur = nx;
      } else {
        if (idx == 0) {
          float v = reg + dtbh;
          cb[192] = (v > 20.f) ? v : log1pf(expf(v));
        }
        if (t + 1 < CHK) reg = PZ[(size_t)(tt + 1) * PZS + DT_OFF + hh];
      }
      __syncthreads();
      float dt_ = cb[192];
      float dA = expf(dt_ * A);
      cdA *= dA;
      float xp = cb[p];
      float dtx = dt_ * xp;
      float acc = 0.f;
#pragma unroll
      for (int i = 0; i < 16; ++i) {
        int s = sc * 16 + i;
        S[i] = fmaf(dA, S[i], dtx * cb[64 + s]);
        acc = fmaf(S[i], cb[128 + s], acc);
      }
      acc += __shfl_xor(acc, 16);
      acc += __shfl_xor(acc, 32);
      if (l < 16) yb[(size_t)tt * DI + hh * 64 + p] = fmaf(Dph, xp, acc);
      if (st) {
        float4* dst = (float4*)&Ccb[(size_t)tt * DI + hh * 64 + sc * 16];
#pragma unroll
        for (int j4 = 0; j4 < 4; ++j4)
          dst[j4] = make_float4(cdA * cb[128 + sc * 16 + j4 * 4 + 0],
                                cdA * cb[128 + sc * 16 + j4 * 4 + 1],
                                cdA * cb[128 + sc * 16 + j4 * 4 + 2],
                                cdA * cb[128 + sc * 16 + j4 * 4 + 3]);
      }
    }
    float* ms = MstM + (size_t)(hh * NCH + c) * 4096;  // [p][s]
    float4* msv = (float4*)&ms[p * 64 + sc * 16];
    msv[0] = make_float4(S[0], S[1], S[2], S[3]);
    msv[1] = make_float4(S[4], S[5], S[6], S[7]);
    msv[2] = make_float4(S[8], S[9], S[10], S[11]);
    msv[3] = make_float4(S[12], S[13], S[14], S[15]);
    if (tid == 0) DcM[hh * NCH + c] = cdA;
  }
}

// ---------------- Phase C: prefix-combine + output correction (+ fused RWKV groupnorm*silu) ----------------
__global__ __launch_bounds__(256) void corr_kernel(
    const float* __restrict__ MstR, const float* __restrict__ DcR,
    const float* __restrict__ rPb, const float* __restrict__ so,
    const float* __restrict__ MstM, const float* __restrict__ DcM,
    const float* __restrict__ Ccb, float* __restrict__ yb,
    const float* __restrict__ PZ, const float* __restrict__ gnw, const float* __restrict__ gnb,
    unsigned short* __restrict__ gob)
{
  __shared__ float S0l[64 * 68];
  __shared__ float Rl[CHK * 68];
  int b = blockIdx.x, tid = threadIdx.x;
  const float* rg; int ostride, obase, t0;
  bool rwkv = (b < 192);
  int h, cidx;
  if (rwkv) {
    h = b >> 5; cidx = b & 31;
    rg = rPb; obase = h * 64; ostride = DD;
  } else {
    int bb = b - 192; h = bb >> 5; cidx = bb & 31;
    rg = Ccb; obase = h * 64; ostride = DI;
  }
  t0 = cidx * CHK;
  float Sreg[16];
#pragma unroll
  for (int it = 0; it < 16; ++it) Sreg[it] = 0.f;
  if (rwkv) {
    int kk = tid & 63;
    for (int cp = 0; cp < cidx; ++cp) {
      float d = DcR[(h * NCH + cp) * 64 + kk];
      const float* mb = MstR + (size_t)(h * NCH + cp) * 4096;
#pragma unroll
      for (int it = 0; it < 16; ++it)
        Sreg[it] = fmaf(d, Sreg[it], mb[tid + 256 * it]);
    }
  } else {
    for (int cp = 0; cp < cidx; ++cp) {
      float d = DcM[h * NCH + cp];
      const float* mb = MstM + (size_t)(h * NCH + cp) * 4096;
#pragma unroll
      for (int it = 0; it < 16; ++it)
        Sreg[it] = fmaf(d, Sreg[it], mb[tid + 256 * it]);
    }
  }
#pragma unroll
  for (int it = 0; it < 16; ++it) {
    int gi = tid + 256 * it;
    S0l[(gi & 63) * 68 + (gi >> 6)] = Sreg[it];
  }
  {
    int t = tid >> 3, q = (tid & 7) * 8;
    const float4* src = (const float4*)&rg[(size_t)(t0 + t) * ostride + obase + q];
    float4* dst = (float4*)&Rl[t * 68 + q];
    dst[0] = src[0]; dst[1] = src[1];
  }
  __syncthreads();
  int t = tid >> 3, q = (tid & 7) * 8;
  float acc[8];
#pragma unroll
  for (int j = 0; j < 8; j++) acc[j] = 0.f;
  for (int k = 0; k < 64; ++k) {
    float rv = Rl[t * 68 + k];
    const float4* sp = (const float4*)&S0l[k * 68 + q];
    float4 s0 = sp[0], s1 = sp[1];
    acc[0] = fmaf(rv, s0.x, acc[0]);
    acc[1] = fmaf(rv, s0.y, acc[1]);
    acc[2] = fmaf(rv, s0.z, acc[2]);
    acc[3] = fmaf(rv, s0.w, acc[3]);
    acc[4] = fmaf(rv, s1.x, acc[4]);
    acc[5] = fmaf(rv, s1.y, acc[5]);
    acc[6] = fmaf(rv, s1.z, acc[6]);
    acc[7] = fmaf(rv, s1.w, acc[7]);
  }
  if (!rwkv) {
    float4* op = (float4*)&yb[(size_t)(t0 + t) * DI + obase + q];
    float4 c0 = op[0], c1 = op[1];
    c0.x += acc[0]; c0.y += acc[1]; c0.z += acc[2]; c0.w += acc[3];
    c1.x += acc[4]; c1.y += acc[5]; c1.z += acc[6]; c1.w += acc[7];
    op[0] = c0; op[1] = c1;
  } else {
    float ov[8];
    const float4* sp = (const float4*)&so[(size_t)(t0 + t) * DD + obase + q];
    float4 s0 = sp[0], s1 = sp[1];
    ov[0] = s0.x + acc[0]; ov[1] = s0.y + acc[1]; ov[2] = s0.z + acc[2]; ov[3] = s0.w + acc[3];
    ov[4] = s1.x + acc[4]; ov[5] = s1.y + acc[5]; ov[6] = s1.z + acc[6]; ov[7] = s1.w + acc[7];
    float m_ = 0.f;
#pragma unroll
    for (int j = 0; j < 8; j++) m_ += ov[j];
    m_ += __shfl_xor(m_, 1); m_ += __shfl_xor(m_, 2); m_ += __shfl_xor(m_, 4);
    float mu = m_ * (1.f / 64.f);
    float vv = 0.f;
#pragma unroll
    for (int j = 0; j < 8; j++) { float d = ov[j] - mu; vv = fmaf(d, d, vv); }
    vv += __shfl_xor(vv, 1); vv += __shfl_xor(vv, 2); vv += __shfl_xor(vv, 4);
    float rstd = rsqrtf(vv * (1.f / 64.f) + 1e-5f);
#pragma unroll
    for (int j = 0; j < 8; j++) {
      int d = obase + q + j;
      float gv = PZ[(size_t)(t0 + t) * PZS + G_OFF + d];
      float o = fmaf((ov[j] - mu) * rstd, gnw[d], gnb[d]) * siluf(gv);
      gob[(size_t)(t0 + t) * DD + d] = f2b(o);
    }
  }
}

// ---------------- Mamba out: rms(y * silu(z), mn_w) -> bf16 (wave per row) ----------------
__global__ __launch_bounds__(256) void mamba_norm_kernel(const float* __restrict__ yb,
    const float* __restrict__ PZ, const float* __restrict__ mnw, unsigned short* __restrict__ out)
{
  int row = blockIdx.x * 4 + (threadIdx.x >> 6);
  int lane = threadIdx.x & 63;
  float v[12]; float ss = 0.f;
#pragma unroll
  for (int j = 0; j < 12; ++j) {
    int c = lane + j * 64;
    float z = PZ[(size_t)row * PZS + Z_OFF + c];
    float t = yb[(size_t)row * DI + c] * siluf(z);
    v[j] = t; ss = fmaf(t, t, ss);
  }
#pragma unroll
  for (int s = 1; s < 64; s <<= 1) ss += __shfl_xor(ss, s);
  float scale = rsqrtf(ss * (1.f / DI) + 1e-6f);
#pragma unroll
  for (int j = 0; j < 12; ++j) {
    int c = lane + j * 64;
    out[(size_t)row * DI + c] = f2b(v[j] * scale * mnw[c]);
  }
}

// ---------------- gate combine + FFN RMSNorm (wave per row) ----------------
__global__ __launch_bounds__(256) void gate_rms_kernel(const float* __restrict__ orb,
    const float* __restrict__ omb, const float* __restrict__ gw,
    const float* __restrict__ gb, const float* __restrict__ flnw,
    float* __restrict__ h, unsigned short* __restrict__ xnb)
{
  int row = blockIdx.x * 4 + (threadIdx.x >> 6);
  int lane = threadIdx.x & 63;
  float a[6], bq[6]; float ss = 0.f;
#pragma unroll
  for (int j = 0; j < 6; ++j) {
    int c = lane + j * 64;
    a[j] = orb[(size_t)row * DD + c]; bq[j] = omb[(size_t)row * DD + c];
    ss += a[j] * gw[c] + bq[j] * gw[DD + c];
  }
#pragma unroll
  for (int s = 1; s < 64; s <<= 1) ss += __shfl_xor(ss, s);
  float gate = sigmoidf_(ss + gb[0]);
  float hn[6]; float ss2 = 0.f;
#pragma unroll
  for (int j = 0; j < 6; ++j) {
    int c = lane + j * 64;
    size_t ix = (size_t)row * DD + c;
    hn[j] = h[ix] + gate * a[j] + (1.f - gate) * bq[j];
    h[ix] = hn[j];
    ss2 = fmaf(hn[j], hn[j], ss2);
  }
#pragma unroll
  for (int s = 1; s < 64; s <<= 1) ss2 += __shfl_xor(ss2, s);
  float scale = rsqrtf(ss2 * (1.f / DD) + 1e-6f);
#pragma unroll
  for (int j = 0; j < 6; ++j) {
    int c = lane + j * 64;
    xnb[(size_t)row * DD + c] = f2b(flnw[c] * hn[j] * scale);
  }
}

// ---------------- launcher ----------------
extern "C" void kernel_launch(void* const* d_in, const int* in_sizes, int n_in,
                              void* d_out, int out_size, void* d_ws, size_t ws_size,
                              hipStream_t stream)
{
  const int*   x        = (const int*)  d_in[0];
  const float* embed    = (const float*)d_in[1];
  const float* ln_w     = (const float*)d_in[2];
  const float* Wr       = (const float*)d_in[3];
  const float* Wk       = (const float*)d_in[4];
  const float* Wv       = (const float*)d_in[5];
  const float* Wg       = (const float*)d_in[6];
  const float* Ww       = (const float*)d_in[7];
  const float* w_bias   = (const float*)d_in[8];
  const float* u        = (const float*)d_in[9];
  const float* gn_w     = (const float*)d_in[10];
  const float* gn_b     = (const float*)d_in[11];
  const float* Wo       = (const float*)d_in[12];
  const float* W_in     = (const float*)d_in[13];
  const float* conv_w   = (const float*)d_in[14];
  const float* conv_b   = (const float*)d_in[15];
  const float* dt_bias  = (const float*)d_in[16];
  const float* A_log    = (const float*)d_in[17];
  const float* Dp       = (const float*)d_in[18];
  const float* mn_w     = (const float*)d_in[19];
  const float* W_out    = (const float*)d_in[20];
  const float* gw       = (const float*)d_in[21];
  const float* gb       = (const float*)d_in[22];
  const float* ffn_ln_w = (const float*)d_in[23];
  const float* ffn_w1   = (const float*)d_in[24];
  const float* ffn_w2   = (const float*)d_in[25];
  const float* ln_out_w = (const float*)d_in[26];

  char* base = (char*)d_ws;
  size_t off = 0;
  auto alloc = [&](size_t bytes) { off = (off + 255) & ~(size_t)255; void* p = base + off; off += bytes; return p; };

  float* h    = (float*)alloc((size_t)TT * DD * 4);
  float* PZ   = (float*)alloc((size_t)TT * PZS * 4);
  float* yb   = (float*)alloc((size_t)TT * DI * 4);
  float* so   = (float*)alloc((size_t)TT * DD * 4);
  float* orb  = (float*)alloc((size_t)TT * DD * 4);
  float* omb  = (float*)alloc((size_t)TT * DD * 4);
  float* rPb  = (float*)alloc((size_t)TT * DD * 4);
  float* Ccb  = (float*)alloc((size_t)TT * DI * 4);
  float* MstR = (float*)alloc((size_t)NH * NCH * 4096 * 4);
  float* DcR  = (float*)alloc((size_t)NH * NCH * 64 * 4);
  float* MstM = (float*)alloc((size_t)MH * NCH * 4096 * 4);
  float* DcM  = (float*)alloc((size_t)MH * NCH * 4);
  unsigned short* xnb = (unsigned short*)alloc((size_t)TT * DD * 2);
  unsigned short* gob = (unsigned short*)alloc((size_t)TT * DD * 2);
  unsigned short* ynb = (unsigned short*)alloc((size_t)TT * DI * 2);
  unsigned short* fhb = (unsigned short*)alloc((size_t)TT * 1536 * 2);
  unsigned short* WallT = (unsigned short*)alloc((size_t)NL * PZS * 384 * 2);
  unsigned short* WoT   = (unsigned short*)alloc((size_t)NL * 384 * 384 * 2);
  unsigned short* WoutT = (unsigned short*)alloc((size_t)NL * 384 * 768 * 2);
  unsigned short* F1T   = (unsigned short*)alloc((size_t)NL * 1536 * 384 * 2);
  unsigned short* F2T   = (unsigned short*)alloc((size_t)NL * 384 * 1536 * 2);
  unsigned short* embB  = (unsigned short*)alloc((size_t)NV * DD * 2);
  (void)ws_size; (void)in_sizes; (void)n_in; (void)out_size;

  dim3 blk(256);
  int gTD = (TT * DD + 255) / 256;

  // ---- one-time (per launch) weight conversion, single dispatch ----
  TC10 tc;
  int te = 0;
  auto setjob = [&](int q, const float* src, unsigned short* dst, int K, int N, int Npad,
                    int nx, int ny, size_t sStr, size_t dStr) {
    te += nx * ny;
    tc.j[q] = TCJob{src, dst, K, N, Npad, nx, sStr, dStr, te};
  };
  setjob(0, Wr, WallT + (size_t)0 * 384 * 384, 384, 384, 384, 12, 12, (size_t)384 * 384, (size_t)PZS * 384);
  setjob(1, Wk, WallT + (size_t)1 * 384 * 384, 384, 384, 384, 12, 12, (size_t)384 * 384, (size_t)PZS * 384);
  setjob(2, Wv, WallT + (size_t)2 * 384 * 384, 384, 384, 384, 12, 12, (size_t)384 * 384, (size_t)PZS * 384);
  setjob(3, Wg, WallT + (size_t)3 * 384 * 384, 384, 384, 384, 12, 12, (size_t)384 * 384, (size_t)PZS * 384);
  setjob(4, Ww, WallT + (size_t)4 * 384 * 384, 384, 384, 384, 12, 12, (size_t)384 * 384, (size_t)PZS * 384);
  setjob(5, W_in, WallT + (size_t)1920 * 384, 384, XDIM, 1792, 56, 12, (size_t)384 * XDIM, (size_t)PZS * 384);
  setjob(6, Wo, WoT, 384, 384, 384, 12, 12, (size_t)384 * 384, (size_t)384 * 384);
  setjob(7, W_out, WoutT, 768, 384, 384, 12, 24, (size_t)768 * 384, (size_t)384 * 768);
  setjob(8, ffn_w1, F1T, 384, 1536, 1536, 48, 12, (size_t)384 * 1536, (size_t)1536 * 384);
  setjob(9, ffn_w2, F2T, 1536, 384, 384, 12, 48, (size_t)1536 * 384, (size_t)384 * 1536);
  transconv_all<<<dim3(te, 8), blk, 0, stream>>>(tc);
  conv_b16_kernel<<<(NV * DD + 255) / 256, blk, 0, stream>>>(embed, embB, NV * DD);
  embed_kernel<<<gTD, blk, 0, stream>>>(x, embed, h);

  for (int i = 0; i < NL; ++i) {
    rms_kernel<<<256, blk, 0, stream>>>(h, ln_w + (size_t)i * DD, xnb);

    gemm_bf16<0><<<dim3(58, 16), blk, 0, stream>>>(
        xnb, WallT + (size_t)i * PZS * 384, PZ, nullptr, PZS, 384, PZS);

    scanA_kernel<<<576, blk, 0, stream>>>(PZ, u + (size_t)i * NH * 64, w_bias + (size_t)i * DD,
                                          so, rPb, MstR, DcR,
                                          conv_w + (size_t)i * CONVC * 4, conv_b + (size_t)i * CONVC,
                                          dt_bias + (size_t)i * MH,
                                          A_log + (size_t)i * MH, Dp + (size_t)i * MH,
                                          yb, Ccb, MstM, DcM);
    corr_kernel<<<576, blk, 0, stream>>>(MstR, DcR, rPb, so, MstM, DcM, Ccb, yb,
                                         PZ, gn_w + (size_t)i * DD, gn_b + (size_t)i * DD, gob);

    mamba_norm_kernel<<<256, blk, 0, stream>>>(yb, PZ, mn_w + (size_t)i * DI, ynb);

    gemm_dual<<<192, blk, 0, stream>>>(
        gob, WoT + (size_t)i * 384 * 384, orb, 384, DD, 6, 96,
        ynb, WoutT + (size_t)i * 384 * 768, omb, 768, DD, 6);

    gate_rms_kernel<<<256, blk, 0, stream>>>(orb, omb, gw + (size_t)i * 2 * DD, gb + i,
                                             ffn_ln_w + (size_t)i * DD, h, xnb);

    gemm_bf16<1><<<dim3(24, 16), blk, 0, stream>>>(
        xnb, F1T + (size_t)i * 1536 * 384, nullptr, fhb, 1536, 384, 1536);
    gemm_bf16<3><<<dim3(6, 16, 4), blk, 0, stream>>>(
        fhb, F2T + (size_t)i * 384 * 1536, h, nullptr, 384, 1536, 384);
  }

  rms_kernel<<<256, blk, 0, stream>>>(h, ln_out_w, xnb);
  gemm128<<<dim3(250, 8), blk, 0, stream>>>(
      xnb, embB, (float*)d_out, NV, 384, NV);
}

// Round 11
// 1008.585 us; speedup vs baseline: 11.3636x; 1.0057x over previous
//
#include <hip/hip_runtime.h>
#include <math.h>

#define TT 1024
#define DD 384
#define NH 6
#define DI 768
#define MH 12
#define DS 64
#define NL 8
#define XDIM 1676   // 2*DI + 2*DS + MH
#define CONVC 896   // DI + 2*DS
#define NV 32000
#define PZS 3712    // fused output width: [r|k|v|g|w](1920) + [z|xBC|dt](1792 padded)
#define G_OFF 1152
#define W_OFF 1536
#define Z_OFF 1920
#define XBC_OFF 2688   // Z_OFF + DI
#define DT_OFF 3584    // Z_OFF + 1664
#define CHK 32      // scan chunk length
#define NCH 32      // number of chunks

typedef __attribute__((ext_vector_type(8))) short short8;
typedef __attribute__((ext_vector_type(4))) float f32x4;

// ---------------- helpers ----------------
__device__ __forceinline__ float siluf(float x) { return x / (1.f + expf(-x)); }
__device__ __forceinline__ float sigmoidf_(float x) { return 1.f / (1.f + expf(-x)); }
__device__ __forceinline__ float geluf(float x) {
  return 0.5f * x * (1.f + erff(x * 0.70710678118654752440f));
}
__device__ __forceinline__ unsigned short f2b(float x) {
  union { float f; unsigned int u; } v; v.f = x;
  unsigned int r = v.u + 0x7fffu + ((v.u >> 16) & 1u);
  return (unsigned short)(r >> 16);
}

#define GLDS(gp, lp) __builtin_amdgcn_global_load_lds( \
    (const __attribute__((address_space(1))) void*)(gp), \
    (__attribute__((address_space(3))) void*)(lp), 16, 0, 0)

// ---------------- 64-tile bf16 MFMA GEMM, BK=64. EPI: 0=f32, 1=gelu->bf16, 3=atomic-add ----------------
// Split-K via gridDim.z (K/gridDim.z must be divisible by 64).
// EPI 0/1: coalesced stores staged in LDS aliased onto As/Bs (dead after K-loop).
template<int EPI>
__global__ __launch_bounds__(256) void gemm_bf16(
    const unsigned short* __restrict__ A, const unsigned short* __restrict__ Bt,
    float* __restrict__ C, unsigned short* __restrict__ Cb, int N, int K, int ldC)
{
  __shared__ __align__(16) char smraw[16384];
  unsigned short* As = (unsigned short*)smraw;          // [64][64]
  unsigned short* Bs = (unsigned short*)smraw + 4096;
  int tid = threadIdx.x;
  int wid = tid >> 6, lane = tid & 63;
  int m0 = blockIdx.y * 64, n0 = blockIdx.x * 64;
  int wr = wid >> 1, wc = wid & 1;
  int r0 = tid >> 3, ch = tid & 7;
  int scs = (ch ^ (r0 & 7)) * 8;
  const unsigned short* ga = A  + (size_t)(m0 + r0) * K + scs;
  const unsigned short* gb = Bt + (size_t)(n0 + r0) * K + scs;
  unsigned short* la = As + wid * 512;
  unsigned short* lb = Bs + wid * 512;
  int fr = lane & 15, fc = lane >> 4;
  f32x4 zz = {0.f, 0.f, 0.f, 0.f};
  f32x4 acc[2][2];
  acc[0][0] = zz; acc[0][1] = zz; acc[1][0] = zz; acc[1][1] = zz;

  int kper = K / (int)gridDim.z;
  int ks = blockIdx.z * kper, ke = ks + kper;
  size_t row32 = (size_t)32 * K;
  for (int k0 = ks; k0 < ke; k0 += 64) {
    GLDS(ga + k0, la);
    GLDS(ga + k0 + row32, la + 2048);
    GLDS(gb + k0, lb);
    GLDS(gb + k0 + row32, lb + 2048);
    __syncthreads();
#pragma unroll
    for (int kh = 0; kh < 2; ++kh) {
      short8 af[2], bf[2];
#pragma unroll
      for (int mg = 0; mg < 2; ++mg) {
        int ar = wr * 32 + mg * 16 + fr;
        af[mg] = *reinterpret_cast<const short8*>(&As[ar * 64 + (((kh * 4 + fc) ^ (ar & 7)) * 8)]);
      }
#pragma unroll
      for (int ng = 0; ng < 2; ++ng) {
        int br = wc * 32 + ng * 16 + fr;
        bf[ng] = *reinterpret_cast<const short8*>(&Bs[br * 64 + (((kh * 4 + fc) ^ (br & 7)) * 8)]);
      }
#pragma unroll
      for (int mg = 0; mg < 2; ++mg)
#pragma unroll
        for (int ng = 0; ng < 2; ++ng)
          acc[mg][ng] = __builtin_amdgcn_mfma_f32_16x16x32_bf16(af[mg], bf[ng], acc[mg][ng], 0, 0, 0);
    }
    __syncthreads();
  }
  if (EPI == 3) {
#pragma unroll
    for (int mg = 0; mg < 2; ++mg)
#pragma unroll
      for (int ng = 0; ng < 2; ++ng) {
        int col = n0 + wc * 32 + ng * 16 + fr;
#pragma unroll
        for (int j = 0; j < 4; ++j) {
          int row = m0 + wr * 32 + mg * 16 + fc * 4 + j;
          atomicAdd(&C[(size_t)row * ldC + col], acc[mg][ng][j]);
        }
      }
  } else if (EPI == 0) {
    float* wst = (float*)smraw + wid * (16 * 36);
    int rr = lane >> 2, qq = lane & 3;
#pragma unroll
    for (int mg = 0; mg < 2; ++mg) {
#pragma unroll
      for (int ng = 0; ng < 2; ++ng)
#pragma unroll
        for (int j = 0; j < 4; ++j)
          wst[(fc * 4 + j) * 36 + ng * 16 + fr] = acc[mg][ng][j];
      __syncthreads();
      int row = m0 + wr * 32 + mg * 16 + rr;
      int col = n0 + wc * 32 + qq * 8;
      *(float4*)&C[(size_t)row * ldC + col]     = *(const float4*)&wst[rr * 36 + qq * 8];
      *(float4*)&C[(size_t)row * ldC + col + 4] = *(const float4*)&wst[rr * 36 + qq * 8 + 4];
      __syncthreads();
    }
  } else {
    unsigned short* wst = (unsigned short*)smraw + wid * (16 * 40);
    int rr = lane >> 2, qq = lane & 3;
#pragma unroll
    for (int mg = 0; mg < 2; ++mg) {
#pragma unroll
      for (int ng = 0; ng < 2; ++ng)
#pragma unroll
        for (int j = 0; j < 4; ++j)
          wst[(fc * 4 + j) * 40 + ng * 16 + fr] = f2b(geluf(acc[mg][ng][j]));
      __syncthreads();
      int row = m0 + wr * 32 + mg * 16 + rr;
      int col = n0 + wc * 32 + qq * 8;
      *(short8*)&Cb[(size_t)row * ldC + col] = *(const short8*)&wst[rr * 40 + qq * 8];
      __syncthreads();
    }
  }
}

// ---------------- dual 64-tile GEMM (BK=64): blocks [0,nb0) gemm0, rest gemm1 ----------------
__global__ __launch_bounds__(256) void gemm_dual(
    const unsigned short* __restrict__ A0, const unsigned short* __restrict__ B0t,
    float* __restrict__ C0, int K0, int ld0, int nx0, int nb0,
    const unsigned short* __restrict__ A1, const unsigned short* __restrict__ B1t,
    float* __restrict__ C1, int K1, int ld1, int nx1)
{
  __shared__ __align__(16) char smraw[16384];
  unsigned short* As = (unsigned short*)smraw;
  unsigned short* Bs = (unsigned short*)smraw + 4096;
  int b = blockIdx.x;
  const unsigned short *A, *Bt; float* C; int K, ldC, bx, by;
  if (b < nb0) { A = A0; Bt = B0t; C = C0; K = K0; ldC = ld0; bx = b % nx0; by = b / nx0; }
  else { b -= nb0; A = A1; Bt = B1t; C = C1; K = K1; ldC = ld1; bx = b % nx1; by = b / nx1; }
  int tid = threadIdx.x;
  int wid = tid >> 6, lane = tid & 63;
  int m0 = by * 64, n0 = bx * 64;
  int wr = wid >> 1, wc = wid & 1;
  int r0 = tid >> 3, ch = tid & 7;
  int scs = (ch ^ (r0 & 7)) * 8;
  const unsigned short* ga = A  + (size_t)(m0 + r0) * K + scs;
  const unsigned short* gb = Bt + (size_t)(n0 + r0) * K + scs;
  unsigned short* la = As + wid * 512;
  unsigned short* lb = Bs + wid * 512;
  int fr = lane & 15, fc = lane >> 4;
  f32x4 zz = {0.f, 0.f, 0.f, 0.f};
  f32x4 acc[2][2];
  acc[0][0] = zz; acc[0][1] = zz; acc[1][0] = zz; acc[1][1] = zz;
  size_t row32 = (size_t)32 * K;
  for (int k0 = 0; k0 < K; k0 += 64) {
    GLDS(ga + k0, la);
    GLDS(ga + k0 + row32, la + 2048);
    GLDS(gb + k0, lb);
    GLDS(gb + k0 + row32, lb + 2048);
    __syncthreads();
#pragma unroll
    for (int kh = 0; kh < 2; ++kh) {
      short8 af[2], bf[2];
#pragma unroll
      for (int mg = 0; mg < 2; ++mg) {
        int ar = wr * 32 + mg * 16 + fr;
        af[mg] = *reinterpret_cast<const short8*>(&As[ar * 64 + (((kh * 4 + fc) ^ (ar & 7)) * 8)]);
      }
#pragma unroll
      for (int ng = 0; ng < 2; ++ng) {
        int br = wc * 32 + ng * 16 + fr;
        bf[ng] = *reinterpret_cast<const short8*>(&Bs[br * 64 + (((kh * 4 + fc) ^ (br & 7)) * 8)]);
      }
#pragma unroll
      for (int mg = 0; mg < 2; ++mg)
#pragma unroll
        for (int ng = 0; ng < 2; ++ng)
          acc[mg][ng] = __builtin_amdgcn_mfma_f32_16x16x32_bf16(af[mg], bf[ng], acc[mg][ng], 0, 0, 0);
    }
    __syncthreads();
  }
  float* wst = (float*)smraw + wid * (16 * 36);
  int rr = lane >> 2, qq = lane & 3;
#pragma unroll
  for (int mg = 0; mg < 2; ++mg) {
#pragma unroll
    for (int ng = 0; ng < 2; ++ng)
#pragma unroll
      for (int j = 0; j < 4; ++j)
        wst[(fc * 4 + j) * 36 + ng * 16 + fr] = acc[mg][ng][j];
    __syncthreads();
    int row = m0 + wr * 32 + mg * 16 + rr;
    int col = n0 + wc * 32 + qq * 8;
    *(float4*)&C[(size_t)row * ldC + col]     = *(const float4*)&wst[rr * 36 + qq * 8];
    *(float4*)&C[(size_t)row * ldC + col + 4] = *(const float4*)&wst[rr * 36 + qq * 8 + 4];
    __syncthreads();
  }
}

// ---------------- 128-tile bf16 MFMA GEMM (logits), BK=64, XCD-local swizzle + coalesced stores ----------------
// 1-D grid of 2000 blocks; each XCD (b%8) owns ~32 complete B-panels (all 8 m-tiles).
__global__ __launch_bounds__(256) void gemm128(
    const unsigned short* __restrict__ A, const unsigned short* __restrict__ Bt,
    float* __restrict__ C, int N, int K, int ldC)
{
  __shared__ __align__(16) char smraw[32768];
  unsigned short* As = (unsigned short*)smraw;          // [128][64]
  unsigned short* Bs = (unsigned short*)smraw + 8192;
  int tid = threadIdx.x;
  int wid = tid >> 6, lane = tid & 63;
  int bb = blockIdx.x;
  int xcd = bb & 7, ii = bb >> 3;
  int tt = xcd * 250 + ii;
  int m0 = (tt & 7) * 128, n0 = (tt >> 3) * 128;
  int wr = wid >> 1, wc = wid & 1;
  int r0 = tid >> 3, ch = tid & 7;
  int scs = (ch ^ (r0 & 7)) * 8;
  const unsigned short* ga = A  + (size_t)(m0 + r0) * K + scs;
  const unsigned short* gb = Bt + (size_t)(n0 + r0) * K + scs;
  int fr = lane & 15, fc = lane >> 4;
  f32x4 zz = {0.f, 0.f, 0.f, 0.f};
  f32x4 acc[4][4];
#pragma unroll
  for (int i = 0; i < 4; i++)
#pragma unroll
    for (int j = 0; j < 4; j++) acc[i][j] = zz;

  size_t row32 = (size_t)32 * K;
  for (int k0 = 0; k0 < K; k0 += 64) {
#pragma unroll
    for (int i = 0; i < 4; ++i) {
      GLDS(ga + k0 + i * row32, As + i * 2048 + wid * 512);
      GLDS(gb + k0 + i * row32, Bs + i * 2048 + wid * 512);
    }
    __syncthreads();
#pragma unroll
    for (int kh = 0; kh < 2; ++kh) {
      short8 af[4], bf[4];
#pragma unroll
      for (int mg = 0; mg < 4; ++mg) {
        int ar = wr * 64 + mg * 16 + fr;
        af[mg] = *reinterpret_cast<const short8*>(&As[ar * 64 + (((kh * 4 + fc) ^ (ar & 7)) * 8)]);
      }
#pragma unroll
      for (int ng = 0; ng < 4; ++ng) {
        int br = wc * 64 + ng * 16 + fr;
        bf[ng] = *reinterpret_cast<const short8*>(&Bs[br * 64 + (((kh * 4 + fc) ^ (br & 7)) * 8)]);
      }
#pragma unroll
      for (int mg = 0; mg < 4; ++mg)
#pragma unroll
        for (int ng = 0; ng < 4; ++ng)
          acc[mg][ng] = __builtin_amdgcn_mfma_f32_16x16x32_bf16(af[mg], bf[ng], acc[mg][ng], 0, 0, 0);
    }
    __syncthreads();
  }
  float* wst = (float*)smraw + wid * 1088;   // per-wave [16][68]
  int rr = lane >> 2, q = (lane & 3) * 16;
#pragma unroll
  for (int mg = 0; mg < 4; ++mg) {
#pragma unroll
    for (int ng = 0; ng < 4; ++ng)
#pragma unroll
      for (int j = 0; j < 4; ++j)
        wst[(fc * 4 + j) * 68 + ng * 16 + fr] = acc[mg][ng][j];
    __syncthreads();
    int row = m0 + wr * 64 + mg * 16 + rr;
    size_t rb = (size_t)row * ldC + n0 + wc * 64 + q;
#pragma unroll
    for (int i = 0; i < 4; ++i)
      *(float4*)&C[rb + i * 4] = *(const float4*)&wst[rr * 68 + q + i * 4];
    __syncthreads();
  }
}

// ---------------- merged weight transpose + fp32->bf16 (all jobs, one dispatch) ----------------
struct TCJob { const float* src; unsigned short* dst; int K, N, Npad, nx; size_t sStr, dStr; int tend; };
struct TC10 { TCJob j[10]; };

__global__ __launch_bounds__(256) void transconv_all(TC10 P)
{
  __shared__ float tile[32][33];
  int bid = blockIdx.x;
  int q = 0;
  while (bid >= P.j[q].tend) ++q;
  int tstart = (q == 0) ? 0 : P.j[q - 1].tend;
  TCJob jb = P.j[q];
  int local = bid - tstart;
  int bx = local % jb.nx, by = local / jb.nx;
  const float* src = jb.src + (size_t)blockIdx.y * jb.sStr;
  unsigned short* dst = jb.dst + (size_t)blockIdx.y * jb.dStr;
  int k0 = by * 32, n0 = bx * 32;
  int tx = threadIdx.x & 31, ty = threadIdx.x >> 5;
  for (int i = ty; i < 32; i += 8) {
    int k = k0 + i, n = n0 + tx;
    tile[i][tx] = (k < jb.K && n < jb.N) ? src[(size_t)k * jb.N + n] : 0.f;
  }
  __syncthreads();
  for (int i = ty; i < 32; i += 8) {
    int n = n0 + i, k = k0 + tx;
    if (n < jb.Npad && k < jb.K) dst[(size_t)n * jb.K + k] = f2b(tile[tx][i]);
  }
}

__global__ void conv_b16_kernel(const float* __restrict__ src, unsigned short* __restrict__ dst, int n)
{
  int idx = blockIdx.x * 256 + threadIdx.x;
  if (idx < n) dst[idx] = f2b(src[idx]);
}

// ---------------- embedding gather ----------------
__global__ void embed_kernel(const int* __restrict__ x, const float* __restrict__ embed,
                             float* __restrict__ h)
{
  int idx = blockIdx.x * 256 + threadIdx.x;
  if (idx < TT * DD) {
    int t = idx / DD, d = idx % DD;
    h[idx] = embed[(size_t)x[t] * DD + d];
  }
}

// ---------------- RMSNorm (wave per row) -> bf16 ----------------
__global__ __launch_bounds__(256) void rms_kernel(const float* __restrict__ in,
                                                  const float* __restrict__ w,
                                                  unsigned short* __restrict__ out)
{
  int row = blockIdx.x * 4 + (threadIdx.x >> 6);
  int lane = threadIdx.x & 63;
  const float* r = in + (size_t)row * DD;
  float v[6]; float ss = 0.f;
#pragma unroll
  for (int j = 0; j < 6; ++j) { v[j] = r[lane + j * 64]; ss = fmaf(v[j], v[j], ss); }
#pragma unroll
  for (int s = 1; s < 64; s <<= 1) ss += __shfl_xor(ss, s);
  float scale = rsqrtf(ss * (1.f / DD) + 1e-6f);
#pragma unroll
  for (int j = 0; j < 6; ++j)
    out[(size_t)row * DD + lane + j * 64] = f2b(w[lane + j * 64] * v[j] * scale);
}

// ---------------- Phase A: per-chunk local scans (decay, dt, conv1d all fused) ----------------
// blocks 0..191: RWKV (h = b>>5, chunk c = b&31); 192..575: Mamba (hh, c)
__global__ __launch_bounds__(256) void scanA_kernel(
    const float* __restrict__ PZ, const float* __restrict__ u, const float* __restrict__ wbias,
    float* __restrict__ so, float* __restrict__ rPb,
    float* __restrict__ MstR, float* __restrict__ DcR,
    const float* __restrict__ cw, const float* __restrict__ cbia,
    const float* __restrict__ dtbias,
    const float* __restrict__ Alog, const float* __restrict__ Dpw,
    float* __restrict__ yb, float* __restrict__ Ccb,
    float* __restrict__ MstM, float* __restrict__ DcM)
{
  __shared__ float smem[2 * 256 + 64];
  int b = blockIdx.x, tid = threadIdx.x;
  if (b < 192) {
    int h = b >> 5, c = b & 31;
    float* sbuf = smem; float* us = smem + 512;
    if (tid < 64) us[tid] = u[h * 64 + tid];
    int wv = tid >> 6, l = tid & 63;
    int vv = wv * 16 + (l & 15);
    int kc = l >> 4;
    int arr = tid >> 6, idx = tid & 63;
    int off = (arr == 0) ? 0 : (arr == 1) ? 384 : (arr == 2) ? W_OFF : 768;  // r,k,w(raw),v
    float wb = (arr == 2) ? wbias[h * 64 + idx] : 0.f;
    size_t base = (size_t)h * 64 + idx + off;
    int t0 = c * CHK;
    float S[16], Pc[16];
#pragma unroll
    for (int i = 0; i < 16; i++) { S[i] = 0.f; Pc[i] = 1.f; }
    float reg = PZ[(size_t)t0 * PZS + base];
    bool st = (wv == 0) && ((l & 15) == 0);   // 4 threads, kc = 0..3
    for (int t = 0; t < CHK; ++t) {
      int tt = t0 + t;
      float* cb = sbuf + (t & 1) * 256;
      cb[arr * 64 + idx] = (arr == 2) ? expf(-expf(reg + wb)) : reg;
      if (t + 1 < CHK) reg = PZ[(size_t)(tt + 1) * PZS + base];
      __syncthreads();
      float vt = cb[192 + vv];
      float acc = 0.f;
      float rp[16];
#pragma unroll
      for (int i = 0; i < 16; ++i) {
        int kk = kc * 16 + i;
        float rv = cb[kk], kv = cb[64 + kk], dv = cb[128 + kk];
        rp[i] = rv * Pc[i];
        float kvv = kv * vt;
        acc = fmaf(rv, fmaf(us[kk], kvv, S[i]), acc);
        S[i] = fmaf(dv, S[i], kvv);
        Pc[i] *= dv;
      }
      acc += __shfl_xor(acc, 16);
      acc += __shfl_xor(acc, 32);
      if (l < 16) so[(size_t)tt * DD + h * 64 + vv] = acc;
      if (st) {
        float4* dst = (float4*)&rPb[(size_t)tt * DD + h * 64 + kc * 16];
        dst[0] = make_float4(rp[0], rp[1], rp[2], rp[3]);
        dst[1] = make_float4(rp[4], rp[5], rp[6], rp[7]);
        dst[2] = make_float4(rp[8], rp[9], rp[10], rp[11]);
        dst[3] = make_float4(rp[12], rp[13], rp[14], rp[15]);
      }
    }
    float* ms = MstR + (size_t)(h * NCH + c) * 4096;   // [v][k]
    float4* msv = (float4*)&ms[vv * 64 + kc * 16];
    msv[0] = make_float4(S[0], S[1], S[2], S[3]);
    msv[1] = make_float4(S[4], S[5], S[6], S[7]);
    msv[2] = make_float4(S[8], S[9], S[10], S[11]);
    msv[3] = make_float4(S[12], S[13], S[14], S[15]);
    if (st) {
      float4* dd_ = (float4*)&DcR[(h * NCH + c) * 64 + kc * 16];
      dd_[0] = make_float4(Pc[0], Pc[1], Pc[2], Pc[3]);
      dd_[1] = make_float4(Pc[4], Pc[5], Pc[6], Pc[7]);
      dd_[2] = make_float4(Pc[8], Pc[9], Pc[10], Pc[11]);
      dd_[3] = make_float4(Pc[12], Pc[13], Pc[14], Pc[15]);
    }
  } else {
    int bb = b - 192;
    int hh = bb >> 5, c = bb & 31;
    float* sbuf = smem;
    int wv = tid >> 6, l = tid & 63;
    int p = wv * 16 + (l & 15);
    int sc = l >> 4;
    int arr = tid >> 6, idx = tid & 63;
    float A = -expf(Alog[hh]);
    float Dph = Dpw[hh];
    float dtbh = dtbias[hh];
    int t0 = c * CHK;
    float cw0 = 0.f, cw1 = 0.f, cw2 = 0.f, cw3 = 0.f, cbv = 0.f;
    float xw0 = 0.f, xw1 = 0.f, xw2 = 0.f, cur = 0.f;
    const float* xcol = nullptr;
    float reg = 0.f;
    if (arr < 3) {
      int chn = (arr == 0) ? (hh * 64 + idx) : (arr == 1) ? (DI + idx) : (DI + DS + idx);
      cw0 = cw[chn * 4 + 0]; cw1 = cw[chn * 4 + 1]; cw2 = cw[chn * 4 + 2]; cw3 = cw[chn * 4 + 3];
      cbv = cbia[chn];
      xcol = PZ + XBC_OFF + chn;
      xw0 = (t0 >= 3) ? xcol[(size_t)(t0 - 3) * PZS] : 0.f;
      xw1 = (t0 >= 2) ? xcol[(size_t)(t0 - 2) * PZS] : 0.f;
      xw2 = (t0 >= 1) ? xcol[(size_t)(t0 - 1) * PZS] : 0.f;
      cur = xcol[(size_t)t0 * PZS];
    } else {
      reg = PZ[(size_t)t0 * PZS + DT_OFF + hh];
    }
    float S[16]; float cdA = 1.f;
#pragma unroll
    for (int i = 0; i < 16; i++) S[i] = 0.f;
    bool st = (wv == 0) && ((l & 15) == 0);
    for (int t = 0; t < CHK; ++t) {
      int tt = t0 + t;
      float* cb = sbuf + (t & 1) * 256;
      if (arr < 3) {
        float cvv = fmaf(cw3, cur, fmaf(cw2, xw2, fmaf(cw1, xw1, fmaf(cw0, xw0, cbv))));
        cb[arr * 64 + idx] = siluf(cvv);
        float nx = (t + 1 < CHK) ? xcol[(size_t)(tt + 1) * PZS] : 0.f;
        xw0 = xw1; xw1 = xw2; xw2 = cur; cur = nx;
      } else {
        if (idx == 0) {
          float v = reg + dtbh;
          cb[192] = (v > 20.f) ? v : log1pf(expf(v));
        }
        if (t + 1 < CHK) reg = PZ[(size_t)(tt + 1) * PZS + DT_OFF + hh];
      }
      __syncthreads();
      float dt_ = cb[192];
      float dA = expf(dt_ * A);
      cdA *= dA;
      float xp = cb[p];
      float dtx = dt_ * xp;
      float acc = 0.f;
#pragma unroll
      for (int i = 0; i < 16; ++i) {
        int s = sc * 16 + i;
        S[i] = fmaf(dA, S[i], dtx * cb[64 + s]);
        acc = fmaf(S[i], cb[128 + s], acc);
      }
      acc += __shfl_xor(acc, 16);
      acc += __shfl_xor(acc, 32);
      if (l < 16) yb[(size_t)tt * DI + hh * 64 + p] = fmaf(Dph, xp, acc);
      if (st) {
        float4* dst = (float4*)&Ccb[(size_t)tt * DI + hh * 64 + sc * 16];
#pragma unroll
        for (int j4 = 0; j4 < 4; ++j4)
          dst[j4] = make_float4(cdA * cb[128 + sc * 16 + j4 * 4 + 0],
                                cdA * cb[128 + sc * 16 + j4 * 4 + 1],
                                cdA * cb[128 + sc * 16 + j4 * 4 + 2],
                                cdA * cb[128 + sc * 16 + j4 * 4 + 3]);
      }
    }
    float* ms = MstM + (size_t)(hh * NCH + c) * 4096;  // [p][s]
    float4* msv = (float4*)&ms[p * 64 + sc * 16];
    msv[0] = make_float4(S[0], S[1], S[2], S[3]);
    msv[1] = make_float4(S[4], S[5], S[6], S[7]);
    msv[2] = make_float4(S[8], S[9], S[10], S[11]);
    msv[3] = make_float4(S[12], S[13], S[14], S[15]);
    if (tid == 0) DcM[hh * NCH + c] = cdA;
  }
}

// ---------------- Phase C: prefix-combine + output correction (+ fused RWKV groupnorm*silu) ----------------
__global__ __launch_bounds__(256) void corr_kernel(
    const float* __restrict__ MstR, const float* __restrict__ DcR,
    const float* __restrict__ rPb, const float* __restrict__ so,
    const float* __restrict__ MstM, const float* __restrict__ DcM,
    const float* __restrict__ Ccb, float* __restrict__ yb,
    const float* __restrict__ PZ, const float* __restrict__ gnw, const float* __restrict__ gnb,
    unsigned short* __restrict__ gob)
{
  __shared__ float S0l[64 * 68];
  __shared__ float Rl[CHK * 68];
  int b = blockIdx.x, tid = threadIdx.x;
  const float* rg; int ostride, obase, t0;
  bool rwkv = (b < 192);
  int h, cidx;
  if (rwkv) {
    h = b >> 5; cidx = b & 31;
    rg = rPb; obase = h * 64; ostride = DD;
  } else {
    int bb = b - 192; h = bb >> 5; cidx = bb & 31;
    rg = Ccb; obase = h * 64; ostride = DI;
  }
  t0 = cidx * CHK;
  float Sreg[16];
#pragma unroll
  for (int it = 0; it < 16; ++it) Sreg[it] = 0.f;
  if (rwkv) {
    int kk = tid & 63;
    for (int cp = 0; cp < cidx; ++cp) {
      float d = DcR[(h * NCH + cp) * 64 + kk];
      const float* mb = MstR + (size_t)(h * NCH + cp) * 4096;
#pragma unroll
      for (int it = 0; it < 16; ++it)
        Sreg[it] = fmaf(d, Sreg[it], mb[tid + 256 * it]);
    }
  } else {
    for (int cp = 0; cp < cidx; ++cp) {
      float d = DcM[h * NCH + cp];
      const float* mb = MstM + (size_t)(h * NCH + cp) * 4096;
#pragma unroll
      for (int it = 0; it < 16; ++it)
        Sreg[it] = fmaf(d, Sreg[it], mb[tid + 256 * it]);
    }
  }
#pragma unroll
  for (int it = 0; it < 16; ++it) {
    int gi = tid + 256 * it;
    S0l[(gi & 63) * 68 + (gi >> 6)] = Sreg[it];
  }
  {
    int t = tid >> 3, q = (tid & 7) * 8;
    const float4* src = (const float4*)&rg[(size_t)(t0 + t) * ostride + obase + q];
    float4* dst = (float4*)&Rl[t * 68 + q];
    dst[0] = src[0]; dst[1] = src[1];
  }
  __syncthreads();
  int t = tid >> 3, q = (tid & 7) * 8;
  float acc[8];
#pragma unroll
  for (int j = 0; j < 8; j++) acc[j] = 0.f;
  for (int k = 0; k < 64; ++k) {
    float rv = Rl[t * 68 + k];
    const float4* sp = (const float4*)&S0l[k * 68 + q];
    float4 s0 = sp[0], s1 = sp[1];
    acc[0] = fmaf(rv, s0.x, acc[0]);
    acc[1] = fmaf(rv, s0.y, acc[1]);
    acc[2] = fmaf(rv, s0.z, acc[2]);
    acc[3] = fmaf(rv, s0.w, acc[3]);
    acc[4] = fmaf(rv, s1.x, acc[4]);
    acc[5] = fmaf(rv, s1.y, acc[5]);
    acc[6] = fmaf(rv, s1.z, acc[6]);
    acc[7] = fmaf(rv, s1.w, acc[7]);
  }
  if (!rwkv) {
    float4* op = (float4*)&yb[(size_t)(t0 + t) * DI + obase + q];
    float4 c0 = op[0], c1 = op[1];
    c0.x += acc[0]; c0.y += acc[1]; c0.z += acc[2]; c0.w += acc[3];
    c1.x += acc[4]; c1.y += acc[5]; c1.z += acc[6]; c1.w += acc[7];
    op[0] = c0; op[1] = c1;
  } else {
    float ov[8];
    const float4* sp = (const float4*)&so[(size_t)(t0 + t) * DD + obase + q];
    float4 s0 = sp[0], s1 = sp[1];
    ov[0] = s0.x + acc[0]; ov[1] = s0.y + acc[1]; ov[2] = s0.z + acc[2]; ov[3] = s0.w + acc[3];
    ov[4] = s1.x + acc[4]; ov[5] = s1.y + acc[5]; ov[6] = s1.z + acc[6]; ov[7] = s1.w + acc[7];
    float m_ = 0.f;
#pragma unroll
    for (int j = 0; j < 8; j++) m_ += ov[j];
    m_ += __shfl_xor(m_, 1); m_ += __shfl_xor(m_, 2); m_ += __shfl_xor(m_, 4);
    float mu = m_ * (1.f / 64.f);
    float vv = 0.f;
#pragma unroll
    for (int j = 0; j < 8; j++) { float d = ov[j] - mu; vv = fmaf(d, d, vv); }
    vv += __shfl_xor(vv, 1); vv += __shfl_xor(vv, 2); vv += __shfl_xor(vv, 4);
    float rstd = rsqrtf(vv * (1.f / 64.f) + 1e-5f);
#pragma unroll
    for (int j = 0; j < 8; j++) {
      int d = obase + q + j;
      float gv = PZ[(size_t)(t0 + t) * PZS + G_OFF + d];
      float o = fmaf((ov[j] - mu) * rstd, gnw[d], gnb[d]) * siluf(gv);
      gob[(size_t)(t0 + t) * DD + d] = f2b(o);
    }
  }
}

// ---------------- Mamba out: rms(y * silu(z), mn_w) -> bf16 (wave per row) ----------------
__global__ __launch_bounds__(256) void mamba_norm_kernel(const float* __restrict__ yb,
    const float* __restrict__ PZ, const float* __restrict__ mnw, unsigned short* __restrict__ out)
{
  int row = blockIdx.x * 4 + (threadIdx.x >> 6);
  int lane = threadIdx.x & 63;
  float v[12]; float ss = 0.f;
#pragma unroll
  for (int j = 0; j < 12; ++j) {
    int c = lane + j * 64;
    float z = PZ[(size_t)row * PZS + Z_OFF + c];
    float t = yb[(size_t)row * DI + c] * siluf(z);
    v[j] = t; ss = fmaf(t, t, ss);
  }
#pragma unroll
  for (int s = 1; s < 64; s <<= 1) ss += __shfl_xor(ss, s);
  float scale = rsqrtf(ss * (1.f / DI) + 1e-6f);
#pragma unroll
  for (int j = 0; j < 12; ++j) {
    int c = lane + j * 64;
    out[(size_t)row * DI + c] = f2b(v[j] * scale * mnw[c]);
  }
}

// ---------------- gate combine + FFN RMSNorm (wave per row) ----------------
__global__ __launch_bounds__(256) void gate_rms_kernel(const float* __restrict__ orb,
    const float* __restrict__ omb, const float* __restrict__ gw,
    const float* __restrict__ gb, const float* __restrict__ flnw,
    float* __restrict__ h, unsigned short* __restrict__ xnb)
{
  int row = blockIdx.x * 4 + (threadIdx.x >> 6);
  int lane = threadIdx.x & 63;
  float a[6], bq[6]; float ss = 0.f;
#pragma unroll
  for (int j = 0; j < 6; ++j) {
    int c = lane + j * 64;
    a[j] = orb[(size_t)row * DD + c]; bq[j] = omb[(size_t)row * DD + c];
    ss += a[j] * gw[c] + bq[j] * gw[DD + c];
  }
#pragma unroll
  for (int s = 1; s < 64; s <<= 1) ss += __shfl_xor(ss, s);
  float gate = sigmoidf_(ss + gb[0]);
  float hn[6]; float ss2 = 0.f;
#pragma unroll
  for (int j = 0; j < 6; ++j) {
    int c = lane + j * 64;
    size_t ix = (size_t)row * DD + c;
    hn[j] = h[ix] + gate * a[j] + (1.f - gate) * bq[j];
    h[ix] = hn[j];
    ss2 = fmaf(hn[j], hn[j], ss2);
  }
#pragma unroll
  for (int s = 1; s < 64; s <<= 1) ss2 += __shfl_xor(ss2, s);
  float scale = rsqrtf(ss2 * (1.f / DD) + 1e-6f);
#pragma unroll
  for (int j = 0; j < 6; ++j) {
    int c = lane + j * 64;
    xnb[(size_t)row * DD + c] = f2b(flnw[c] * hn[j] * scale);
  }
}

// ---------------- launcher ----------------
extern "C" void kernel_launch(void* const* d_in, const int* in_sizes, int n_in,
                              void* d_out, int out_size, void* d_ws, size_t ws_size,
                              hipStream_t stream)
{
  const int*   x        = (const int*)  d_in[0];
  const float* embed    = (const float*)d_in[1];
  const float* ln_w     = (const float*)d_in[2];
  const float* Wr       = (const float*)d_in[3];
  const float* Wk       = (const float*)d_in[4];
  const float* Wv       = (const float*)d_in[5];
  const float* Wg       = (const float*)d_in[6];
  const float* Ww       = (const float*)d_in[7];
  const float* w_bias   = (const float*)d_in[8];
  const float* u        = (const float*)d_in[9];
  const float* gn_w     = (const float*)d_in[10];
  const float* gn_b     = (const float*)d_in[11];
  const float* Wo       = (const float*)d_in[12];
  const float* W_in     = (const float*)d_in[13];
  const float* conv_w   = (const float*)d_in[14];
  const float* conv_b   = (const float*)d_in[15];
  const float* dt_bias  = (const float*)d_in[16];
  const float* A_log    = (const float*)d_in[17];
  const float* Dp       = (const float*)d_in[18];
  const float* mn_w     = (const float*)d_in[19];
  const float* W_out    = (const float*)d_in[20];
  const float* gw       = (const float*)d_in[21];
  const float* gb       = (const float*)d_in[22];
  const float* ffn_ln_w = (const float*)d_in[23];
  const float* ffn_w1   = (const float*)d_in[24];
  const float* ffn_w2   = (const float*)d_in[25];
  const float* ln_out_w = (const float*)d_in[26];

  char* base = (char*)d_ws;
  size_t off = 0;
  auto alloc = [&](size_t bytes) { off = (off + 255) & ~(size_t)255; void* p = base + off; off += bytes; return p; };

  float* h    = (float*)alloc((size_t)TT * DD * 4);
  float* PZ   = (float*)alloc((size_t)TT * PZS * 4);
  float* yb   = (float*)alloc((size_t)TT * DI * 4);
  float* so   = (float*)alloc((size_t)TT * DD * 4);
  float* orb  = (float*)alloc((size_t)TT * DD * 4);
  float* omb  = (float*)alloc((size_t)TT * DD * 4);
  float* rPb  = (float*)alloc((size_t)TT * DD * 4);
  float* Ccb  = (float*)alloc((size_t)TT * DI * 4);
  float* MstR = (float*)alloc((size_t)NH * NCH * 4096 * 4);
  float* DcR  = (float*)alloc((size_t)NH * NCH * 64 * 4);
  float* MstM = (float*)alloc((size_t)MH * NCH * 4096 * 4);
  float* DcM  = (float*)alloc((size_t)MH * NCH * 4);
  unsigned short* xnb = (unsigned short*)alloc((size_t)TT * DD * 2);
  unsigned short* gob = (unsigned short*)alloc((size_t)TT * DD * 2);
  unsigned short* ynb = (unsigned short*)alloc((size_t)TT * DI * 2);
  unsigned short* fhb = (unsigned short*)alloc((size_t)TT * 1536 * 2);
  unsigned short* WallT = (unsigned short*)alloc((size_t)NL * PZS * 384 * 2);
  unsigned short* WoT   = (unsigned short*)alloc((size_t)NL * 384 * 384 * 2);
  unsigned short* WoutT = (unsigned short*)alloc((size_t)NL * 384 * 768 * 2);
  unsigned short* F1T   = (unsigned short*)alloc((size_t)NL * 1536 * 384 * 2);
  unsigned short* F2T   = (unsigned short*)alloc((size_t)NL * 384 * 1536 * 2);
  unsigned short* embB  = (unsigned short*)alloc((size_t)NV * DD * 2);
  (void)ws_size; (void)in_sizes; (void)n_in; (void)out_size;

  dim3 blk(256);
  int gTD = (TT * DD + 255) / 256;

  // ---- one-time (per launch) weight conversion, single dispatch ----
  TC10 tc;
  int te = 0;
  auto setjob = [&](int q, const float* src, unsigned short* dst, int K, int N, int Npad,
                    int nx, int ny, size_t sStr, size_t dStr) {
    te += nx * ny;
    tc.j[q] = TCJob{src, dst, K, N, Npad, nx, sStr, dStr, te};
  };
  setjob(0, Wr, WallT + (size_t)0 * 384 * 384, 384, 384, 384, 12, 12, (size_t)384 * 384, (size_t)PZS * 384);
  setjob(1, Wk, WallT + (size_t)1 * 384 * 384, 384, 384, 384, 12, 12, (size_t)384 * 384, (size_t)PZS * 384);
  setjob(2, Wv, WallT + (size_t)2 * 384 * 384, 384, 384, 384, 12, 12, (size_t)384 * 384, (size_t)PZS * 384);
  setjob(3, Wg, WallT + (size_t)3 * 384 * 384, 384, 384, 384, 12, 12, (size_t)384 * 384, (size_t)PZS * 384);
  setjob(4, Ww, WallT + (size_t)4 * 384 * 384, 384, 384, 384, 12, 12, (size_t)384 * 384, (size_t)PZS * 384);
  setjob(5, W_in, WallT + (size_t)1920 * 384, 384, XDIM, 1792, 56, 12, (size_t)384 * XDIM, (size_t)PZS * 384);
  setjob(6, Wo, WoT, 384, 384, 384, 12, 12, (size_t)384 * 384, (size_t)384 * 384);
  setjob(7, W_out, WoutT, 768, 384, 384, 12, 24, (size_t)768 * 384, (size_t)384 * 768);
  setjob(8, ffn_w1, F1T, 384, 1536, 1536, 48, 12, (size_t)384 * 1536, (size_t)1536 * 384);
  setjob(9, ffn_w2, F2T, 1536, 384, 384, 12, 48, (size_t)1536 * 384, (size_t)384 * 1536);
  transconv_all<<<dim3(te, 8), blk, 0, stream>>>(tc);
  conv_b16_kernel<<<(NV * DD + 255) / 256, blk, 0, stream>>>(embed, embB, NV * DD);
  embed_kernel<<<gTD, blk, 0, stream>>>(x, embed, h);

  for (int i = 0; i < NL; ++i) {
    rms_kernel<<<256, blk, 0, stream>>>(h, ln_w + (size_t)i * DD, xnb);

    gemm_bf16<0><<<dim3(58, 16), blk, 0, stream>>>(
        xnb, WallT + (size_t)i * PZS * 384, PZ, nullptr, PZS, 384, PZS);

    scanA_kernel<<<576, blk, 0, stream>>>(PZ, u + (size_t)i * NH * 64, w_bias + (size_t)i * DD,
                                          so, rPb, MstR, DcR,
                                          conv_w + (size_t)i * CONVC * 4, conv_b + (size_t)i * CONVC,
                                          dt_bias + (size_t)i * MH,
                                          A_log + (size_t)i * MH, Dp + (size_t)i * MH,
                                          yb, Ccb, MstM, DcM);
    corr_kernel<<<576, blk, 0, stream>>>(MstR, DcR, rPb, so, MstM, DcM, Ccb, yb,
                                         PZ, gn_w + (size_t)i * DD, gn_b + (size_t)i * DD, gob);

    mamba_norm_kernel<<<256, blk, 0, stream>>>(yb, PZ, mn_w + (size_t)i * DI, ynb);

    gemm_dual<<<192, blk, 0, stream>>>(
        gob, WoT + (size_t)i * 384 * 384, orb, 384, DD, 6, 96,
        ynb, WoutT + (size_t)i * 384 * 768, omb, 768, DD, 6);

    gate_rms_kernel<<<256, blk, 0, stream>>>(orb, omb, gw + (size_t)i * 2 * DD, gb + i,
                                             ffn_ln_w + (size_t)i * DD, h, xnb);

    gemm_bf16<1><<<dim3(24, 16), blk, 0, stream>>>(
        xnb, F1T + (size_t)i * 1536 * 384, nullptr, fhb, 1536, 384, 1536);
    gemm_bf16<3><<<dim3(6, 16, 4), blk, 0, stream>>>(
        fhb, F2T + (size_t)i * 384 * 1536, h, nullptr, 384, 1536, 384);
  }

  rms_kernel<<<256, blk, 0, stream>>>(h, ln_out_w, xnb);
  gemm128<<<dim3(2000), blk, 0, stream>>>(
      xnb, embB, (float*)d_out, NV, 384, NV);
}

// Round 12
// 993.953 us; speedup vs baseline: 11.5309x; 1.0147x over previous
//
#include <hip/hip_runtime.h>
#include <math.h>

#define TT 1024
#define DD 384
#define NH 6
#define DI 768
#define MH 12
#define DS 64
#define NL 8
#define XDIM 1676   // 2*DI + 2*DS + MH
#define CONVC 896   // DI + 2*DS
#define NV 32000
#define PZS 3712    // fused output width: [r|k|v|g|w](1920) + [z|xBC|dt](1792 padded)
#define G_OFF 1152
#define W_OFF 1536
#define Z_OFF 1920
#define XBC_OFF 2688   // Z_OFF + DI
#define DT_OFF 3584    // Z_OFF + 1664
#define CHK 32      // scan chunk length
#define NCH 32      // number of chunks

typedef __attribute__((ext_vector_type(8))) short short8;
typedef __attribute__((ext_vector_type(4))) float f32x4;

// ---------------- helpers ----------------
__device__ __forceinline__ float siluf(float x) { return x / (1.f + expf(-x)); }
__device__ __forceinline__ float sigmoidf_(float x) { return 1.f / (1.f + expf(-x)); }
__device__ __forceinline__ float geluf(float x) {
  return 0.5f * x * (1.f + erff(x * 0.70710678118654752440f));
}
__device__ __forceinline__ unsigned short f2b(float x) {
  union { float f; unsigned int u; } v; v.f = x;
  unsigned int r = v.u + 0x7fffu + ((v.u >> 16) & 1u);
  return (unsigned short)(r >> 16);
}

#define GLDS(gp, lp) __builtin_amdgcn_global_load_lds( \
    (const __attribute__((address_space(1))) void*)(gp), \
    (__attribute__((address_space(3))) void*)(lp), 16, 0, 0)

// ---------------- 64-tile bf16 MFMA GEMM, BK=64. EPI: 0=f32, 1=gelu->bf16, 3=atomic-add ----------------
// Split-K via gridDim.z (K/gridDim.z must be divisible by 64). Scattered stores (best measured).
template<int EPI>
__global__ __launch_bounds__(256) void gemm_bf16(
    const unsigned short* __restrict__ A, const unsigned short* __restrict__ Bt,
    float* __restrict__ C, unsigned short* __restrict__ Cb, int N, int K, int ldC)
{
  __shared__ unsigned short As[4096];   // [64][64]
  __shared__ unsigned short Bs[4096];
  int tid = threadIdx.x;
  int wid = tid >> 6, lane = tid & 63;
  int m0 = blockIdx.y * 64, n0 = blockIdx.x * 64;
  int wr = wid >> 1, wc = wid & 1;
  int r0 = tid >> 3, ch = tid & 7;
  int scs = (ch ^ (r0 & 7)) * 8;
  const unsigned short* ga = A  + (size_t)(m0 + r0) * K + scs;
  const unsigned short* gb = Bt + (size_t)(n0 + r0) * K + scs;
  unsigned short* la = As + wid * 512;
  unsigned short* lb = Bs + wid * 512;
  int fr = lane & 15, fc = lane >> 4;
  f32x4 zz = {0.f, 0.f, 0.f, 0.f};
  f32x4 acc[2][2];
  acc[0][0] = zz; acc[0][1] = zz; acc[1][0] = zz; acc[1][1] = zz;

  int kper = K / (int)gridDim.z;
  int ks = blockIdx.z * kper, ke = ks + kper;
  size_t row32 = (size_t)32 * K;
  for (int k0 = ks; k0 < ke; k0 += 64) {
    GLDS(ga + k0, la);
    GLDS(ga + k0 + row32, la + 2048);
    GLDS(gb + k0, lb);
    GLDS(gb + k0 + row32, lb + 2048);
    __syncthreads();
#pragma unroll
    for (int kh = 0; kh < 2; ++kh) {
      short8 af[2], bf[2];
#pragma unroll
      for (int mg = 0; mg < 2; ++mg) {
        int ar = wr * 32 + mg * 16 + fr;
        af[mg] = *reinterpret_cast<const short8*>(&As[ar * 64 + (((kh * 4 + fc) ^ (ar & 7)) * 8)]);
      }
#pragma unroll
      for (int ng = 0; ng < 2; ++ng) {
        int br = wc * 32 + ng * 16 + fr;
        bf[ng] = *reinterpret_cast<const short8*>(&Bs[br * 64 + (((kh * 4 + fc) ^ (br & 7)) * 8)]);
      }
#pragma unroll
      for (int mg = 0; mg < 2; ++mg)
#pragma unroll
        for (int ng = 0; ng < 2; ++ng)
          acc[mg][ng] = __builtin_amdgcn_mfma_f32_16x16x32_bf16(af[mg], bf[ng], acc[mg][ng], 0, 0, 0);
    }
    __syncthreads();
  }
#pragma unroll
  for (int mg = 0; mg < 2; ++mg)
#pragma unroll
    for (int ng = 0; ng < 2; ++ng) {
      int col = n0 + wc * 32 + ng * 16 + fr;
      if (col < N) {
#pragma unroll
        for (int j = 0; j < 4; ++j) {
          int row = m0 + wr * 32 + mg * 16 + fc * 4 + j;
          if (EPI == 1)      Cb[(size_t)row * ldC + col] = f2b(geluf(acc[mg][ng][j]));
          else if (EPI == 3) atomicAdd(&C[(size_t)row * ldC + col], acc[mg][ng][j]);
          else               C[(size_t)row * ldC + col]  = acc[mg][ng][j];
        }
      }
    }
}

// ---------------- dual 64-tile GEMM (BK=64): blocks [0,nb0) gemm0, rest gemm1 ----------------
__global__ __launch_bounds__(256) void gemm_dual(
    const unsigned short* __restrict__ A0, const unsigned short* __restrict__ B0t,
    float* __restrict__ C0, int K0, int ld0, int nx0, int nb0,
    const unsigned short* __restrict__ A1, const unsigned short* __restrict__ B1t,
    float* __restrict__ C1, int K1, int ld1, int nx1)
{
  __shared__ unsigned short As[4096];
  __shared__ unsigned short Bs[4096];
  int b = blockIdx.x;
  const unsigned short *A, *Bt; float* C; int K, ldC, bx, by;
  if (b < nb0) { A = A0; Bt = B0t; C = C0; K = K0; ldC = ld0; bx = b % nx0; by = b / nx0; }
  else { b -= nb0; A = A1; Bt = B1t; C = C1; K = K1; ldC = ld1; bx = b % nx1; by = b / nx1; }
  int tid = threadIdx.x;
  int wid = tid >> 6, lane = tid & 63;
  int m0 = by * 64, n0 = bx * 64;
  int wr = wid >> 1, wc = wid & 1;
  int r0 = tid >> 3, ch = tid & 7;
  int scs = (ch ^ (r0 & 7)) * 8;
  const unsigned short* ga = A  + (size_t)(m0 + r0) * K + scs;
  const unsigned short* gb = Bt + (size_t)(n0 + r0) * K + scs;
  unsigned short* la = As + wid * 512;
  unsigned short* lb = Bs + wid * 512;
  int fr = lane & 15, fc = lane >> 4;
  f32x4 zz = {0.f, 0.f, 0.f, 0.f};
  f32x4 acc[2][2];
  acc[0][0] = zz; acc[0][1] = zz; acc[1][0] = zz; acc[1][1] = zz;
  size_t row32 = (size_t)32 * K;
  for (int k0 = 0; k0 < K; k0 += 64) {
    GLDS(ga + k0, la);
    GLDS(ga + k0 + row32, la + 2048);
    GLDS(gb + k0, lb);
    GLDS(gb + k0 + row32, lb + 2048);
    __syncthreads();
#pragma unroll
    for (int kh = 0; kh < 2; ++kh) {
      short8 af[2], bf[2];
#pragma unroll
      for (int mg = 0; mg < 2; ++mg) {
        int ar = wr * 32 + mg * 16 + fr;
        af[mg] = *reinterpret_cast<const short8*>(&As[ar * 64 + (((kh * 4 + fc) ^ (ar & 7)) * 8)]);
      }
#pragma unroll
      for (int ng = 0; ng < 2; ++ng) {
        int br = wc * 32 + ng * 16 + fr;
        bf[ng] = *reinterpret_cast<const short8*>(&Bs[br * 64 + (((kh * 4 + fc) ^ (br & 7)) * 8)]);
      }
#pragma unroll
      for (int mg = 0; mg < 2; ++mg)
#pragma unroll
        for (int ng = 0; ng < 2; ++ng)
          acc[mg][ng] = __builtin_amdgcn_mfma_f32_16x16x32_bf16(af[mg], bf[ng], acc[mg][ng], 0, 0, 0);
    }
    __syncthreads();
  }
#pragma unroll
  for (int mg = 0; mg < 2; ++mg)
#pragma unroll
    for (int ng = 0; ng < 2; ++ng) {
      int col = n0 + wc * 32 + ng * 16 + fr;
#pragma unroll
      for (int j = 0; j < 4; ++j) {
        int row = m0 + wr * 32 + mg * 16 + fc * 4 + j;
        C[(size_t)row * ldC + col] = acc[mg][ng][j];
      }
    }
}

// ---------------- 128-tile bf16 MFMA GEMM (logits), BK=64, XCD-local swizzle + staged stores ----------------
// 1-D grid of 2000 blocks; each XCD (b%8) owns ~32 complete B-panels (all 8 m-tiles).
__global__ __launch_bounds__(256) void gemm128(
    const unsigned short* __restrict__ A, const unsigned short* __restrict__ Bt,
    float* __restrict__ C, int N, int K, int ldC)
{
  __shared__ __align__(16) char smraw[32768];
  unsigned short* As = (unsigned short*)smraw;          // [128][64]
  unsigned short* Bs = (unsigned short*)smraw + 8192;
  int tid = threadIdx.x;
  int wid = tid >> 6, lane = tid & 63;
  int bb = blockIdx.x;
  int xcd = bb & 7, ii = bb >> 3;
  int tt = xcd * 250 + ii;
  int m0 = (tt & 7) * 128, n0 = (tt >> 3) * 128;
  int wr = wid >> 1, wc = wid & 1;
  int r0 = tid >> 3, ch = tid & 7;
  int scs = (ch ^ (r0 & 7)) * 8;
  const unsigned short* ga = A  + (size_t)(m0 + r0) * K + scs;
  const unsigned short* gb = Bt + (size_t)(n0 + r0) * K + scs;
  int fr = lane & 15, fc = lane >> 4;
  f32x4 zz = {0.f, 0.f, 0.f, 0.f};
  f32x4 acc[4][4];
#pragma unroll
  for (int i = 0; i < 4; i++)
#pragma unroll
    for (int j = 0; j < 4; j++) acc[i][j] = zz;

  size_t row32 = (size_t)32 * K;
  for (int k0 = 0; k0 < K; k0 += 64) {
#pragma unroll
    for (int i = 0; i < 4; ++i) {
      GLDS(ga + k0 + i * row32, As + i * 2048 + wid * 512);
      GLDS(gb + k0 + i * row32, Bs + i * 2048 + wid * 512);
    }
    __syncthreads();
#pragma unroll
    for (int kh = 0; kh < 2; ++kh) {
      short8 af[4], bf[4];
#pragma unroll
      for (int mg = 0; mg < 4; ++mg) {
        int ar = wr * 64 + mg * 16 + fr;
        af[mg] = *reinterpret_cast<const short8*>(&As[ar * 64 + (((kh * 4 + fc) ^ (ar & 7)) * 8)]);
      }
#pragma unroll
      for (int ng = 0; ng < 4; ++ng) {
        int br = wc * 64 + ng * 16 + fr;
        bf[ng] = *reinterpret_cast<const short8*>(&Bs[br * 64 + (((kh * 4 + fc) ^ (br & 7)) * 8)]);
      }
#pragma unroll
      for (int mg = 0; mg < 4; ++mg)
#pragma unroll
        for (int ng = 0; ng < 4; ++ng)
          acc[mg][ng] = __builtin_amdgcn_mfma_f32_16x16x32_bf16(af[mg], bf[ng], acc[mg][ng], 0, 0, 0);
    }
    __syncthreads();
  }
  float* wst = (float*)smraw + wid * 1088;   // per-wave [16][68], aliased onto As/Bs
  int rr = lane >> 2, q = (lane & 3) * 16;
#pragma unroll
  for (int mg = 0; mg < 4; ++mg) {
#pragma unroll
    for (int ng = 0; ng < 4; ++ng)
#pragma unroll
      for (int j = 0; j < 4; ++j)
        wst[(fc * 4 + j) * 68 + ng * 16 + fr] = acc[mg][ng][j];
    __syncthreads();
    int row = m0 + wr * 64 + mg * 16 + rr;
    size_t rb = (size_t)row * ldC + n0 + wc * 64 + q;
#pragma unroll
    for (int i = 0; i < 4; ++i)
      *(float4*)&C[rb + i * 4] = *(const float4*)&wst[rr * 68 + q + i * 4];
    __syncthreads();
  }
}

// ---------------- merged weight transpose + fp32->bf16 (all jobs, one dispatch) ----------------
struct TCJob { const float* src; unsigned short* dst; int K, N, Npad, nx; size_t sStr, dStr; int tend; };
struct TC10 { TCJob j[10]; };

__global__ __launch_bounds__(256) void transconv_all(TC10 P)
{
  __shared__ float tile[32][33];
  int bid = blockIdx.x;
  int q = 0;
  while (bid >= P.j[q].tend) ++q;
  int tstart = (q == 0) ? 0 : P.j[q - 1].tend;
  TCJob jb = P.j[q];
  int local = bid - tstart;
  int bx = local % jb.nx, by = local / jb.nx;
  const float* src = jb.src + (size_t)blockIdx.y * jb.sStr;
  unsigned short* dst = jb.dst + (size_t)blockIdx.y * jb.dStr;
  int k0 = by * 32, n0 = bx * 32;
  int tx = threadIdx.x & 31, ty = threadIdx.x >> 5;
  for (int i = ty; i < 32; i += 8) {
    int k = k0 + i, n = n0 + tx;
    tile[i][tx] = (k < jb.K && n < jb.N) ? src[(size_t)k * jb.N + n] : 0.f;
  }
  __syncthreads();
  for (int i = ty; i < 32; i += 8) {
    int n = n0 + i, k = k0 + tx;
    if (n < jb.Npad && k < jb.K) dst[(size_t)n * jb.K + k] = f2b(tile[tx][i]);
  }
}

__global__ void conv_b16_kernel(const float* __restrict__ src, unsigned short* __restrict__ dst, int n)
{
  int idx = blockIdx.x * 256 + threadIdx.x;
  if (idx < n) dst[idx] = f2b(src[idx]);
}

// ---------------- embedding gather ----------------
__global__ void embed_kernel(const int* __restrict__ x, const float* __restrict__ embed,
                             float* __restrict__ h)
{
  int idx = blockIdx.x * 256 + threadIdx.x;
  if (idx < TT * DD) {
    int t = idx / DD, d = idx % DD;
    h[idx] = embed[(size_t)x[t] * DD + d];
  }
}

// ---------------- RMSNorm (wave per row) -> bf16 ----------------
__global__ __launch_bounds__(256) void rms_kernel(const float* __restrict__ in,
                                                  const float* __restrict__ w,
                                                  unsigned short* __restrict__ out)
{
  int row = blockIdx.x * 4 + (threadIdx.x >> 6);
  int lane = threadIdx.x & 63;
  const float* r = in + (size_t)row * DD;
  float v[6]; float ss = 0.f;
#pragma unroll
  for (int j = 0; j < 6; ++j) { v[j] = r[lane + j * 64]; ss = fmaf(v[j], v[j], ss); }
#pragma unroll
  for (int s = 1; s < 64; s <<= 1) ss += __shfl_xor(ss, s);
  float scale = rsqrtf(ss * (1.f / DD) + 1e-6f);
#pragma unroll
  for (int j = 0; j < 6; ++j)
    out[(size_t)row * DD + lane + j * 64] = f2b(w[lane + j * 64] * v[j] * scale);
}

// ---------------- Phase A: per-chunk local scans (decay, dt, conv1d all fused) ----------------
// blocks 0..191: RWKV (h = b>>5, chunk c = b&31); 192..575: Mamba (hh, c)
__global__ __launch_bounds__(256) void scanA_kernel(
    const float* __restrict__ PZ, const float* __restrict__ u, const float* __restrict__ wbias,
    float* __restrict__ so, float* __restrict__ rPb,
    float* __restrict__ MstR, float* __restrict__ DcR,
    const float* __restrict__ cw, const float* __restrict__ cbia,
    const float* __restrict__ dtbias,
    const float* __restrict__ Alog, const float* __restrict__ Dpw,
    float* __restrict__ yb, float* __restrict__ Ccb,
    float* __restrict__ MstM, float* __restrict__ DcM)
{
  __shared__ float smem[2 * 256 + 64];
  int b = blockIdx.x, tid = threadIdx.x;
  if (b < 192) {
    int h = b >> 5, c = b & 31;
    float* sbuf = smem; float* us = smem + 512;
    if (tid < 64) us[tid] = u[h * 64 + tid];
    int wv = tid >> 6, l = tid & 63;
    int vv = wv * 16 + (l & 15);
    int kc = l >> 4;
    int arr = tid >> 6, idx = tid & 63;
    int off = (arr == 0) ? 0 : (arr == 1) ? 384 : (arr == 2) ? W_OFF : 768;  // r,k,w(raw),v
    float wb = (arr == 2) ? wbias[h * 64 + idx] : 0.f;
    size_t base = (size_t)h * 64 + idx + off;
    int t0 = c * CHK;
    float S[16], Pc[16];
#pragma unroll
    for (int i = 0; i < 16; i++) { S[i] = 0.f; Pc[i] = 1.f; }
    float reg = PZ[(size_t)t0 * PZS + base];
    bool st = (wv == 0) && ((l & 15) == 0);   // 4 threads, kc = 0..3
    for (int t = 0; t < CHK; ++t) {
      int tt = t0 + t;
      float* cb = sbuf + (t & 1) * 256;
      cb[arr * 64 + idx] = (arr == 2) ? expf(-expf(reg + wb)) : reg;
      if (t + 1 < CHK) reg = PZ[(size_t)(tt + 1) * PZS + base];
      __syncthreads();
      float vt = cb[192 + vv];
      float acc = 0.f;
      float rp[16];
#pragma unroll
      for (int i = 0; i < 16; ++i) {
        int kk = kc * 16 + i;
        float rv = cb[kk], kv = cb[64 + kk], dv = cb[128 + kk];
        rp[i] = rv * Pc[i];
        float kvv = kv * vt;
        acc = fmaf(rv, fmaf(us[kk], kvv, S[i]), acc);
        S[i] = fmaf(dv, S[i], kvv);
        Pc[i] *= dv;
      }
      acc += __shfl_xor(acc, 16);
      acc += __shfl_xor(acc, 32);
      if (l < 16) so[(size_t)tt * DD + h * 64 + vv] = acc;
      if (st) {
        float4* dst = (float4*)&rPb[(size_t)tt * DD + h * 64 + kc * 16];
        dst[0] = make_float4(rp[0], rp[1], rp[2], rp[3]);
        dst[1] = make_float4(rp[4], rp[5], rp[6], rp[7]);
        dst[2] = make_float4(rp[8], rp[9], rp[10], rp[11]);
        dst[3] = make_float4(rp[12], rp[13], rp[14], rp[15]);
      }
    }
    float* ms = MstR + (size_t)(h * NCH + c) * 4096;   // [v][k]
    float4* msv = (float4*)&ms[vv * 64 + kc * 16];
    msv[0] = make_float4(S[0], S[1], S[2], S[3]);
    msv[1] = make_float4(S[4], S[5], S[6], S[7]);
    msv[2] = make_float4(S[8], S[9], S[10], S[11]);
    msv[3] = make_float4(S[12], S[13], S[14], S[15]);
    if (st) {
      float4* dd_ = (float4*)&DcR[(h * NCH + c) * 64 + kc * 16];
      dd_[0] = make_float4(Pc[0], Pc[1], Pc[2], Pc[3]);
      dd_[1] = make_float4(Pc[4], Pc[5], Pc[6], Pc[7]);
      dd_[2] = make_float4(Pc[8], Pc[9], Pc[10], Pc[11]);
      dd_[3] = make_float4(Pc[12], Pc[13], Pc[14], Pc[15]);
    }
  } else {
    int bb = b - 192;
    int hh = bb >> 5, c = bb & 31;
    float* sbuf = smem;
    int wv = tid >> 6, l = tid & 63;
    int p = wv * 16 + (l & 15);
    int sc = l >> 4;
    int arr = tid >> 6, idx = tid & 63;
    float A = -expf(Alog[hh]);
    float Dph = Dpw[hh];
    float dtbh = dtbias[hh];
    int t0 = c * CHK;
    float cw0 = 0.f, cw1 = 0.f, cw2 = 0.f, cw3 = 0.f, cbv = 0.f;
    float xw0 = 0.f, xw1 = 0.f, xw2 = 0.f, cur = 0.f;
    const float* xcol = nullptr;
    float reg = 0.f;
    if (arr < 3) {
      int chn = (arr == 0) ? (hh * 64 + idx) : (arr == 1) ? (DI + idx) : (DI + DS + idx);
      cw0 = cw[chn * 4 + 0]; cw1 = cw[chn * 4 + 1]; cw2 = cw[chn * 4 + 2]; cw3 = cw[chn * 4 + 3];
      cbv = cbia[chn];
      xcol = PZ + XBC_OFF + chn;
      xw0 = (t0 >= 3) ? xcol[(size_t)(t0 - 3) * PZS] : 0.f;
      xw1 = (t0 >= 2) ? xcol[(size_t)(t0 - 2) * PZS] : 0.f;
      xw2 = (t0 >= 1) ? xcol[(size_t)(t0 - 1) * PZS] : 0.f;
      cur = xcol[(size_t)t0 * PZS];
    } else {
      reg = PZ[(size_t)t0 * PZS + DT_OFF + hh];
    }
    float S[16]; float cdA = 1.f;
#pragma unroll
    for (int i = 0; i < 16; i++) S[i] = 0.f;
    bool st = (wv == 0) && ((l & 15) == 0);
    for (int t = 0; t < CHK; ++t) {
      int tt = t0 + t;
      float* cb = sbuf + (t & 1) * 256;
      if (arr < 3) {
        float cvv = fmaf(cw3, cur, fmaf(cw2, xw2, fmaf(cw1, xw1, fmaf(cw0, xw0, cbv))));
        cb[arr * 64 + idx] = siluf(cvv);
        float nx = (t + 1 < CHK) ? xcol[(size_t)(tt + 1) * PZS] : 0.f;
        xw0 = xw1; xw1 = xw2; xw2 = cur; cur = nx;
      } else {
        if (idx == 0) {
          float v = reg + dtbh;
          cb[192] = (v > 20.f) ? v : log1pf(expf(v));
        }
        if (t + 1 < CHK) reg = PZ[(size_t)(tt + 1) * PZS + DT_OFF + hh];
      }
      __syncthreads();
      float dt_ = cb[192];
      float dA = expf(dt_ * A);
      cdA *= dA;
      float xp = cb[p];
      float dtx = dt_ * xp;
      float acc = 0.f;
#pragma unroll
      for (int i = 0; i < 16; ++i) {
        int s = sc * 16 + i;
        S[i] = fmaf(dA, S[i], dtx * cb[64 + s]);
        acc = fmaf(S[i], cb[128 + s], acc);
      }
      acc += __shfl_xor(acc, 16);
      acc += __shfl_xor(acc, 32);
      if (l < 16) yb[(size_t)tt * DI + hh * 64 + p] = fmaf(Dph, xp, acc);
      if (st) {
        float4* dst = (float4*)&Ccb[(size_t)tt * DI + hh * 64 + sc * 16];
#pragma unroll
        for (int j4 = 0; j4 < 4; ++j4)
          dst[j4] = make_float4(cdA * cb[128 + sc * 16 + j4 * 4 + 0],
                                cdA * cb[128 + sc * 16 + j4 * 4 + 1],
                                cdA * cb[128 + sc * 16 + j4 * 4 + 2],
                                cdA * cb[128 + sc * 16 + j4 * 4 + 3]);
      }
    }
    float* ms = MstM + (size_t)(hh * NCH + c) * 4096;  // [p][s]
    float4* msv = (float4*)&ms[p * 64 + sc * 16];
    msv[0] = make_float4(S[0], S[1], S[2], S[3]);
    msv[1] = make_float4(S[4], S[5], S[6], S[7]);
    msv[2] = make_float4(S[8], S[9], S[10], S[11]);
    msv[3] = make_float4(S[12], S[13], S[14], S[15]);
    if (tid == 0) DcM[hh * NCH + c] = cdA;
  }
}

// ---------------- Phase C: prefix-combine + output correction (+ fused RWKV groupnorm*silu) ----------------
__global__ __launch_bounds__(256) void corr_kernel(
    const float* __restrict__ MstR, const float* __restrict__ DcR,
    const float* __restrict__ rPb, const float* __restrict__ so,
    const float* __restrict__ MstM, const float* __restrict__ DcM,
    const float* __restrict__ Ccb, float* __restrict__ yb,
    const float* __restrict__ PZ, const float* __restrict__ gnw, const float* __restrict__ gnb,
    unsigned short* __restrict__ gob)
{
  __shared__ float S0l[64 * 68];
  __shared__ float Rl[CHK * 68];
  int b = blockIdx.x, tid = threadIdx.x;
  const float* rg; int ostride, obase, t0;
  bool rwkv = (b < 192);
  int h, cidx;
  if (rwkv) {
    h = b >> 5; cidx = b & 31;
    rg = rPb; obase = h * 64; ostride = DD;
  } else {
    int bb = b - 192; h = bb >> 5; cidx = bb & 31;
    rg = Ccb; obase = h * 64; ostride = DI;
  }
  t0 = cidx * CHK;
  float Sreg[16];
#pragma unroll
  for (int it = 0; it < 16; ++it) Sreg[it] = 0.f;
  if (rwkv) {
    int kk = tid & 63;
    for (int cp = 0; cp < cidx; ++cp) {
      float d = DcR[(h * NCH + cp) * 64 + kk];
      const float* mb = MstR + (size_t)(h * NCH + cp) * 4096;
#pragma unroll
      for (int it = 0; it < 16; ++it)
        Sreg[it] = fmaf(d, Sreg[it], mb[tid + 256 * it]);
    }
  } else {
    for (int cp = 0; cp < cidx; ++cp) {
      float d = DcM[h * NCH + cp];
      const float* mb = MstM + (size_t)(h * NCH + cp) * 4096;
#pragma unroll
      for (int it = 0; it < 16; ++it)
        Sreg[it] = fmaf(d, Sreg[it], mb[tid + 256 * it]);
    }
  }
#pragma unroll
  for (int it = 0; it < 16; ++it) {
    int gi = tid + 256 * it;
    S0l[(gi & 63) * 68 + (gi >> 6)] = Sreg[it];
  }
  {
    int t = tid >> 3, q = (tid & 7) * 8;
    const float4* src = (const float4*)&rg[(size_t)(t0 + t) * ostride + obase + q];
    float4* dst = (float4*)&Rl[t * 68 + q];
    dst[0] = src[0]; dst[1] = src[1];
  }
  __syncthreads();
  int t = tid >> 3, q = (tid & 7) * 8;
  float acc[8];
#pragma unroll
  for (int j = 0; j < 8; j++) acc[j] = 0.f;
  for (int k = 0; k < 64; ++k) {
    float rv = Rl[t * 68 + k];
    const float4* sp = (const float4*)&S0l[k * 68 + q];
    float4 s0 = sp[0], s1 = sp[1];
    acc[0] = fmaf(rv, s0.x, acc[0]);
    acc[1] = fmaf(rv, s0.y, acc[1]);
    acc[2] = fmaf(rv, s0.z, acc[2]);
    acc[3] = fmaf(rv, s0.w, acc[3]);
    acc[4] = fmaf(rv, s1.x, acc[4]);
    acc[5] = fmaf(rv, s1.y, acc[5]);
    acc[6] = fmaf(rv, s1.z, acc[6]);
    acc[7] = fmaf(rv, s1.w, acc[7]);
  }
  if (!rwkv) {
    float4* op = (float4*)&yb[(size_t)(t0 + t) * DI + obase + q];
    float4 c0 = op[0], c1 = op[1];
    c0.x += acc[0]; c0.y += acc[1]; c0.z += acc[2]; c0.w += acc[3];
    c1.x += acc[4]; c1.y += acc[5]; c1.z += acc[6]; c1.w += acc[7];
    op[0] = c0; op[1] = c1;
  } else {
    float ov[8];
    const float4* sp = (const float4*)&so[(size_t)(t0 + t) * DD + obase + q];
    float4 s0 = sp[0], s1 = sp[1];
    ov[0] = s0.x + acc[0]; ov[1] = s0.y + acc[1]; ov[2] = s0.z + acc[2]; ov[3] = s0.w + acc[3];
    ov[4] = s1.x + acc[4]; ov[5] = s1.y + acc[5]; ov[6] = s1.z + acc[6]; ov[7] = s1.w + acc[7];
    float m_ = 0.f;
#pragma unroll
    for (int j = 0; j < 8; j++) m_ += ov[j];
    m_ += __shfl_xor(m_, 1); m_ += __shfl_xor(m_, 2); m_ += __shfl_xor(m_, 4);
    float mu = m_ * (1.f / 64.f);
    float vv = 0.f;
#pragma unroll
    for (int j = 0; j < 8; j++) { float d = ov[j] - mu; vv = fmaf(d, d, vv); }
    vv += __shfl_xor(vv, 1); vv += __shfl_xor(vv, 2); vv += __shfl_xor(vv, 4);
    float rstd = rsqrtf(vv * (1.f / 64.f) + 1e-5f);
#pragma unroll
    for (int j = 0; j < 8; j++) {
      int d = obase + q + j;
      float gv = PZ[(size_t)(t0 + t) * PZS + G_OFF + d];
      float o = fmaf((ov[j] - mu) * rstd, gnw[d], gnb[d]) * siluf(gv);
      gob[(size_t)(t0 + t) * DD + d] = f2b(o);
    }
  }
}

// ---------------- Mamba out: rms(y * silu(z), mn_w) -> bf16 (wave per row) ----------------
__global__ __launch_bounds__(256) void mamba_norm_kernel(const float* __restrict__ yb,
    const float* __restrict__ PZ, const float* __restrict__ mnw, unsigned short* __restrict__ out)
{
  int row = blockIdx.x * 4 + (threadIdx.x >> 6);
  int lane = threadIdx.x & 63;
  float v[12]; float ss = 0.f;
#pragma unroll
  for (int j = 0; j < 12; ++j) {
    int c = lane + j * 64;
    float z = PZ[(size_t)row * PZS + Z_OFF + c];
    float t = yb[(size_t)row * DI + c] * siluf(z);
    v[j] = t; ss = fmaf(t, t, ss);
  }
#pragma unroll
  for (int s = 1; s < 64; s <<= 1) ss += __shfl_xor(ss, s);
  float scale = rsqrtf(ss * (1.f / DI) + 1e-6f);
#pragma unroll
  for (int j = 0; j < 12; ++j) {
    int c = lane + j * 64;
    out[(size_t)row * DI + c] = f2b(v[j] * scale * mnw[c]);
  }
}

// ---------------- gate combine + FFN RMSNorm (wave per row) ----------------
__global__ __launch_bounds__(256) void gate_rms_kernel(const float* __restrict__ orb,
    const float* __restrict__ omb, const float* __restrict__ gw,
    const float* __restrict__ gb, const float* __restrict__ flnw,
    float* __restrict__ h, unsigned short* __restrict__ xnb)
{
  int row = blockIdx.x * 4 + (threadIdx.x >> 6);
  int lane = threadIdx.x & 63;
  float a[6], bq[6]; float ss = 0.f;
#pragma unroll
  for (int j = 0; j < 6; ++j) {
    int c = lane + j * 64;
    a[j] = orb[(size_t)row * DD + c]; bq[j] = omb[(size_t)row * DD + c];
    ss += a[j] * gw[c] + bq[j] * gw[DD + c];
  }
#pragma unroll
  for (int s = 1; s < 64; s <<= 1) ss += __shfl_xor(ss, s);
  float gate = sigmoidf_(ss + gb[0]);
  float hn[6]; float ss2 = 0.f;
#pragma unroll
  for (int j = 0; j < 6; ++j) {
    int c = lane + j * 64;
    size_t ix = (size_t)row * DD + c;
    hn[j] = h[ix] + gate * a[j] + (1.f - gate) * bq[j];
    h[ix] = hn[j];
    ss2 = fmaf(hn[j], hn[j], ss2);
  }
#pragma unroll
  for (int s = 1; s < 64; s <<= 1) ss2 += __shfl_xor(ss2, s);
  float scale = rsqrtf(ss2 * (1.f / DD) + 1e-6f);
#pragma unroll
  for (int j = 0; j < 6; ++j) {
    int c = lane + j * 64;
    xnb[(size_t)row * DD + c] = f2b(flnw[c] * hn[j] * scale);
  }
}

// ---------------- launcher ----------------
extern "C" void kernel_launch(void* const* d_in, const int* in_sizes, int n_in,
                              void* d_out, int out_size, void* d_ws, size_t ws_size,
                              hipStream_t stream)
{
  const int*   x        = (const int*)  d_in[0];
  const float* embed    = (const float*)d_in[1];
  const float* ln_w     = (const float*)d_in[2];
  const float* Wr       = (const float*)d_in[3];
  const float* Wk       = (const float*)d_in[4];
  const float* Wv       = (const float*)d_in[5];
  const float* Wg       = (const float*)d_in[6];
  const float* Ww       = (const float*)d_in[7];
  const float* w_bias   = (const float*)d_in[8];
  const float* u        = (const float*)d_in[9];
  const float* gn_w     = (const float*)d_in[10];
  const float* gn_b     = (const float*)d_in[11];
  const float* Wo       = (const float*)d_in[12];
  const float* W_in     = (const float*)d_in[13];
  const float* conv_w   = (const float*)d_in[14];
  const float* conv_b   = (const float*)d_in[15];
  const float* dt_bias  = (const float*)d_in[16];
  const float* A_log    = (const float*)d_in[17];
  const float* Dp       = (const float*)d_in[18];
  const float* mn_w     = (const float*)d_in[19];
  const float* W_out    = (const float*)d_in[20];
  const float* gw       = (const float*)d_in[21];
  const float* gb       = (const float*)d_in[22];
  const float* ffn_ln_w = (const float*)d_in[23];
  const float* ffn_w1   = (const float*)d_in[24];
  const float* ffn_w2   = (const float*)d_in[25];
  const float* ln_out_w = (const float*)d_in[26];

  char* base = (char*)d_ws;
  size_t off = 0;
  auto alloc = [&](size_t bytes) { off = (off + 255) & ~(size_t)255; void* p = base + off; off += bytes; return p; };

  float* h    = (float*)alloc((size_t)TT * DD * 4);
  float* PZ   = (float*)alloc((size_t)TT * PZS * 4);
  float* yb   = (float*)alloc((size_t)TT * DI * 4);
  float* so   = (float*)alloc((size_t)TT * DD * 4);
  float* orb  = (float*)alloc((size_t)TT * DD * 4);
  float* omb  = (float*)alloc((size_t)TT * DD * 4);
  float* rPb  = (float*)alloc((size_t)TT * DD * 4);
  float* Ccb  = (float*)alloc((size_t)TT * DI * 4);
  float* MstR = (float*)alloc((size_t)NH * NCH * 4096 * 4);
  float* DcR  = (float*)alloc((size_t)NH * NCH * 64 * 4);
  float* MstM = (float*)alloc((size_t)MH * NCH * 4096 * 4);
  float* DcM  = (float*)alloc((size_t)MH * NCH * 4);
  unsigned short* xnb = (unsigned short*)alloc((size_t)TT * DD * 2);
  unsigned short* gob = (unsigned short*)alloc((size_t)TT * DD * 2);
  unsigned short* ynb = (unsigned short*)alloc((size_t)TT * DI * 2);
  unsigned short* fhb = (unsigned short*)alloc((size_t)TT * 1536 * 2);
  unsigned short* WallT = (unsigned short*)alloc((size_t)NL * PZS * 384 * 2);
  unsigned short* WoT   = (unsigned short*)alloc((size_t)NL * 384 * 384 * 2);
  unsigned short* WoutT = (unsigned short*)alloc((size_t)NL * 384 * 768 * 2);
  unsigned short* F1T   = (unsigned short*)alloc((size_t)NL * 1536 * 384 * 2);
  unsigned short* F2T   = (unsigned short*)alloc((size_t)NL * 384 * 1536 * 2);
  unsigned short* embB  = (unsigned short*)alloc((size_t)NV * DD * 2);
  (void)ws_size; (void)in_sizes; (void)n_in; (void)out_size;

  dim3 blk(256);
  int gTD = (TT * DD + 255) / 256;

  // ---- one-time (per launch) weight conversion, single dispatch ----
  TC10 tc;
  int te = 0;
  auto setjob = [&](int q, const float* src, unsigned short* dst, int K, int N, int Npad,
                    int nx, int ny, size_t sStr, size_t dStr) {
    te += nx * ny;
    tc.j[q] = TCJob{src, dst, K, N, Npad, nx, sStr, dStr, te};
  };
  setjob(0, Wr, WallT + (size_t)0 * 384 * 384, 384, 384, 384, 12, 12, (size_t)384 * 384, (size_t)PZS * 384);
  setjob(1, Wk, WallT + (size_t)1 * 384 * 384, 384, 384, 384, 12, 12, (size_t)384 * 384, (size_t)PZS * 384);
  setjob(2, Wv, WallT + (size_t)2 * 384 * 384, 384, 384, 384, 12, 12, (size_t)384 * 384, (size_t)PZS * 384);
  setjob(3, Wg, WallT + (size_t)3 * 384 * 384, 384, 384, 384, 12, 12, (size_t)384 * 384, (size_t)PZS * 384);
  setjob(4, Ww, WallT + (size_t)4 * 384 * 384, 384, 384, 384, 12, 12, (size_t)384 * 384, (size_t)PZS * 384);
  setjob(5, W_in, WallT + (size_t)1920 * 384, 384, XDIM, 1792, 56, 12, (size_t)384 * XDIM, (size_t)PZS * 384);
  setjob(6, Wo, WoT, 384, 384, 384, 12, 12, (size_t)384 * 384, (size_t)384 * 384);
  setjob(7, W_out, WoutT, 768, 384, 384, 12, 24, (size_t)768 * 384, (size_t)384 * 768);
  setjob(8, ffn_w1, F1T, 384, 1536, 1536, 48, 12, (size_t)384 * 1536, (size_t)1536 * 384);
  setjob(9, ffn_w2, F2T, 1536, 384, 384, 12, 48, (size_t)1536 * 384, (size_t)384 * 1536);
  transconv_all<<<dim3(te, 8), blk, 0, stream>>>(tc);
  conv_b16_kernel<<<(NV * DD + 255) / 256, blk, 0, stream>>>(embed, embB, NV * DD);
  embed_kernel<<<gTD, blk, 0, stream>>>(x, embed, h);

  for (int i = 0; i < NL; ++i) {
    rms_kernel<<<256, blk, 0, stream>>>(h, ln_w + (size_t)i * DD, xnb);

    gemm_bf16<0><<<dim3(58, 16), blk, 0, stream>>>(
        xnb, WallT + (size_t)i * PZS * 384, PZ, nullptr, PZS, 384, PZS);

    scanA_kernel<<<576, blk, 0, stream>>>(PZ, u + (size_t)i * NH * 64, w_bias + (size_t)i * DD,
                                          so, rPb, MstR, DcR,
                                          conv_w + (size_t)i * CONVC * 4, conv_b + (size_t)i * CONVC,
                                          dt_bias + (size_t)i * MH,
                                          A_log + (size_t)i * MH, Dp + (size_t)i * MH,
                                          yb, Ccb, MstM, DcM);
    corr_kernel<<<576, blk, 0, stream>>>(MstR, DcR, rPb, so, MstM, DcM, Ccb, yb,
                                         PZ, gn_w + (size_t)i * DD, gn_b + (size_t)i * DD, gob);

    mamba_norm_kernel<<<256, blk, 0, stream>>>(yb, PZ, mn_w + (size_t)i * DI, ynb);

    gemm_dual<<<192, blk, 0, stream>>>(
        gob, WoT + (size_t)i * 384 * 384, orb, 384, DD, 6, 96,
        ynb, WoutT + (size_t)i * 384 * 768, omb, 768, DD, 6);

    gate_rms_kernel<<<256, blk, 0, stream>>>(orb, omb, gw + (size_t)i * 2 * DD, gb + i,
                                             ffn_ln_w + (size_t)i * DD, h, xnb);

    gemm_bf16<1><<<dim3(24, 16), blk, 0, stream>>>(
        xnb, F1T + (size_t)i * 1536 * 384, nullptr, fhb, 1536, 384, 1536);
    gemm_bf16<3><<<dim3(6, 16, 4), blk, 0, stream>>>(
        fhb, F2T + (size_t)i * 384 * 1536, h, nullptr, 384, 1536, 384);
  }

  rms_kernel<<<256, blk, 0, stream>>>(h, ln_out_w, xnb);
  gemm128<<<dim3(2000), blk, 0, stream>>>(
      xnb, embB, (float*)d_out, NV, 384, NV);
}